// Round 15
// baseline (558.228 us; speedup 1.0000x reference)
//
#include <hip/hip_runtime.h>
#include <hip/hip_bf16.h>
#include <math.h>

typedef unsigned short u16;
typedef __attribute__((ext_vector_type(8))) short bf16x8;
typedef __attribute__((ext_vector_type(4))) float f32x4;

#define Bb 16
#define Cch 512
#define Ss 1024
#define NHh 8
#define DHh 64
#define CPG 64
#define EPSV 1e-5f
#define R_TOTAL (Bb*Ss)   // 16384

__device__ inline u16 f2bf(float f) {
    unsigned int u = __float_as_uint(f);
    unsigned int r = (u + 0x7fffu + ((u >> 16) & 1u)) >> 16;
    return (u16)r;
}
__device__ inline u16 f2bf_rz(float f) {           // truncate: 1 op, P in [0,1]
    return (u16)(__float_as_uint(f) >> 16);
}

// swizzled LDS offset (u16 units): row-stride 64, 16B chunk XOR'd by row&7
__device__ inline int swz(int row, int chunk) {
    return row * 64 + ((chunk ^ (row & 7)) * 8);
}

// async global->LDS, 16B per lane, dest = wave-uniform base + lane*16
__device__ inline void gld16(const u16* g, u16* l) {
    __builtin_amdgcn_global_load_lds(
        (const __attribute__((address_space(1))) void*)g,
        (__attribute__((address_space(3))) void*)l,
        16, 0, 0);
}

// ---------------- GroupNorm stats ----------------
__global__ __launch_bounds__(256) void gn_stats(const float* __restrict__ x,
                                                float* __restrict__ stats) {
    int bg = blockIdx.x;
    int b = bg >> 3, g = bg & 7;
    const float* base = x + ((size_t)b * Cch + (size_t)g * CPG) * Ss;
    float s = 0.f, ss = 0.f;
    for (int i = threadIdx.x; i < CPG * Ss; i += 256) {
        float v = base[i];
        s += v; ss += v * v;
    }
    for (int o = 32; o > 0; o >>= 1) { s += __shfl_down(s, o); ss += __shfl_down(ss, o); }
    __shared__ float red[2][4];
    int wid = threadIdx.x >> 6, lane = threadIdx.x & 63;
    if (lane == 0) { red[0][wid] = s; red[1][wid] = ss; }
    __syncthreads();
    if (threadIdx.x == 0) {
        float S1 = red[0][0] + red[0][1] + red[0][2] + red[0][3];
        float S2 = red[1][0] + red[1][1] + red[1][2] + red[1][3];
        const float inv_n = 1.0f / (CPG * Ss);
        float mu = S1 * inv_n;
        float var = S2 * inv_n - mu * mu;
        stats[bg * 2]     = mu;
        stats[bg * 2 + 1] = rsqrtf(var + EPSV);
    }
}

// ---------------- GroupNorm apply + transpose -> bf16 (B,S,C) ----------------
__global__ __launch_bounds__(256) void gn_apply_t_bf(const float* __restrict__ x,
                                                     const float* __restrict__ stats,
                                                     const float* __restrict__ gw,
                                                     const float* __restrict__ gb,
                                                     u16* __restrict__ ht) {
    __shared__ float tile[32][33];
    int b  = blockIdx.z;
    int c0 = blockIdx.y * 32;
    int s0 = blockIdx.x * 32;
    int tx = threadIdx.x, ty = threadIdx.y;
#pragma unroll
    for (int i = 0; i < 4; i++) {
        int c = c0 + ty + i * 8;
        int g = c >> 6;
        float mu = stats[(b * 8 + g) * 2];
        float rs = stats[(b * 8 + g) * 2 + 1];
        float v = x[((size_t)b * Cch + c) * Ss + s0 + tx];
        tile[ty + i * 8][tx] = (v - mu) * rs * gw[c] + gb[c];
    }
    __syncthreads();
#pragma unroll
    for (int i = 0; i < 4; i++) {
        int s = s0 + ty + i * 8;
        ht[((size_t)b * Ss + s) * Cch + c0 + tx] = f2bf(tile[tx][ty + i * 8]);
    }
}

// ---------------- fp32 -> bf16 straight convert ----------------
__global__ __launch_bounds__(256) void conv_bf16(const float* __restrict__ in,
                                                 u16* __restrict__ outp, int n) {
    for (int i = blockIdx.x * 256 + threadIdx.x; i < n; i += gridDim.x * 256)
        outp[i] = f2bf(in[i]);
}

// ---------------- transpose + convert: in (R x C) fp32 -> out (C x R) bf16 ----------------
__global__ __launch_bounds__(256) void convT_bf16(const float* __restrict__ in,
                                                  u16* __restrict__ outp, int R, int C) {
    __shared__ float tile[32][33];
    int c0 = blockIdx.x * 32, r0 = blockIdx.y * 32;
    int tx = threadIdx.x, ty = threadIdx.y;
#pragma unroll
    for (int i = 0; i < 4; i++)
        tile[ty + i * 8][tx] = in[(size_t)(r0 + ty + i * 8) * C + c0 + tx];
    __syncthreads();
#pragma unroll
    for (int i = 0; i < 4; i++)
        outp[(size_t)(c0 + ty + i * 8) * R + r0 + tx] = f2bf(tile[tx][ty + i * 8]);
}

// ---------------- per-head V transpose: vb [b][s][512] -> vt [(b*8+h)][64][1024] ----------
__global__ __launch_bounds__(256) void vtrans(const u16* __restrict__ in,
                                              u16* __restrict__ outp) {
    __shared__ u16 tile[64][66];
    int s0 = blockIdx.x * 64, h = blockIdx.y, b = blockIdx.z;
    const u16* src = in + ((size_t)b * Ss + s0) * Cch + h * 64;
    int r = threadIdx.x >> 3, c8 = (threadIdx.x & 7) * 8;
#pragma unroll
    for (int p = 0; p < 2; p++) {
        int rr = r + p * 32;
        *(int4*)&tile[rr][c8] = *(const int4*)&src[(size_t)rr * Cch + c8];
    }
    __syncthreads();
    u16* dst = outp + ((size_t)(b * 8 + h) * 64) * Ss + s0;
#pragma unroll
    for (int p = 0; p < 2; p++) {
        int d = r + p * 32;
        u16 vals[8];
#pragma unroll
        for (int e = 0; e < 8; e++) vals[e] = tile[c8 + e][d];
        *(int4*)&dst[(size_t)d * Ss + c8] = *(int4*)vals;
    }
}

// ---------------- LayerNorm rows (fp32 in, bf16 out) ----------------
__global__ __launch_bounds__(256) void layer_norm_rows_bf(const float* __restrict__ in,
                                                          const float* __restrict__ w,
                                                          const float* __restrict__ bb,
                                                          u16* __restrict__ outp) {
    int row = blockIdx.x;
    const float* p = in + (size_t)row * Cch;
    float v0 = p[threadIdx.x], v1 = p[threadIdx.x + 256];
    float s = v0 + v1, ss = v0 * v0 + v1 * v1;
    for (int o = 32; o > 0; o >>= 1) { s += __shfl_down(s, o); ss += __shfl_down(ss, o); }
    __shared__ float red[2][4];
    __shared__ float mu_s, rs_s;
    int wid = threadIdx.x >> 6, lane = threadIdx.x & 63;
    if (lane == 0) { red[0][wid] = s; red[1][wid] = ss; }
    __syncthreads();
    if (threadIdx.x == 0) {
        float S1 = red[0][0] + red[0][1] + red[0][2] + red[0][3];
        float S2 = red[1][0] + red[1][1] + red[1][2] + red[1][3];
        float mu = S1 * (1.0f / Cch);
        float var = S2 * (1.0f / Cch) - mu * mu;
        mu_s = mu; rs_s = rsqrtf(var + EPSV);
    }
    __syncthreads();
    float mu = mu_s, rs = rs_s;
    outp[(size_t)row * Cch + threadIdx.x]       = f2bf((v0 - mu) * rs * w[threadIdx.x] + bb[threadIdx.x]);
    outp[(size_t)row * Cch + threadIdx.x + 256] = f2bf((v1 - mu) * rs * w[threadIdx.x + 256] + bb[threadIdx.x + 256]);
}

// ---------------- MFMA GEMM: out(MxN) = A(MxK bf16) @ Bt(NxK bf16)^T ----------------
// 128x128 tile, BK=32, 256 thr = 4 waves (2x2). Double-buffered global_load_lds:
// next tile's loads are issued BEFORE reading current tile (m97 schedule) so they
// overlap MFMA; the single end-of-iter barrier drains vmcnt after compute.
// EPI: 0 = store bf16; 1 = fp32 +bias; 2 = fp32 +bias+res(inplace); 3 = EPI2 + bf16 copy.
template<int EPI>
__global__ __launch_bounds__(256) void mfma_gemm(const u16* __restrict__ A,
                                                 const u16* __restrict__ Bt,
                                                 const float* __restrict__ bias,
                                                 float* __restrict__ fout,
                                                 u16* __restrict__ outb,
                                                 int K, int N) {
    __shared__ u16 As[2][128 * 32];
    __shared__ u16 Bs[2][128 * 32];
    int tid = threadIdx.x;
    int m0 = blockIdx.y * 128, n0 = blockIdx.x * 128;
    int wave = tid >> 6, lane = tid & 63;
    int wr = wave >> 1, wc = wave & 1;
    int l15 = lane & 15, l4 = lane >> 4;

    f32x4 zero4 = {0.f, 0.f, 0.f, 0.f};
    f32x4 acc[4][4];
#pragma unroll
    for (int i = 0; i < 4; i++)
#pragma unroll
        for (int j = 0; j < 4; j++) acc[i][j] = zero4;

    int gr = lane >> 2, gk = (lane & 3) * 8;
    const u16* ga = A  + (size_t)(m0 + wave * 32 + gr) * K + gk;
    const u16* gb = Bt + (size_t)(n0 + wave * 32 + gr) * K + gk;
    int wof = wave * 1024;

    // prologue: stage tile 0
    gld16(ga,                 As[0] + wof);
    gld16(ga + (size_t)16 * K, As[0] + wof + 512);
    gld16(gb,                 Bs[0] + wof);
    gld16(gb + (size_t)16 * K, Bs[0] + wof + 512);
    __syncthreads();

    int cur = 0;
    for (int kt = 0; kt < K; kt += 32) {
        int nxt = cur ^ 1;
        if (kt + 32 < K) {      // issue next tile's loads (fly during MFMA)
            gld16(ga + kt + 32,                 As[nxt] + wof);
            gld16(ga + (size_t)16 * K + kt + 32, As[nxt] + wof + 512);
            gld16(gb + kt + 32,                 Bs[nxt] + wof);
            gld16(gb + (size_t)16 * K + kt + 32, Bs[nxt] + wof + 512);
        }
        bf16x8 af[4], bfr[4];
#pragma unroll
        for (int mi = 0; mi < 4; mi++)
            af[mi] = *(const bf16x8*)&As[cur][(wr * 64 + mi * 16 + l15) * 32 + l4 * 8];
#pragma unroll
        for (int nj = 0; nj < 4; nj++)
            bfr[nj] = *(const bf16x8*)&Bs[cur][(wc * 64 + nj * 16 + l15) * 32 + l4 * 8];
#pragma unroll
        for (int mi = 0; mi < 4; mi++)
#pragma unroll
            for (int nj = 0; nj < 4; nj++)
                acc[mi][nj] = __builtin_amdgcn_mfma_f32_16x16x32_bf16(af[mi], bfr[nj], acc[mi][nj], 0, 0, 0);
        __syncthreads();        // drains vmcnt (next tile ready) + guards buffer reuse
        cur = nxt;
    }

#pragma unroll
    for (int mi = 0; mi < 4; mi++)
#pragma unroll
        for (int nj = 0; nj < 4; nj++)
#pragma unroll
            for (int r = 0; r < 4; r++) {
                int row = m0 + wr * 64 + mi * 16 + l4 * 4 + r;
                int col = n0 + wc * 64 + nj * 16 + l15;
                float v = acc[mi][nj][r];
                if constexpr (EPI == 0) {
                    outb[(size_t)row * N + col] = f2bf(v);
                } else {
                    v += bias[col];
                    if constexpr (EPI >= 2) v += fout[(size_t)row * N + col];
                    fout[(size_t)row * N + col] = v;
                    if constexpr (EPI == 3) outb[(size_t)row * N + col] = f2bf(v);
                }
            }
}

// ---------------- GEGLU MFMA: both halves of tn3 @ wg, fused exact GELU, bf16 out --------
__global__ __launch_bounds__(256) void geglu_mfma(const u16* __restrict__ A,
                                                  const u16* __restrict__ WgT,  // [4096][512]
                                                  const float* __restrict__ bg,
                                                  u16* __restrict__ ag) {
    __shared__ u16 As[2][128 * 32];
    __shared__ u16 Bs1[2][64 * 32];
    __shared__ u16 Bs2[2][64 * 32];
    const int K = 512;
    int tid = threadIdx.x;
    int m0 = blockIdx.y * 128, n0 = blockIdx.x * 64;
    int wave = tid >> 6, lane = tid & 63;
    int wr = wave >> 1, wc = wave & 1;
    int l15 = lane & 15, l4 = lane >> 4;

    f32x4 zero4 = {0.f, 0.f, 0.f, 0.f};
    f32x4 accA[4][2], accG[4][2];
#pragma unroll
    for (int i = 0; i < 4; i++) { accA[i][0] = zero4; accA[i][1] = zero4; accG[i][0] = zero4; accG[i][1] = zero4; }

    int gr = lane >> 2, gk = (lane & 3) * 8;
    const u16* ga  = A   + (size_t)(m0 + wave * 32 + gr) * K + gk;
    const u16* gb1 = WgT + (size_t)(n0 + wave * 16 + gr) * K + gk;
    const u16* gb2 = WgT + (size_t)(2048 + n0 + wave * 16 + gr) * K + gk;
    int wofA = wave * 1024, wofB = wave * 512;

    gld16(ga,                 As[0] + wofA);
    gld16(ga + (size_t)16 * K, As[0] + wofA + 512);
    gld16(gb1,                Bs1[0] + wofB);
    gld16(gb2,                Bs2[0] + wofB);
    __syncthreads();

    int cur = 0;
    for (int kt = 0; kt < K; kt += 32) {
        int nxt = cur ^ 1;
        if (kt + 32 < K) {
            gld16(ga + kt + 32,                 As[nxt] + wofA);
            gld16(ga + (size_t)16 * K + kt + 32, As[nxt] + wofA + 512);
            gld16(gb1 + kt + 32,                Bs1[nxt] + wofB);
            gld16(gb2 + kt + 32,                Bs2[nxt] + wofB);
        }
        bf16x8 af[4], b1[2], b2[2];
#pragma unroll
        for (int mi = 0; mi < 4; mi++)
            af[mi] = *(const bf16x8*)&As[cur][(wr * 64 + mi * 16 + l15) * 32 + l4 * 8];
#pragma unroll
        for (int nj = 0; nj < 2; nj++) {
            b1[nj] = *(const bf16x8*)&Bs1[cur][(wc * 32 + nj * 16 + l15) * 32 + l4 * 8];
            b2[nj] = *(const bf16x8*)&Bs2[cur][(wc * 32 + nj * 16 + l15) * 32 + l4 * 8];
        }
#pragma unroll
        for (int mi = 0; mi < 4; mi++)
#pragma unroll
            for (int nj = 0; nj < 2; nj++) {
                accA[mi][nj] = __builtin_amdgcn_mfma_f32_16x16x32_bf16(af[mi], b1[nj], accA[mi][nj], 0, 0, 0);
                accG[mi][nj] = __builtin_amdgcn_mfma_f32_16x16x32_bf16(af[mi], b2[nj], accG[mi][nj], 0, 0, 0);
            }
        __syncthreads();
        cur = nxt;
    }

#pragma unroll
    for (int mi = 0; mi < 4; mi++)
#pragma unroll
        for (int nj = 0; nj < 2; nj++)
#pragma unroll
            for (int r = 0; r < 4; r++) {
                int row = m0 + wr * 64 + mi * 16 + l4 * 4 + r;
                int col = n0 + wc * 32 + nj * 16 + l15;
                float a = accA[mi][nj][r] + bg[col];
                float g = accG[mi][nj][r] + bg[2048 + col];
                float ge = 0.5f * g * (1.0f + erff(g * 0.70710678118654752f));
                ag[(size_t)row * 2048 + col] = f2bf(a * ge);
            }
}

// ---------------- MFMA flash attention (XOR-swizzled LDS, __expf softmax) ----------------
__global__ __launch_bounds__(256) void flash_attn_mfma(const u16* __restrict__ q,
                                                       const u16* __restrict__ k,
                                                       const u16* __restrict__ vt,  // [b*8+h][64][1024]
                                                       u16* __restrict__ o) {
    __shared__ u16 Qs[64 * 64];
    __shared__ u16 Ks[64 * 64];
    __shared__ u16 Vt[64 * 64];
    __shared__ u16 Ps[64 * 64];
    const int tid = threadIdx.x;
    const int h = blockIdx.y, b = blockIdx.z;
    const int q0 = blockIdx.x * 64;
    const size_t hb  = (size_t)b * Ss * Cch + (size_t)h * DHh;
    const size_t vhb = ((size_t)(b * NHh + h) * DHh) * Ss;

    const int wq = tid >> 6;
    const int lane = tid & 63;
    const int l15 = lane & 15, l4 = lane >> 4;

    // stage Q (64x64), coalesced 32B/thread, swizzled dest
    {
        int r = tid >> 2, ch = (tid & 3) * 2;
        const u16* src = q + hb + (size_t)(q0 + r) * Cch + ch * 8;
        *(int4*)&Qs[swz(r, ch)]     = *(const int4*)src;
        *(int4*)&Qs[swz(r, ch + 1)] = *(const int4*)(src + 8);
    }

    f32x4 zero4 = {0.f, 0.f, 0.f, 0.f};
    f32x4 oacc[4];
    float m_[4], l_[4];
#pragma unroll
    for (int j = 0; j < 4; j++) oacc[j] = zero4;
#pragma unroll
    for (int r = 0; r < 4; r++) { m_[r] = -1e30f; l_[r] = 0.f; }

    for (int t0 = 0; t0 < Ss; t0 += 64) {
        __syncthreads();
        {
            int r = tid >> 2, ch = (tid & 3) * 2;
            const u16* ksrc = k + hb + (size_t)(t0 + r) * Cch + ch * 8;
            *(int4*)&Ks[swz(r, ch)]     = *(const int4*)ksrc;
            *(int4*)&Ks[swz(r, ch + 1)] = *(const int4*)(ksrc + 8);
            const u16* vsrc = vt + vhb + (size_t)r * Ss + t0 + ch * 8;
            *(int4*)&Vt[swz(r, ch)]     = *(const int4*)vsrc;
            *(int4*)&Vt[swz(r, ch + 1)] = *(const int4*)(vsrc + 8);
        }
        __syncthreads();

        // QK^T: wave's 16 q-rows x 64 t-cols
        f32x4 sacc[4];
#pragma unroll
        for (int j = 0; j < 4; j++) sacc[j] = zero4;
#pragma unroll
        for (int ks = 0; ks < 2; ks++) {
            bf16x8 aq = *(const bf16x8*)&Qs[swz(wq * 16 + l15, ks * 4 + l4)];
#pragma unroll
            for (int j = 0; j < 4; j++) {
                bf16x8 bk = *(const bf16x8*)&Ks[swz(j * 16 + l15, ks * 4 + l4)];
                sacc[j] = __builtin_amdgcn_mfma_f32_16x16x32_bf16(aq, bk, sacc[j], 0, 0, 0);
            }
        }

        // online softmax: lane holds rows l4*4+r, cols l15+16j
#pragma unroll
        for (int r = 0; r < 4; r++) {
            float s0 = sacc[0][r] * 0.125f;
            float s1 = sacc[1][r] * 0.125f;
            float s2 = sacc[2][r] * 0.125f;
            float s3 = sacc[3][r] * 0.125f;
            float tm = fmaxf(fmaxf(s0, s1), fmaxf(s2, s3));
            tm = fmaxf(tm, __shfl_xor(tm, 1));
            tm = fmaxf(tm, __shfl_xor(tm, 2));
            tm = fmaxf(tm, __shfl_xor(tm, 4));
            tm = fmaxf(tm, __shfl_xor(tm, 8));
            float nm = fmaxf(m_[r], tm);
            float sc = __expf(m_[r] - nm);
            m_[r] = nm;
            float p0 = __expf(s0 - nm), p1 = __expf(s1 - nm);
            float p2 = __expf(s2 - nm), p3 = __expf(s3 - nm);
            int row = wq * 16 + l4 * 4 + r;
            int rx = row & 7, base = row * 64, wi = l15 & 7, hi = l15 >> 3;
            Ps[base + (((0 + hi) ^ rx) * 8) + wi] = f2bf_rz(p0);
            Ps[base + (((2 + hi) ^ rx) * 8) + wi] = f2bf_rz(p1);
            Ps[base + (((4 + hi) ^ rx) * 8) + wi] = f2bf_rz(p2);
            Ps[base + (((6 + hi) ^ rx) * 8) + wi] = f2bf_rz(p3);
            float rs = p0 + p1 + p2 + p3;
            rs += __shfl_xor(rs, 1);
            rs += __shfl_xor(rs, 2);
            rs += __shfl_xor(rs, 4);
            rs += __shfl_xor(rs, 8);
            l_[r] = l_[r] * sc + rs;
#pragma unroll
            for (int j = 0; j < 4; j++) oacc[j][r] *= sc;
        }

        // PV: A=Ps (own rows, same-wave dep), Bt=Vt[d][t]
#pragma unroll
        for (int ks = 0; ks < 2; ks++) {
            bf16x8 pa = *(const bf16x8*)&Ps[swz(wq * 16 + l15, ks * 4 + l4)];
#pragma unroll
            for (int j = 0; j < 4; j++) {
                bf16x8 bv = *(const bf16x8*)&Vt[swz(j * 16 + l15, ks * 4 + l4)];
                oacc[j] = __builtin_amdgcn_mfma_f32_16x16x32_bf16(pa, bv, oacc[j], 0, 0, 0);
            }
        }
    }

    // finalize: O /= l, stage via Qs (wave-private rows, swizzled), coalesced store
#pragma unroll
    for (int r = 0; r < 4; r++) {
        float inv = 1.0f / l_[r];
        int row = wq * 16 + l4 * 4 + r;
        int rx = row & 7, base = row * 64, wi = l15 & 7, hi = l15 >> 3;
        Qs[base + (((0 + hi) ^ rx) * 8) + wi] = f2bf(oacc[0][r] * inv);
        Qs[base + (((2 + hi) ^ rx) * 8) + wi] = f2bf(oacc[1][r] * inv);
        Qs[base + (((4 + hi) ^ rx) * 8) + wi] = f2bf(oacc[2][r] * inv);
        Qs[base + (((6 + hi) ^ rx) * 8) + wi] = f2bf(oacc[3][r] * inv);
    }
    __syncthreads();
    {
        int r = tid >> 2, ch = (tid & 3) * 2;
        u16* dst = o + hb + (size_t)(q0 + r) * Cch + ch * 8;
        *(int4*)dst       = *(const int4*)&Qs[swz(r, ch)];
        *(int4*)(dst + 8) = *(const int4*)&Qs[swz(r, ch + 1)];
    }
}

// ---------------- final: out(B,C,S) = tmp(B,S,C)^T + x ----------------
__global__ __launch_bounds__(256) void final_out(const float* __restrict__ tmp,
                                                 const float* __restrict__ x,
                                                 float* __restrict__ outp) {
    __shared__ float tile[32][33];
    int b = blockIdx.z, c0 = blockIdx.y * 32, s0 = blockIdx.x * 32;
    int tx = threadIdx.x, ty = threadIdx.y;
#pragma unroll
    for (int i = 0; i < 4; i++) {
        int s = s0 + ty + i * 8;
        tile[ty + i * 8][tx] = tmp[((size_t)b * Ss + s) * Cch + c0 + tx];
    }
    __syncthreads();
#pragma unroll
    for (int i = 0; i < 4; i++) {
        int c = c0 + ty + i * 8;
        size_t idx = ((size_t)b * Cch + c) * Ss + s0 + tx;
        outp[idx] = tile[tx][ty + i * 8] + x[idx];
    }
}

extern "C" void kernel_launch(void* const* d_in, const int* in_sizes, int n_in,
                              void* d_out, int out_size, void* d_ws, size_t ws_size,
                              hipStream_t stream) {
    (void)in_sizes; (void)n_in; (void)out_size; (void)ws_size;
    const float* x      = (const float*)d_in[0];
    const float* gn_w   = (const float*)d_in[1];
    const float* gn_b   = (const float*)d_in[2];
    const float* pin_w  = (const float*)d_in[3];
    const float* pin_b  = (const float*)d_in[4];
    const float* ln1_w  = (const float*)d_in[5];
    const float* ln1_b  = (const float*)d_in[6];
    const float* wq     = (const float*)d_in[7];
    const float* wk     = (const float*)d_in[8];
    const float* wv     = (const float*)d_in[9];
    const float* wo     = (const float*)d_in[10];
    const float* bo     = (const float*)d_in[11];
    const float* ln3_w  = (const float*)d_in[12];
    const float* ln3_b  = (const float*)d_in[13];
    const float* wg     = (const float*)d_in[14];
    const float* bg     = (const float*)d_in[15];
    const float* wd     = (const float*)d_in[16];
    const float* bd     = (const float*)d_in[17];
    const float* pout_w = (const float*)d_in[18];
    const float* pout_b = (const float*)d_in[19];
    float* out = (float*)d_out;

    // ---- workspace layout (bytes) ----
    char* W = (char*)d_ws;
    float* t_f32   = (float*)W;                                   // 33.55 MB
    float* tmp_f32 = (float*)(W + 33554432);                      // 33.55 MB
    u16* qb    = (u16*)(W + 67108864);                            // 16.78 MB
    u16* kb    = qb + 8388608;
    u16* vb    = kb + 8388608;
    u16* attnb = vb + 8388608;
    u16* Xb    = attnb + 8388608;                                 // 16.78 MB
    float* stats = (float*)(W + 67108864 + 5ull * 16777216);      // 1 KB
    u16* wbase = (u16*)(W + 67108864 + 5ull * 16777216 + 1024);
    u16* pinB  = wbase;                 // 512*512  (already [N][K])
    u16* poutB = pinB  + 262144;
    u16* wqT   = poutB + 262144;        // [512][512] transposed
    u16* wkT   = wqT   + 262144;
    u16* wvT   = wkT   + 262144;
    u16* woT   = wvT   + 262144;
    u16* wgT   = woT   + 262144;        // [4096][512]
    u16* wdT   = wgT   + 2097152;       // [512][2048]
    u16* ag    = qb;                    // R x 2048 bf16, aliases qb..attnb (dead by then)
    u16* vtb   = (u16*)tmp_f32;         // V^T [b*8+h][64][1024], aliases tmp_f32 (dead until pout)

    dim3 tb(32, 8);

    // stats + weight prep
    gn_stats<<<128, 256, 0, stream>>>(x, stats);
    conv_bf16<<<256, 256, 0, stream>>>(pin_w,  pinB,  262144);
    conv_bf16<<<256, 256, 0, stream>>>(pout_w, poutB, 262144);
    convT_bf16<<<dim3(16, 16),  tb, 0, stream>>>(wq, wqT, 512, 512);
    convT_bf16<<<dim3(16, 16),  tb, 0, stream>>>(wk, wkT, 512, 512);
    convT_bf16<<<dim3(16, 16),  tb, 0, stream>>>(wv, wvT, 512, 512);
    convT_bf16<<<dim3(16, 16),  tb, 0, stream>>>(wo, woT, 512, 512);
    convT_bf16<<<dim3(128, 16), tb, 0, stream>>>(wg, wgT, 512, 4096);
    convT_bf16<<<dim3(16, 64),  tb, 0, stream>>>(wd, wdT, 2048, 512);

    // h = GN(x) transposed -> Xb (bf16)
    gn_apply_t_bf<<<dim3(32, 16, 16), tb, 0, stream>>>(x, stats, gn_w, gn_b, Xb);

    // t = h @ pin_w^T + pin_b -> t_f32
    mfma_gemm<1><<<dim3(4, 128), 256, 0, stream>>>(Xb, pinB, pin_b, t_f32, nullptr, 512, 512);
    // tn = ln1(t) -> Xb
    layer_norm_rows_bf<<<16384, 256, 0, stream>>>(t_f32, ln1_w, ln1_b, Xb);
    // q, k, v (bf16, coalesced)
    mfma_gemm<0><<<dim3(4, 128), 256, 0, stream>>>(Xb, wqT, nullptr, nullptr, qb, 512, 512);
    mfma_gemm<0><<<dim3(4, 128), 256, 0, stream>>>(Xb, wkT, nullptr, nullptr, kb, 512, 512);
    mfma_gemm<0><<<dim3(4, 128), 256, 0, stream>>>(Xb, wvT, nullptr, nullptr, vb, 512, 512);
    // per-head V transpose -> vtb
    vtrans<<<dim3(16, 8, 16), 256, 0, stream>>>(vb, vtb);
    // attention (MFMA) -> attnb (bf16)
    flash_attn_mfma<<<dim3(16, 8, 16), 256, 0, stream>>>(qb, kb, vtb, attnb);
    // t += attn @ wo + bo (in-place on t_f32)
    mfma_gemm<2><<<dim3(4, 128), 256, 0, stream>>>(attnb, woT, bo, t_f32, nullptr, 512, 512);
    // tn3 = ln3(t) -> Xb
    layer_norm_rows_bf<<<16384, 256, 0, stream>>>(t_f32, ln3_w, ln3_b, Xb);
    // ag = a * gelu(g) (bf16), aliases q/k/v/attn space
    geglu_mfma<<<dim3(32, 128), 256, 0, stream>>>(Xb, wgT, bg, ag);
    // t += ag @ wd + bd (in-place), plus bf16 copy of new t -> Xb
    mfma_gemm<3><<<dim3(4, 128), 256, 0, stream>>>(ag, wdT, bd, t_f32, Xb, 2048, 512);
    // tmp = t @ pout_w^T + pout_b -> tmp_f32
    mfma_gemm<1><<<dim3(4, 128), 256, 0, stream>>>(Xb, poutB, pout_b, tmp_f32, nullptr, 512, 512);
    // out = tmp^T + x
    final_out<<<dim3(32, 16, 16), tb, 0, stream>>>(tmp_f32, x, out);
}

// Round 16
// 555.396 us; speedup vs baseline: 1.0051x; 1.0051x over previous
//
#include <hip/hip_runtime.h>
#include <hip/hip_bf16.h>
#include <math.h>

typedef unsigned short u16;
typedef __attribute__((ext_vector_type(8))) short bf16x8;
typedef __attribute__((ext_vector_type(4))) float f32x4;

#define Bb 16
#define Cch 512
#define Ss 1024
#define NHh 8
#define DHh 64
#define CPG 64
#define EPSV 1e-5f
#define R_TOTAL (Bb*Ss)   // 16384

__device__ inline u16 f2bf(float f) {
    unsigned int u = __float_as_uint(f);
    unsigned int r = (u + 0x7fffu + ((u >> 16) & 1u)) >> 16;
    return (u16)r;
}
__device__ inline u16 f2bf_rz(float f) {           // truncate: 1 op, P in [0,1]
    return (u16)(__float_as_uint(f) >> 16);
}

// swizzled LDS offset (u16 units): row-stride 64, 16B chunk XOR'd by row&7
__device__ inline int swz(int row, int chunk) {
    return row * 64 + ((chunk ^ (row & 7)) * 8);
}

// ---------------- GroupNorm stats ----------------
__global__ __launch_bounds__(256) void gn_stats(const float* __restrict__ x,
                                                float* __restrict__ stats) {
    int bg = blockIdx.x;
    int b = bg >> 3, g = bg & 7;
    const float* base = x + ((size_t)b * Cch + (size_t)g * CPG) * Ss;
    float s = 0.f, ss = 0.f;
    for (int i = threadIdx.x; i < CPG * Ss; i += 256) {
        float v = base[i];
        s += v; ss += v * v;
    }
    for (int o = 32; o > 0; o >>= 1) { s += __shfl_down(s, o); ss += __shfl_down(ss, o); }
    __shared__ float red[2][4];
    int wid = threadIdx.x >> 6, lane = threadIdx.x & 63;
    if (lane == 0) { red[0][wid] = s; red[1][wid] = ss; }
    __syncthreads();
    if (threadIdx.x == 0) {
        float S1 = red[0][0] + red[0][1] + red[0][2] + red[0][3];
        float S2 = red[1][0] + red[1][1] + red[1][2] + red[1][3];
        const float inv_n = 1.0f / (CPG * Ss);
        float mu = S1 * inv_n;
        float var = S2 * inv_n - mu * mu;
        stats[bg * 2]     = mu;
        stats[bg * 2 + 1] = rsqrtf(var + EPSV);
    }
}

// ---------------- GroupNorm apply + transpose -> bf16 (B,S,C) ----------------
__global__ __launch_bounds__(256) void gn_apply_t_bf(const float* __restrict__ x,
                                                     const float* __restrict__ stats,
                                                     const float* __restrict__ gw,
                                                     const float* __restrict__ gb,
                                                     u16* __restrict__ ht) {
    __shared__ float tile[32][33];
    int b  = blockIdx.z;
    int c0 = blockIdx.y * 32;
    int s0 = blockIdx.x * 32;
    int tx = threadIdx.x, ty = threadIdx.y;
#pragma unroll
    for (int i = 0; i < 4; i++) {
        int c = c0 + ty + i * 8;
        int g = c >> 6;
        float mu = stats[(b * 8 + g) * 2];
        float rs = stats[(b * 8 + g) * 2 + 1];
        float v = x[((size_t)b * Cch + c) * Ss + s0 + tx];
        tile[ty + i * 8][tx] = (v - mu) * rs * gw[c] + gb[c];
    }
    __syncthreads();
#pragma unroll
    for (int i = 0; i < 4; i++) {
        int s = s0 + ty + i * 8;
        ht[((size_t)b * Ss + s) * Cch + c0 + tx] = f2bf(tile[tx][ty + i * 8]);
    }
}

// ---------------- fp32 -> bf16 straight convert ----------------
__global__ __launch_bounds__(256) void conv_bf16(const float* __restrict__ in,
                                                 u16* __restrict__ outp, int n) {
    for (int i = blockIdx.x * 256 + threadIdx.x; i < n; i += gridDim.x * 256)
        outp[i] = f2bf(in[i]);
}

// ---------------- transpose + convert: in (R x C) fp32 -> out (C x R) bf16 ----------------
__global__ __launch_bounds__(256) void convT_bf16(const float* __restrict__ in,
                                                  u16* __restrict__ outp, int R, int C) {
    __shared__ float tile[32][33];
    int c0 = blockIdx.x * 32, r0 = blockIdx.y * 32;
    int tx = threadIdx.x, ty = threadIdx.y;
#pragma unroll
    for (int i = 0; i < 4; i++)
        tile[ty + i * 8][tx] = in[(size_t)(r0 + ty + i * 8) * C + c0 + tx];
    __syncthreads();
#pragma unroll
    for (int i = 0; i < 4; i++)
        outp[(size_t)(c0 + ty + i * 8) * R + r0 + tx] = f2bf(tile[tx][ty + i * 8]);
}

// ---------------- per-head V transpose: vb [b][s][512] -> vt [(b*8+h)][64][1024] ----------
__global__ __launch_bounds__(256) void vtrans(const u16* __restrict__ in,
                                              u16* __restrict__ outp) {
    __shared__ u16 tile[64][66];
    int s0 = blockIdx.x * 64, h = blockIdx.y, b = blockIdx.z;
    const u16* src = in + ((size_t)b * Ss + s0) * Cch + h * 64;
    int r = threadIdx.x >> 3, c8 = (threadIdx.x & 7) * 8;
#pragma unroll
    for (int p = 0; p < 2; p++) {
        int rr = r + p * 32;
        *(int4*)&tile[rr][c8] = *(const int4*)&src[(size_t)rr * Cch + c8];
    }
    __syncthreads();
    u16* dst = outp + ((size_t)(b * 8 + h) * 64) * Ss + s0;
#pragma unroll
    for (int p = 0; p < 2; p++) {
        int d = r + p * 32;
        u16 vals[8];
#pragma unroll
        for (int e = 0; e < 8; e++) vals[e] = tile[c8 + e][d];
        *(int4*)&dst[(size_t)d * Ss + c8] = *(int4*)vals;
    }
}

// ---------------- LayerNorm rows (fp32 in, bf16 out) ----------------
__global__ __launch_bounds__(256) void layer_norm_rows_bf(const float* __restrict__ in,
                                                          const float* __restrict__ w,
                                                          const float* __restrict__ bb,
                                                          u16* __restrict__ outp) {
    int row = blockIdx.x;
    const float* p = in + (size_t)row * Cch;
    float v0 = p[threadIdx.x], v1 = p[threadIdx.x + 256];
    float s = v0 + v1, ss = v0 * v0 + v1 * v1;
    for (int o = 32; o > 0; o >>= 1) { s += __shfl_down(s, o); ss += __shfl_down(ss, o); }
    __shared__ float red[2][4];
    __shared__ float mu_s, rs_s;
    int wid = threadIdx.x >> 6, lane = threadIdx.x & 63;
    if (lane == 0) { red[0][wid] = s; red[1][wid] = ss; }
    __syncthreads();
    if (threadIdx.x == 0) {
        float S1 = red[0][0] + red[0][1] + red[0][2] + red[0][3];
        float S2 = red[1][0] + red[1][1] + red[1][2] + red[1][3];
        float mu = S1 * (1.0f / Cch);
        float var = S2 * (1.0f / Cch) - mu * mu;
        mu_s = mu; rs_s = rsqrtf(var + EPSV);
    }
    __syncthreads();
    float mu = mu_s, rs = rs_s;
    outp[(size_t)row * Cch + threadIdx.x]       = f2bf((v0 - mu) * rs * w[threadIdx.x] + bb[threadIdx.x]);
    outp[(size_t)row * Cch + threadIdx.x + 256] = f2bf((v1 - mu) * rs * w[threadIdx.x + 256] + bb[threadIdx.x + 256]);
}

// ---------------- MFMA GEMM: out(MxN) = A(MxK bf16) @ Bt(NxK bf16)^T ----------------
// 128x128 tile, BK=32, 256 thr = 4 waves (2x2). Reg-staged with register prefetch:
// next tile's global loads are issued before the MFMA block (overlap compute).
// EPI: 0 = store bf16; 1 = fp32 +bias; 2 = fp32 +bias+res(inplace); 3 = EPI2 + bf16 copy.
template<int EPI>
__global__ __launch_bounds__(256) void mfma_gemm(const u16* __restrict__ A,
                                                 const u16* __restrict__ Bt,
                                                 const float* __restrict__ bias,
                                                 float* __restrict__ fout,
                                                 u16* __restrict__ outb,
                                                 int K, int N) {
    __shared__ short As[128 * 32];
    __shared__ short Bs[128 * 32];
    int tid = threadIdx.x;
    int m0 = blockIdx.y * 128, n0 = blockIdx.x * 128;
    int wave = tid >> 6, lane = tid & 63;
    int wr = wave >> 1, wc = wave & 1;
    int l15 = lane & 15, l4 = lane >> 4;

    f32x4 zero4 = {0.f, 0.f, 0.f, 0.f};
    f32x4 acc[4][4];
#pragma unroll
    for (int i = 0; i < 4; i++)
#pragma unroll
        for (int j = 0; j < 4; j++) acc[i][j] = zero4;

    int srow = tid >> 1;
    int se   = (tid & 1) * 16;

    int4 ra0, ra1, rb0, rb1;
    {
        const u16* pa = A  + (size_t)(m0 + srow) * K + se;
        ra0 = *(const int4*)pa; ra1 = *(const int4*)(pa + 8);
        const u16* pb = Bt + (size_t)(n0 + srow) * K + se;
        rb0 = *(const int4*)pb; rb1 = *(const int4*)(pb + 8);
    }
    for (int kt = 0; kt < K; kt += 32) {
        __syncthreads();
        *(int4*)&As[srow * 32 + se]     = ra0;
        *(int4*)&As[srow * 32 + se + 8] = ra1;
        *(int4*)&Bs[srow * 32 + se]     = rb0;
        *(int4*)&Bs[srow * 32 + se + 8] = rb1;
        __syncthreads();
        int kn = kt + 32;
        if (kn < K) {
            const u16* pa = A  + (size_t)(m0 + srow) * K + kn + se;
            ra0 = *(const int4*)pa; ra1 = *(const int4*)(pa + 8);
            const u16* pb = Bt + (size_t)(n0 + srow) * K + kn + se;
            rb0 = *(const int4*)pb; rb1 = *(const int4*)(pb + 8);
        }
        bf16x8 af[4], bfr[4];
#pragma unroll
        for (int mi = 0; mi < 4; mi++)
            af[mi] = *(const bf16x8*)&As[(wr * 64 + mi * 16 + l15) * 32 + l4 * 8];
#pragma unroll
        for (int nj = 0; nj < 4; nj++)
            bfr[nj] = *(const bf16x8*)&Bs[(wc * 64 + nj * 16 + l15) * 32 + l4 * 8];
#pragma unroll
        for (int mi = 0; mi < 4; mi++)
#pragma unroll
            for (int nj = 0; nj < 4; nj++)
                acc[mi][nj] = __builtin_amdgcn_mfma_f32_16x16x32_bf16(af[mi], bfr[nj], acc[mi][nj], 0, 0, 0);
    }

#pragma unroll
    for (int mi = 0; mi < 4; mi++)
#pragma unroll
        for (int nj = 0; nj < 4; nj++)
#pragma unroll
            for (int r = 0; r < 4; r++) {
                int row = m0 + wr * 64 + mi * 16 + l4 * 4 + r;
                int col = n0 + wc * 64 + nj * 16 + l15;
                float v = acc[mi][nj][r];
                if constexpr (EPI == 0) {
                    outb[(size_t)row * N + col] = f2bf(v);
                } else {
                    v += bias[col];
                    if constexpr (EPI >= 2) v += fout[(size_t)row * N + col];
                    fout[(size_t)row * N + col] = v;
                    if constexpr (EPI == 3) outb[(size_t)row * N + col] = f2bf(v);
                }
            }
}

// ---------------- GEGLU MFMA: both halves of tn3 @ wg, fused exact GELU, bf16 out --------
__global__ __launch_bounds__(256) void geglu_mfma(const u16* __restrict__ A,
                                                  const u16* __restrict__ WgT,  // [4096][512]
                                                  const float* __restrict__ bg,
                                                  u16* __restrict__ ag) {
    __shared__ short As[128 * 32];
    __shared__ short Bs1[64 * 32];
    __shared__ short Bs2[64 * 32];
    const int K = 512;
    int tid = threadIdx.x;
    int m0 = blockIdx.y * 128, n0 = blockIdx.x * 64;
    int wave = tid >> 6, lane = tid & 63;
    int wr = wave >> 1, wc = wave & 1;
    int l15 = lane & 15, l4 = lane >> 4;

    f32x4 zero4 = {0.f, 0.f, 0.f, 0.f};
    f32x4 accA[4][2], accG[4][2];
#pragma unroll
    for (int i = 0; i < 4; i++) { accA[i][0] = zero4; accA[i][1] = zero4; accG[i][0] = zero4; accG[i][1] = zero4; }

    int srow = tid >> 1;
    int se   = (tid & 1) * 16;
    int brow = tid >> 2;
    int bqe  = (tid & 3) * 8;

    int4 ra0, ra1, rb1, rb2;
    {
        const u16* pa = A + (size_t)(m0 + srow) * K + se;
        ra0 = *(const int4*)pa; ra1 = *(const int4*)(pa + 8);
        rb1 = *(const int4*)(WgT + (size_t)(n0 + brow) * K + bqe);
        rb2 = *(const int4*)(WgT + (size_t)(2048 + n0 + brow) * K + bqe);
    }
    for (int kt = 0; kt < K; kt += 32) {
        __syncthreads();
        *(int4*)&As[srow * 32 + se]     = ra0;
        *(int4*)&As[srow * 32 + se + 8] = ra1;
        *(int4*)&Bs1[brow * 32 + bqe]   = rb1;
        *(int4*)&Bs2[brow * 32 + bqe]   = rb2;
        __syncthreads();
        int kn = kt + 32;
        if (kn < K) {
            const u16* pa = A + (size_t)(m0 + srow) * K + kn + se;
            ra0 = *(const int4*)pa; ra1 = *(const int4*)(pa + 8);
            rb1 = *(const int4*)(WgT + (size_t)(n0 + brow) * K + kn + bqe);
            rb2 = *(const int4*)(WgT + (size_t)(2048 + n0 + brow) * K + kn + bqe);
        }
        bf16x8 af[4], b1[2], b2[2];
#pragma unroll
        for (int mi = 0; mi < 4; mi++)
            af[mi] = *(const bf16x8*)&As[(wr * 64 + mi * 16 + l15) * 32 + l4 * 8];
#pragma unroll
        for (int nj = 0; nj < 2; nj++) {
            b1[nj] = *(const bf16x8*)&Bs1[(wc * 32 + nj * 16 + l15) * 32 + l4 * 8];
            b2[nj] = *(const bf16x8*)&Bs2[(wc * 32 + nj * 16 + l15) * 32 + l4 * 8];
        }
#pragma unroll
        for (int mi = 0; mi < 4; mi++)
#pragma unroll
            for (int nj = 0; nj < 2; nj++) {
                accA[mi][nj] = __builtin_amdgcn_mfma_f32_16x16x32_bf16(af[mi], b1[nj], accA[mi][nj], 0, 0, 0);
                accG[mi][nj] = __builtin_amdgcn_mfma_f32_16x16x32_bf16(af[mi], b2[nj], accG[mi][nj], 0, 0, 0);
            }
    }

#pragma unroll
    for (int mi = 0; mi < 4; mi++)
#pragma unroll
        for (int nj = 0; nj < 2; nj++)
#pragma unroll
            for (int r = 0; r < 4; r++) {
                int row = m0 + wr * 64 + mi * 16 + l4 * 4 + r;
                int col = n0 + wc * 32 + nj * 16 + l15;
                float a = accA[mi][nj][r] + bg[col];
                float g = accG[mi][nj][r] + bg[2048 + col];
                float ge = 0.5f * g * (1.0f + erff(g * 0.70710678118654752f));
                ag[(size_t)row * 2048 + col] = f2bf(a * ge);
            }
}

// ---------------- MFMA flash attention (XOR-swizzled LDS, __expf softmax) ----------------
__global__ __launch_bounds__(256) void flash_attn_mfma(const u16* __restrict__ q,
                                                       const u16* __restrict__ k,
                                                       const u16* __restrict__ vt,  // [b*8+h][64][1024]
                                                       u16* __restrict__ o) {
    __shared__ u16 Qs[64 * 64];
    __shared__ u16 Ks[64 * 64];
    __shared__ u16 Vt[64 * 64];
    __shared__ u16 Ps[64 * 64];
    const int tid = threadIdx.x;
    const int h = blockIdx.y, b = blockIdx.z;
    const int q0 = blockIdx.x * 64;
    const size_t hb  = (size_t)b * Ss * Cch + (size_t)h * DHh;
    const size_t vhb = ((size_t)(b * NHh + h) * DHh) * Ss;

    const int wq = tid >> 6;
    const int lane = tid & 63;
    const int l15 = lane & 15, l4 = lane >> 4;

    // stage Q (64x64), coalesced 32B/thread, swizzled dest
    {
        int r = tid >> 2, ch = (tid & 3) * 2;
        const u16* src = q + hb + (size_t)(q0 + r) * Cch + ch * 8;
        *(int4*)&Qs[swz(r, ch)]     = *(const int4*)src;
        *(int4*)&Qs[swz(r, ch + 1)] = *(const int4*)(src + 8);
    }

    f32x4 zero4 = {0.f, 0.f, 0.f, 0.f};
    f32x4 oacc[4];
    float m_[4], l_[4];
#pragma unroll
    for (int j = 0; j < 4; j++) oacc[j] = zero4;
#pragma unroll
    for (int r = 0; r < 4; r++) { m_[r] = -1e30f; l_[r] = 0.f; }

    for (int t0 = 0; t0 < Ss; t0 += 64) {
        __syncthreads();
        {
            int r = tid >> 2, ch = (tid & 3) * 2;
            const u16* ksrc = k + hb + (size_t)(t0 + r) * Cch + ch * 8;
            *(int4*)&Ks[swz(r, ch)]     = *(const int4*)ksrc;
            *(int4*)&Ks[swz(r, ch + 1)] = *(const int4*)(ksrc + 8);
            const u16* vsrc = vt + vhb + (size_t)r * Ss + t0 + ch * 8;
            *(int4*)&Vt[swz(r, ch)]     = *(const int4*)vsrc;
            *(int4*)&Vt[swz(r, ch + 1)] = *(const int4*)(vsrc + 8);
        }
        __syncthreads();

        // QK^T: wave's 16 q-rows x 64 t-cols
        f32x4 sacc[4];
#pragma unroll
        for (int j = 0; j < 4; j++) sacc[j] = zero4;
#pragma unroll
        for (int ks = 0; ks < 2; ks++) {
            bf16x8 aq = *(const bf16x8*)&Qs[swz(wq * 16 + l15, ks * 4 + l4)];
#pragma unroll
            for (int j = 0; j < 4; j++) {
                bf16x8 bk = *(const bf16x8*)&Ks[swz(j * 16 + l15, ks * 4 + l4)];
                sacc[j] = __builtin_amdgcn_mfma_f32_16x16x32_bf16(aq, bk, sacc[j], 0, 0, 0);
            }
        }

        // online softmax: lane holds rows l4*4+r, cols l15+16j
#pragma unroll
        for (int r = 0; r < 4; r++) {
            float s0 = sacc[0][r] * 0.125f;
            float s1 = sacc[1][r] * 0.125f;
            float s2 = sacc[2][r] * 0.125f;
            float s3 = sacc[3][r] * 0.125f;
            float tm = fmaxf(fmaxf(s0, s1), fmaxf(s2, s3));
            tm = fmaxf(tm, __shfl_xor(tm, 1));
            tm = fmaxf(tm, __shfl_xor(tm, 2));
            tm = fmaxf(tm, __shfl_xor(tm, 4));
            tm = fmaxf(tm, __shfl_xor(tm, 8));
            float nm = fmaxf(m_[r], tm);
            float sc = __expf(m_[r] - nm);
            m_[r] = nm;
            float p0 = __expf(s0 - nm), p1 = __expf(s1 - nm);
            float p2 = __expf(s2 - nm), p3 = __expf(s3 - nm);
            int row = wq * 16 + l4 * 4 + r;
            int rx = row & 7, base = row * 64, wi = l15 & 7, hi = l15 >> 3;
            Ps[base + (((0 + hi) ^ rx) * 8) + wi] = f2bf_rz(p0);
            Ps[base + (((2 + hi) ^ rx) * 8) + wi] = f2bf_rz(p1);
            Ps[base + (((4 + hi) ^ rx) * 8) + wi] = f2bf_rz(p2);
            Ps[base + (((6 + hi) ^ rx) * 8) + wi] = f2bf_rz(p3);
            float rs = p0 + p1 + p2 + p3;
            rs += __shfl_xor(rs, 1);
            rs += __shfl_xor(rs, 2);
            rs += __shfl_xor(rs, 4);
            rs += __shfl_xor(rs, 8);
            l_[r] = l_[r] * sc + rs;
#pragma unroll
            for (int j = 0; j < 4; j++) oacc[j][r] *= sc;
        }

        // PV: A=Ps (own rows, same-wave dep), Bt=Vt[d][t]
#pragma unroll
        for (int ks = 0; ks < 2; ks++) {
            bf16x8 pa = *(const bf16x8*)&Ps[swz(wq * 16 + l15, ks * 4 + l4)];
#pragma unroll
            for (int j = 0; j < 4; j++) {
                bf16x8 bv = *(const bf16x8*)&Vt[swz(j * 16 + l15, ks * 4 + l4)];
                oacc[j] = __builtin_amdgcn_mfma_f32_16x16x32_bf16(pa, bv, oacc[j], 0, 0, 0);
            }
        }
    }

    // finalize: O /= l, stage via Qs (wave-private rows, swizzled), coalesced store
#pragma unroll
    for (int r = 0; r < 4; r++) {
        float inv = 1.0f / l_[r];
        int row = wq * 16 + l4 * 4 + r;
        int rx = row & 7, base = row * 64, wi = l15 & 7, hi = l15 >> 3;
        Qs[base + (((0 + hi) ^ rx) * 8) + wi] = f2bf(oacc[0][r] * inv);
        Qs[base + (((2 + hi) ^ rx) * 8) + wi] = f2bf(oacc[1][r] * inv);
        Qs[base + (((4 + hi) ^ rx) * 8) + wi] = f2bf(oacc[2][r] * inv);
        Qs[base + (((6 + hi) ^ rx) * 8) + wi] = f2bf(oacc[3][r] * inv);
    }
    __syncthreads();
    {
        int r = tid >> 2, ch = (tid & 3) * 2;
        u16* dst = o + hb + (size_t)(q0 + r) * Cch + ch * 8;
        *(int4*)dst       = *(const int4*)&Qs[swz(r, ch)];
        *(int4*)(dst + 8) = *(const int4*)&Qs[swz(r, ch + 1)];
    }
}

// ---------------- final: out(B,C,S) = tmp(B,S,C)^T + x ----------------
__global__ __launch_bounds__(256) void final_out(const float* __restrict__ tmp,
                                                 const float* __restrict__ x,
                                                 float* __restrict__ outp) {
    __shared__ float tile[32][33];
    int b = blockIdx.z, c0 = blockIdx.y * 32, s0 = blockIdx.x * 32;
    int tx = threadIdx.x, ty = threadIdx.y;
#pragma unroll
    for (int i = 0; i < 4; i++) {
        int s = s0 + ty + i * 8;
        tile[ty + i * 8][tx] = tmp[((size_t)b * Ss + s) * Cch + c0 + tx];
    }
    __syncthreads();
#pragma unroll
    for (int i = 0; i < 4; i++) {
        int c = c0 + ty + i * 8;
        size_t idx = ((size_t)b * Cch + c) * Ss + s0 + tx;
        outp[idx] = tile[tx][ty + i * 8] + x[idx];
    }
}

extern "C" void kernel_launch(void* const* d_in, const int* in_sizes, int n_in,
                              void* d_out, int out_size, void* d_ws, size_t ws_size,
                              hipStream_t stream) {
    (void)in_sizes; (void)n_in; (void)out_size; (void)ws_size;
    const float* x      = (const float*)d_in[0];
    const float* gn_w   = (const float*)d_in[1];
    const float* gn_b   = (const float*)d_in[2];
    const float* pin_w  = (const float*)d_in[3];
    const float* pin_b  = (const float*)d_in[4];
    const float* ln1_w  = (const float*)d_in[5];
    const float* ln1_b  = (const float*)d_in[6];
    const float* wq     = (const float*)d_in[7];
    const float* wk     = (const float*)d_in[8];
    const float* wv     = (const float*)d_in[9];
    const float* wo     = (const float*)d_in[10];
    const float* bo     = (const float*)d_in[11];
    const float* ln3_w  = (const float*)d_in[12];
    const float* ln3_b  = (const float*)d_in[13];
    const float* wg     = (const float*)d_in[14];
    const float* bg     = (const float*)d_in[15];
    const float* wd     = (const float*)d_in[16];
    const float* bd     = (const float*)d_in[17];
    const float* pout_w = (const float*)d_in[18];
    const float* pout_b = (const float*)d_in[19];
    float* out = (float*)d_out;

    // ---- workspace layout (bytes) ----
    char* W = (char*)d_ws;
    float* t_f32   = (float*)W;                                   // 33.55 MB
    float* tmp_f32 = (float*)(W + 33554432);                      // 33.55 MB
    u16* qb    = (u16*)(W + 67108864);                            // 16.78 MB
    u16* kb    = qb + 8388608;
    u16* vb    = kb + 8388608;
    u16* attnb = vb + 8388608;
    u16* Xb    = attnb + 8388608;                                 // 16.78 MB
    float* stats = (float*)(W + 67108864 + 5ull * 16777216);      // 1 KB
    u16* wbase = (u16*)(W + 67108864 + 5ull * 16777216 + 1024);
    u16* pinB  = wbase;                 // 512*512  (already [N][K])
    u16* poutB = pinB  + 262144;
    u16* wqT   = poutB + 262144;        // [512][512] transposed
    u16* wkT   = wqT   + 262144;
    u16* wvT   = wkT   + 262144;
    u16* woT   = wvT   + 262144;
    u16* wgT   = woT   + 262144;        // [4096][512]
    u16* wdT   = wgT   + 2097152;       // [512][2048]
    u16* ag    = qb;                    // R x 2048 bf16, aliases qb..attnb (dead by then)
    u16* vtb   = (u16*)tmp_f32;         // V^T [b*8+h][64][1024], aliases tmp_f32 (dead until pout)

    dim3 tb(32, 8);

    // stats + weight prep
    gn_stats<<<128, 256, 0, stream>>>(x, stats);
    conv_bf16<<<256, 256, 0, stream>>>(pin_w,  pinB,  262144);
    conv_bf16<<<256, 256, 0, stream>>>(pout_w, poutB, 262144);
    convT_bf16<<<dim3(16, 16),  tb, 0, stream>>>(wq, wqT, 512, 512);
    convT_bf16<<<dim3(16, 16),  tb, 0, stream>>>(wk, wkT, 512, 512);
    convT_bf16<<<dim3(16, 16),  tb, 0, stream>>>(wv, wvT, 512, 512);
    convT_bf16<<<dim3(16, 16),  tb, 0, stream>>>(wo, woT, 512, 512);
    convT_bf16<<<dim3(128, 16), tb, 0, stream>>>(wg, wgT, 512, 4096);
    convT_bf16<<<dim3(16, 64),  tb, 0, stream>>>(wd, wdT, 2048, 512);

    // h = GN(x) transposed -> Xb (bf16)
    gn_apply_t_bf<<<dim3(32, 16, 16), tb, 0, stream>>>(x, stats, gn_w, gn_b, Xb);

    // t = h @ pin_w^T + pin_b -> t_f32
    mfma_gemm<1><<<dim3(4, 128), 256, 0, stream>>>(Xb, pinB, pin_b, t_f32, nullptr, 512, 512);
    // tn = ln1(t) -> Xb
    layer_norm_rows_bf<<<16384, 256, 0, stream>>>(t_f32, ln1_w, ln1_b, Xb);
    // q, k, v (bf16, coalesced)
    mfma_gemm<0><<<dim3(4, 128), 256, 0, stream>>>(Xb, wqT, nullptr, nullptr, qb, 512, 512);
    mfma_gemm<0><<<dim3(4, 128), 256, 0, stream>>>(Xb, wkT, nullptr, nullptr, kb, 512, 512);
    mfma_gemm<0><<<dim3(4, 128), 256, 0, stream>>>(Xb, wvT, nullptr, nullptr, vb, 512, 512);
    // per-head V transpose -> vtb
    vtrans<<<dim3(16, 8, 16), 256, 0, stream>>>(vb, vtb);
    // attention (MFMA) -> attnb (bf16)
    flash_attn_mfma<<<dim3(16, 8, 16), 256, 0, stream>>>(qb, kb, vtb, attnb);
    // t += attn @ wo + bo (in-place on t_f32)
    mfma_gemm<2><<<dim3(4, 128), 256, 0, stream>>>(attnb, woT, bo, t_f32, nullptr, 512, 512);
    // tn3 = ln3(t) -> Xb
    layer_norm_rows_bf<<<16384, 256, 0, stream>>>(t_f32, ln3_w, ln3_b, Xb);
    // ag = a * gelu(g) (bf16), aliases q/k/v/attn space
    geglu_mfma<<<dim3(32, 128), 256, 0, stream>>>(Xb, wgT, bg, ag);
    // t += ag @ wd + bd (in-place), plus bf16 copy of new t -> Xb
    mfma_gemm<3><<<dim3(4, 128), 256, 0, stream>>>(ag, wdT, bd, t_f32, Xb, 2048, 512);
    // tmp = t @ pout_w^T + pout_b -> tmp_f32
    mfma_gemm<1><<<dim3(4, 128), 256, 0, stream>>>(Xb, poutB, pout_b, tmp_f32, nullptr, 512, 512);
    // out = tmp^T + x
    final_out<<<dim3(32, 16, 16), tb, 0, stream>>>(tmp_f32, x, out);
}

// Round 17
// 546.744 us; speedup vs baseline: 1.0210x; 1.0158x over previous
//
#include <hip/hip_runtime.h>
#include <hip/hip_bf16.h>
#include <math.h>

typedef unsigned short u16;
typedef __attribute__((ext_vector_type(8))) short bf16x8;
typedef __attribute__((ext_vector_type(4))) float f32x4;

#define Bb 16
#define Cch 512
#define Ss 1024
#define NHh 8
#define DHh 64
#define CPG 64
#define EPSV 1e-5f
#define R_TOTAL (Bb*Ss)   // 16384

__device__ inline u16 f2bf(float f) {
    unsigned int u = __float_as_uint(f);
    unsigned int r = (u + 0x7fffu + ((u >> 16) & 1u)) >> 16;
    return (u16)r;
}
__device__ inline u16 f2bf_rz(float f) {           // truncate: 1 op, P in [0,1]
    return (u16)(__float_as_uint(f) >> 16);
}

// swizzled LDS offset (u16 units): row-stride 64, 16B chunk XOR'd by row&7
__device__ inline int swz(int row, int chunk) {
    return row * 64 + ((chunk ^ (row & 7)) * 8);
}

// ---------------- GroupNorm stats ----------------
__global__ __launch_bounds__(256) void gn_stats(const float* __restrict__ x,
                                                float* __restrict__ stats) {
    int bg = blockIdx.x;
    int b = bg >> 3, g = bg & 7;
    const float* base = x + ((size_t)b * Cch + (size_t)g * CPG) * Ss;
    float s = 0.f, ss = 0.f;
    for (int i = threadIdx.x; i < CPG * Ss; i += 256) {
        float v = base[i];
        s += v; ss += v * v;
    }
    for (int o = 32; o > 0; o >>= 1) { s += __shfl_down(s, o); ss += __shfl_down(ss, o); }
    __shared__ float red[2][4];
    int wid = threadIdx.x >> 6, lane = threadIdx.x & 63;
    if (lane == 0) { red[0][wid] = s; red[1][wid] = ss; }
    __syncthreads();
    if (threadIdx.x == 0) {
        float S1 = red[0][0] + red[0][1] + red[0][2] + red[0][3];
        float S2 = red[1][0] + red[1][1] + red[1][2] + red[1][3];
        const float inv_n = 1.0f / (CPG * Ss);
        float mu = S1 * inv_n;
        float var = S2 * inv_n - mu * mu;
        stats[bg * 2]     = mu;
        stats[bg * 2 + 1] = rsqrtf(var + EPSV);
    }
}

// ---------------- GroupNorm apply + transpose -> bf16 (B,S,C) ----------------
__global__ __launch_bounds__(256) void gn_apply_t_bf(const float* __restrict__ x,
                                                     const float* __restrict__ stats,
                                                     const float* __restrict__ gw,
                                                     const float* __restrict__ gb,
                                                     u16* __restrict__ ht) {
    __shared__ float tile[32][33];
    int b  = blockIdx.z;
    int c0 = blockIdx.y * 32;
    int s0 = blockIdx.x * 32;
    int tx = threadIdx.x, ty = threadIdx.y;
#pragma unroll
    for (int i = 0; i < 4; i++) {
        int c = c0 + ty + i * 8;
        int g = c >> 6;
        float mu = stats[(b * 8 + g) * 2];
        float rs = stats[(b * 8 + g) * 2 + 1];
        float v = x[((size_t)b * Cch + c) * Ss + s0 + tx];
        tile[ty + i * 8][tx] = (v - mu) * rs * gw[c] + gb[c];
    }
    __syncthreads();
#pragma unroll
    for (int i = 0; i < 4; i++) {
        int s = s0 + ty + i * 8;
        ht[((size_t)b * Ss + s) * Cch + c0 + tx] = f2bf(tile[tx][ty + i * 8]);
    }
}

// ---------------- fused fp32 -> bf16 convert for pin_w & pout_w ----------------
__global__ __launch_bounds__(256) void conv_bf16x2(const float* __restrict__ in0,
                                                   const float* __restrict__ in1,
                                                   u16* __restrict__ o0,
                                                   u16* __restrict__ o1) {
    for (int i = blockIdx.x * 256 + threadIdx.x; i < 524288; i += gridDim.x * 256) {
        if (i < 262144) o0[i] = f2bf(in0[i]);
        else            o1[i - 262144] = f2bf(in1[i - 262144]);
    }
}

// ---------------- transpose + convert: in (R x C) fp32 -> out (C x R) bf16 ----------------
__global__ __launch_bounds__(256) void convT_bf16(const float* __restrict__ in,
                                                  u16* __restrict__ outp, int R, int C) {
    __shared__ float tile[32][33];
    int c0 = blockIdx.x * 32, r0 = blockIdx.y * 32;
    int tx = threadIdx.x, ty = threadIdx.y;
#pragma unroll
    for (int i = 0; i < 4; i++)
        tile[ty + i * 8][tx] = in[(size_t)(r0 + ty + i * 8) * C + c0 + tx];
    __syncthreads();
#pragma unroll
    for (int i = 0; i < 4; i++)
        outp[(size_t)(c0 + ty + i * 8) * R + r0 + tx] = f2bf(tile[tx][ty + i * 8]);
}

// ---------------- fused 512x512 transpose+convert for wq/wk/wv/wo ----------------
__global__ __launch_bounds__(256) void convT4_bf16(const float* __restrict__ w0,
                                                   const float* __restrict__ w1,
                                                   const float* __restrict__ w2,
                                                   const float* __restrict__ w3,
                                                   u16* __restrict__ o0,
                                                   u16* __restrict__ o1,
                                                   u16* __restrict__ o2,
                                                   u16* __restrict__ o3) {
    __shared__ float tile[32][33];
    const float* in; u16* outp;
    switch (blockIdx.z) {
        case 0: in = w0; outp = o0; break;
        case 1: in = w1; outp = o1; break;
        case 2: in = w2; outp = o2; break;
        default: in = w3; outp = o3; break;
    }
    int c0 = blockIdx.x * 32, r0 = blockIdx.y * 32;
    int tx = threadIdx.x, ty = threadIdx.y;
#pragma unroll
    for (int i = 0; i < 4; i++)
        tile[ty + i * 8][tx] = in[(size_t)(r0 + ty + i * 8) * 512 + c0 + tx];
    __syncthreads();
#pragma unroll
    for (int i = 0; i < 4; i++)
        outp[(size_t)(c0 + ty + i * 8) * 512 + r0 + tx] = f2bf(tile[tx][ty + i * 8]);
}

// ---------------- per-head V transpose: vb [b][s][512] -> vt [(b*8+h)][64][1024] ----------
__global__ __launch_bounds__(256) void vtrans(const u16* __restrict__ in,
                                              u16* __restrict__ outp) {
    __shared__ u16 tile[64][66];
    int s0 = blockIdx.x * 64, h = blockIdx.y, b = blockIdx.z;
    const u16* src = in + ((size_t)b * Ss + s0) * Cch + h * 64;
    int r = threadIdx.x >> 3, c8 = (threadIdx.x & 7) * 8;
#pragma unroll
    for (int p = 0; p < 2; p++) {
        int rr = r + p * 32;
        *(int4*)&tile[rr][c8] = *(const int4*)&src[(size_t)rr * Cch + c8];
    }
    __syncthreads();
    u16* dst = outp + ((size_t)(b * 8 + h) * 64) * Ss + s0;
#pragma unroll
    for (int p = 0; p < 2; p++) {
        int d = r + p * 32;
        u16 vals[8];
#pragma unroll
        for (int e = 0; e < 8; e++) vals[e] = tile[c8 + e][d];
        *(int4*)&dst[(size_t)d * Ss + c8] = *(int4*)vals;
    }
}

// ---------------- LayerNorm rows (fp32 in, bf16 out) ----------------
__global__ __launch_bounds__(256) void layer_norm_rows_bf(const float* __restrict__ in,
                                                          const float* __restrict__ w,
                                                          const float* __restrict__ bb,
                                                          u16* __restrict__ outp) {
    int row = blockIdx.x;
    const float* p = in + (size_t)row * Cch;
    float v0 = p[threadIdx.x], v1 = p[threadIdx.x + 256];
    float s = v0 + v1, ss = v0 * v0 + v1 * v1;
    for (int o = 32; o > 0; o >>= 1) { s += __shfl_down(s, o); ss += __shfl_down(ss, o); }
    __shared__ float red[2][4];
    __shared__ float mu_s, rs_s;
    int wid = threadIdx.x >> 6, lane = threadIdx.x & 63;
    if (lane == 0) { red[0][wid] = s; red[1][wid] = ss; }
    __syncthreads();
    if (threadIdx.x == 0) {
        float S1 = red[0][0] + red[0][1] + red[0][2] + red[0][3];
        float S2 = red[1][0] + red[1][1] + red[1][2] + red[1][3];
        float mu = S1 * (1.0f / Cch);
        float var = S2 * (1.0f / Cch) - mu * mu;
        mu_s = mu; rs_s = rsqrtf(var + EPSV);
    }
    __syncthreads();
    float mu = mu_s, rs = rs_s;
    outp[(size_t)row * Cch + threadIdx.x]       = f2bf((v0 - mu) * rs * w[threadIdx.x] + bb[threadIdx.x]);
    outp[(size_t)row * Cch + threadIdx.x + 256] = f2bf((v1 - mu) * rs * w[threadIdx.x + 256] + bb[threadIdx.x + 256]);
}

// ---------------- MFMA GEMM: out(MxN) = A(MxK bf16) @ Bt(NxK bf16)^T ----------------
// 128x128 tile, BK=32, 256 thr = 4 waves (2x2). Reg-staged with register prefetch.
// EPI: 0 = bf16; 1 = fp32 +bias; 2 = fp32 +bias+res(inplace); 3 = EPI2 + bf16 copy;
//      5 = bf16 scaled by 0.125 (Q projection: pre-folds 1/sqrt(DH)).
template<int EPI>
__global__ __launch_bounds__(256) void mfma_gemm(const u16* __restrict__ A,
                                                 const u16* __restrict__ Bt,
                                                 const float* __restrict__ bias,
                                                 float* __restrict__ fout,
                                                 u16* __restrict__ outb,
                                                 int K, int N) {
    __shared__ short As[128 * 32];
    __shared__ short Bs[128 * 32];
    int tid = threadIdx.x;
    int m0 = blockIdx.y * 128, n0 = blockIdx.x * 128;
    int wave = tid >> 6, lane = tid & 63;
    int wr = wave >> 1, wc = wave & 1;
    int l15 = lane & 15, l4 = lane >> 4;

    f32x4 zero4 = {0.f, 0.f, 0.f, 0.f};
    f32x4 acc[4][4];
#pragma unroll
    for (int i = 0; i < 4; i++)
#pragma unroll
        for (int j = 0; j < 4; j++) acc[i][j] = zero4;

    int srow = tid >> 1;
    int se   = (tid & 1) * 16;

    int4 ra0, ra1, rb0, rb1;
    {
        const u16* pa = A  + (size_t)(m0 + srow) * K + se;
        ra0 = *(const int4*)pa; ra1 = *(const int4*)(pa + 8);
        const u16* pb = Bt + (size_t)(n0 + srow) * K + se;
        rb0 = *(const int4*)pb; rb1 = *(const int4*)(pb + 8);
    }
    for (int kt = 0; kt < K; kt += 32) {
        __syncthreads();
        *(int4*)&As[srow * 32 + se]     = ra0;
        *(int4*)&As[srow * 32 + se + 8] = ra1;
        *(int4*)&Bs[srow * 32 + se]     = rb0;
        *(int4*)&Bs[srow * 32 + se + 8] = rb1;
        __syncthreads();
        int kn = kt + 32;
        if (kn < K) {
            const u16* pa = A  + (size_t)(m0 + srow) * K + kn + se;
            ra0 = *(const int4*)pa; ra1 = *(const int4*)(pa + 8);
            const u16* pb = Bt + (size_t)(n0 + srow) * K + kn + se;
            rb0 = *(const int4*)pb; rb1 = *(const int4*)(pb + 8);
        }
        bf16x8 af[4], bfr[4];
#pragma unroll
        for (int mi = 0; mi < 4; mi++)
            af[mi] = *(const bf16x8*)&As[(wr * 64 + mi * 16 + l15) * 32 + l4 * 8];
#pragma unroll
        for (int nj = 0; nj < 4; nj++)
            bfr[nj] = *(const bf16x8*)&Bs[(wc * 64 + nj * 16 + l15) * 32 + l4 * 8];
#pragma unroll
        for (int mi = 0; mi < 4; mi++)
#pragma unroll
            for (int nj = 0; nj < 4; nj++)
                acc[mi][nj] = __builtin_amdgcn_mfma_f32_16x16x32_bf16(af[mi], bfr[nj], acc[mi][nj], 0, 0, 0);
    }

#pragma unroll
    for (int mi = 0; mi < 4; mi++)
#pragma unroll
        for (int nj = 0; nj < 4; nj++)
#pragma unroll
            for (int r = 0; r < 4; r++) {
                int row = m0 + wr * 64 + mi * 16 + l4 * 4 + r;
                int col = n0 + wc * 64 + nj * 16 + l15;
                float v = acc[mi][nj][r];
                if constexpr (EPI == 0) {
                    outb[(size_t)row * N + col] = f2bf(v);
                } else if constexpr (EPI == 5) {
                    outb[(size_t)row * N + col] = f2bf(v * 0.125f);
                } else {
                    v += bias[col];
                    if constexpr (EPI >= 2) v += fout[(size_t)row * N + col];
                    fout[(size_t)row * N + col] = v;
                    if constexpr (EPI == 3) outb[(size_t)row * N + col] = f2bf(v);
                }
            }
}

// ---------------- GEGLU MFMA: both halves of tn3 @ wg, fused exact GELU, bf16 out --------
__global__ __launch_bounds__(256) void geglu_mfma(const u16* __restrict__ A,
                                                  const u16* __restrict__ WgT,  // [4096][512]
                                                  const float* __restrict__ bg,
                                                  u16* __restrict__ ag) {
    __shared__ short As[128 * 32];
    __shared__ short Bs1[64 * 32];
    __shared__ short Bs2[64 * 32];
    const int K = 512;
    int tid = threadIdx.x;
    int m0 = blockIdx.y * 128, n0 = blockIdx.x * 64;
    int wave = tid >> 6, lane = tid & 63;
    int wr = wave >> 1, wc = wave & 1;
    int l15 = lane & 15, l4 = lane >> 4;

    f32x4 zero4 = {0.f, 0.f, 0.f, 0.f};
    f32x4 accA[4][2], accG[4][2];
#pragma unroll
    for (int i = 0; i < 4; i++) { accA[i][0] = zero4; accA[i][1] = zero4; accG[i][0] = zero4; accG[i][1] = zero4; }

    int srow = tid >> 1;
    int se   = (tid & 1) * 16;
    int brow = tid >> 2;
    int bqe  = (tid & 3) * 8;

    int4 ra0, ra1, rb1, rb2;
    {
        const u16* pa = A + (size_t)(m0 + srow) * K + se;
        ra0 = *(const int4*)pa; ra1 = *(const int4*)(pa + 8);
        rb1 = *(const int4*)(WgT + (size_t)(n0 + brow) * K + bqe);
        rb2 = *(const int4*)(WgT + (size_t)(2048 + n0 + brow) * K + bqe);
    }
    for (int kt = 0; kt < K; kt += 32) {
        __syncthreads();
        *(int4*)&As[srow * 32 + se]     = ra0;
        *(int4*)&As[srow * 32 + se + 8] = ra1;
        *(int4*)&Bs1[brow * 32 + bqe]   = rb1;
        *(int4*)&Bs2[brow * 32 + bqe]   = rb2;
        __syncthreads();
        int kn = kt + 32;
        if (kn < K) {
            const u16* pa = A + (size_t)(m0 + srow) * K + kn + se;
            ra0 = *(const int4*)pa; ra1 = *(const int4*)(pa + 8);
            rb1 = *(const int4*)(WgT + (size_t)(n0 + brow) * K + kn + bqe);
            rb2 = *(const int4*)(WgT + (size_t)(2048 + n0 + brow) * K + kn + bqe);
        }
        bf16x8 af[4], b1[2], b2[2];
#pragma unroll
        for (int mi = 0; mi < 4; mi++)
            af[mi] = *(const bf16x8*)&As[(wr * 64 + mi * 16 + l15) * 32 + l4 * 8];
#pragma unroll
        for (int nj = 0; nj < 2; nj++) {
            b1[nj] = *(const bf16x8*)&Bs1[(wc * 32 + nj * 16 + l15) * 32 + l4 * 8];
            b2[nj] = *(const bf16x8*)&Bs2[(wc * 32 + nj * 16 + l15) * 32 + l4 * 8];
        }
#pragma unroll
        for (int mi = 0; mi < 4; mi++)
#pragma unroll
            for (int nj = 0; nj < 2; nj++) {
                accA[mi][nj] = __builtin_amdgcn_mfma_f32_16x16x32_bf16(af[mi], b1[nj], accA[mi][nj], 0, 0, 0);
                accG[mi][nj] = __builtin_amdgcn_mfma_f32_16x16x32_bf16(af[mi], b2[nj], accG[mi][nj], 0, 0, 0);
            }
    }

#pragma unroll
    for (int mi = 0; mi < 4; mi++)
#pragma unroll
        for (int nj = 0; nj < 2; nj++)
#pragma unroll
            for (int r = 0; r < 4; r++) {
                int row = m0 + wr * 64 + mi * 16 + l4 * 4 + r;
                int col = n0 + wc * 32 + nj * 16 + l15;
                float a = accA[mi][nj][r] + bg[col];
                float g = accG[mi][nj][r] + bg[2048 + col];
                float ge = 0.5f * g * (1.0f + erff(g * 0.70710678118654752f));
                ag[(size_t)row * 2048 + col] = f2bf(a * ge);
            }
}

// ---------------- MFMA flash attention ----------------
// Q pre-scaled by 1/8 in projection (EPI5). Q frags hoisted to registers;
// Ps buffer reused for Q/O staging -> LDS 24 KB (6 blocks/CU cap).
// Defer-max: wave-uniform skip of rescale when no row's max grew (exact, THR=0).
__global__ __launch_bounds__(256) void flash_attn_mfma(const u16* __restrict__ q,
                                                       const u16* __restrict__ k,
                                                       const u16* __restrict__ vt,  // [b*8+h][64][1024]
                                                       u16* __restrict__ o) {
    __shared__ u16 Ps[64 * 64];      // Q staging -> P -> O staging
    __shared__ u16 Ks[64 * 64];
    __shared__ u16 Vt[64 * 64];
    const int tid = threadIdx.x;
    const int h = blockIdx.y, b = blockIdx.z;
    const int q0 = blockIdx.x * 64;
    const size_t hb  = (size_t)b * Ss * Cch + (size_t)h * DHh;
    const size_t vhb = ((size_t)(b * NHh + h) * DHh) * Ss;

    const int wq = tid >> 6;
    const int lane = tid & 63;
    const int l15 = lane & 15, l4 = lane >> 4;

    // stage Q (64x64), coalesced, swizzled dest (into Ps buffer)
    {
        int r = tid >> 2, ch = (tid & 3) * 2;
        const u16* src = q + hb + (size_t)(q0 + r) * Cch + ch * 8;
        *(int4*)&Ps[swz(r, ch)]     = *(const int4*)src;
        *(int4*)&Ps[swz(r, ch + 1)] = *(const int4*)(src + 8);
    }
    __syncthreads();
    // hoist Q fragments to registers (wave-private rows; Ps reusable after this)
    bf16x8 aq[2];
    aq[0] = *(const bf16x8*)&Ps[swz(wq * 16 + l15, 0 * 4 + l4)];
    aq[1] = *(const bf16x8*)&Ps[swz(wq * 16 + l15, 1 * 4 + l4)];

    f32x4 zero4 = {0.f, 0.f, 0.f, 0.f};
    f32x4 oacc[4];
    float m_[4], l_[4];
#pragma unroll
    for (int j = 0; j < 4; j++) oacc[j] = zero4;
#pragma unroll
    for (int r = 0; r < 4; r++) { m_[r] = -1e30f; l_[r] = 0.f; }

    for (int t0 = 0; t0 < Ss; t0 += 64) {
        __syncthreads();
        {
            int r = tid >> 2, ch = (tid & 3) * 2;
            const u16* ksrc = k + hb + (size_t)(t0 + r) * Cch + ch * 8;
            *(int4*)&Ks[swz(r, ch)]     = *(const int4*)ksrc;
            *(int4*)&Ks[swz(r, ch + 1)] = *(const int4*)(ksrc + 8);
            const u16* vsrc = vt + vhb + (size_t)r * Ss + t0 + ch * 8;
            *(int4*)&Vt[swz(r, ch)]     = *(const int4*)vsrc;
            *(int4*)&Vt[swz(r, ch + 1)] = *(const int4*)(vsrc + 8);
        }
        __syncthreads();

        // QK^T (already scaled): wave's 16 q-rows x 64 t-cols
        f32x4 sacc[4];
#pragma unroll
        for (int j = 0; j < 4; j++) sacc[j] = zero4;
#pragma unroll
        for (int ks = 0; ks < 2; ks++) {
#pragma unroll
            for (int j = 0; j < 4; j++) {
                bf16x8 bk = *(const bf16x8*)&Ks[swz(j * 16 + l15, ks * 4 + l4)];
                sacc[j] = __builtin_amdgcn_mfma_f32_16x16x32_bf16(aq[ks], bk, sacc[j], 0, 0, 0);
            }
        }

        // tile max per row + defer-max decision (wave-uniform)
        float tmv[4];
        int grew = 0;
#pragma unroll
        for (int r = 0; r < 4; r++) {
            float tm = fmaxf(fmaxf(sacc[0][r], sacc[1][r]), fmaxf(sacc[2][r], sacc[3][r]));
            tm = fmaxf(tm, __shfl_xor(tm, 1));
            tm = fmaxf(tm, __shfl_xor(tm, 2));
            tm = fmaxf(tm, __shfl_xor(tm, 4));
            tm = fmaxf(tm, __shfl_xor(tm, 8));
            tmv[r] = tm;
            grew |= (tm > m_[r]);
        }

        if (__any(grew)) {
            // heavy path: rescale O and l
#pragma unroll
            for (int r = 0; r < 4; r++) {
                float nm = fmaxf(m_[r], tmv[r]);
                float sc = __expf(m_[r] - nm);
                m_[r] = nm;
                float p0 = __expf(sacc[0][r] - nm), p1 = __expf(sacc[1][r] - nm);
                float p2 = __expf(sacc[2][r] - nm), p3 = __expf(sacc[3][r] - nm);
                int row = wq * 16 + l4 * 4 + r;
                int rx = row & 7, base = row * 64, wi = l15 & 7, hi = l15 >> 3;
                Ps[base + (((0 + hi) ^ rx) * 8) + wi] = f2bf_rz(p0);
                Ps[base + (((2 + hi) ^ rx) * 8) + wi] = f2bf_rz(p1);
                Ps[base + (((4 + hi) ^ rx) * 8) + wi] = f2bf_rz(p2);
                Ps[base + (((6 + hi) ^ rx) * 8) + wi] = f2bf_rz(p3);
                float rs = p0 + p1 + p2 + p3;
                rs += __shfl_xor(rs, 1);
                rs += __shfl_xor(rs, 2);
                rs += __shfl_xor(rs, 4);
                rs += __shfl_xor(rs, 8);
                l_[r] = l_[r] * sc + rs;
#pragma unroll
                for (int j = 0; j < 4; j++) oacc[j][r] *= sc;
            }
        } else {
            // light path: m unchanged, no rescale
#pragma unroll
            for (int r = 0; r < 4; r++) {
                float nm = m_[r];
                float p0 = __expf(sacc[0][r] - nm), p1 = __expf(sacc[1][r] - nm);
                float p2 = __expf(sacc[2][r] - nm), p3 = __expf(sacc[3][r] - nm);
                int row = wq * 16 + l4 * 4 + r;
                int rx = row & 7, base = row * 64, wi = l15 & 7, hi = l15 >> 3;
                Ps[base + (((0 + hi) ^ rx) * 8) + wi] = f2bf_rz(p0);
                Ps[base + (((2 + hi) ^ rx) * 8) + wi] = f2bf_rz(p1);
                Ps[base + (((4 + hi) ^ rx) * 8) + wi] = f2bf_rz(p2);
                Ps[base + (((6 + hi) ^ rx) * 8) + wi] = f2bf_rz(p3);
                float rs = p0 + p1 + p2 + p3;
                rs += __shfl_xor(rs, 1);
                rs += __shfl_xor(rs, 2);
                rs += __shfl_xor(rs, 4);
                rs += __shfl_xor(rs, 8);
                l_[r] += rs;
            }
        }

        // PV: A=Ps (own rows, same-wave dep), Bt=Vt[d][t]
#pragma unroll
        for (int ks = 0; ks < 2; ks++) {
            bf16x8 pa = *(const bf16x8*)&Ps[swz(wq * 16 + l15, ks * 4 + l4)];
#pragma unroll
            for (int j = 0; j < 4; j++) {
                bf16x8 bv = *(const bf16x8*)&Vt[swz(j * 16 + l15, ks * 4 + l4)];
                oacc[j] = __builtin_amdgcn_mfma_f32_16x16x32_bf16(pa, bv, oacc[j], 0, 0, 0);
            }
        }
    }

    // finalize: O /= l, stage via Ps (wave-private rows, swizzled), coalesced store
#pragma unroll
    for (int r = 0; r < 4; r++) {
        float inv = 1.0f / l_[r];
        int row = wq * 16 + l4 * 4 + r;
        int rx = row & 7, base = row * 64, wi = l15 & 7, hi = l15 >> 3;
        Ps[base + (((0 + hi) ^ rx) * 8) + wi] = f2bf(oacc[0][r] * inv);
        Ps[base + (((2 + hi) ^ rx) * 8) + wi] = f2bf(oacc[1][r] * inv);
        Ps[base + (((4 + hi) ^ rx) * 8) + wi] = f2bf(oacc[2][r] * inv);
        Ps[base + (((6 + hi) ^ rx) * 8) + wi] = f2bf(oacc[3][r] * inv);
    }
    __syncthreads();
    {
        int r = tid >> 2, ch = (tid & 3) * 2;
        u16* dst = o + hb + (size_t)(q0 + r) * Cch + ch * 8;
        *(int4*)dst       = *(const int4*)&Ps[swz(r, ch)];
        *(int4*)(dst + 8) = *(const int4*)&Ps[swz(r, ch + 1)];
    }
}

// ---------------- final: out(B,C,S) = tmp(B,S,C)^T + x ----------------
__global__ __launch_bounds__(256) void final_out(const float* __restrict__ tmp,
                                                 const float* __restrict__ x,
                                                 float* __restrict__ outp) {
    __shared__ float tile[32][33];
    int b = blockIdx.z, c0 = blockIdx.y * 32, s0 = blockIdx.x * 32;
    int tx = threadIdx.x, ty = threadIdx.y;
#pragma unroll
    for (int i = 0; i < 4; i++) {
        int s = s0 + ty + i * 8;
        tile[ty + i * 8][tx] = tmp[((size_t)b * Ss + s) * Cch + c0 + tx];
    }
    __syncthreads();
#pragma unroll
    for (int i = 0; i < 4; i++) {
        int c = c0 + ty + i * 8;
        size_t idx = ((size_t)b * Cch + c) * Ss + s0 + tx;
        outp[idx] = tile[tx][ty + i * 8] + x[idx];
    }
}

extern "C" void kernel_launch(void* const* d_in, const int* in_sizes, int n_in,
                              void* d_out, int out_size, void* d_ws, size_t ws_size,
                              hipStream_t stream) {
    (void)in_sizes; (void)n_in; (void)out_size; (void)ws_size;
    const float* x      = (const float*)d_in[0];
    const float* gn_w   = (const float*)d_in[1];
    const float* gn_b   = (const float*)d_in[2];
    const float* pin_w  = (const float*)d_in[3];
    const float* pin_b  = (const float*)d_in[4];
    const float* ln1_w  = (const float*)d_in[5];
    const float* ln1_b  = (const float*)d_in[6];
    const float* wq     = (const float*)d_in[7];
    const float* wk     = (const float*)d_in[8];
    const float* wv     = (const float*)d_in[9];
    const float* wo     = (const float*)d_in[10];
    const float* bo     = (const float*)d_in[11];
    const float* ln3_w  = (const float*)d_in[12];
    const float* ln3_b  = (const float*)d_in[13];
    const float* wg     = (const float*)d_in[14];
    const float* bg     = (const float*)d_in[15];
    const float* wd     = (const float*)d_in[16];
    const float* bd     = (const float*)d_in[17];
    const float* pout_w = (const float*)d_in[18];
    const float* pout_b = (const float*)d_in[19];
    float* out = (float*)d_out;

    // ---- workspace layout (bytes) ----
    char* W = (char*)d_ws;
    float* t_f32   = (float*)W;                                   // 33.55 MB
    float* tmp_f32 = (float*)(W + 33554432);                      // 33.55 MB
    u16* qb    = (u16*)(W + 67108864);                            // 16.78 MB
    u16* kb    = qb + 8388608;
    u16* vb    = kb + 8388608;
    u16* attnb = vb + 8388608;
    u16* Xb    = attnb + 8388608;                                 // 16.78 MB
    float* stats = (float*)(W + 67108864 + 5ull * 16777216);      // 1 KB
    u16* wbase = (u16*)(W + 67108864 + 5ull * 16777216 + 1024);
    u16* pinB  = wbase;                 // 512*512  (already [N][K])
    u16* poutB = pinB  + 262144;
    u16* wqT   = poutB + 262144;        // [512][512] transposed
    u16* wkT   = wqT   + 262144;
    u16* wvT   = wkT   + 262144;
    u16* woT   = wvT   + 262144;
    u16* wgT   = woT   + 262144;        // [4096][512]
    u16* wdT   = wgT   + 2097152;       // [512][2048]
    u16* ag    = qb;                    // R x 2048 bf16, aliases qb..attnb (dead by then)
    u16* vtb   = (u16*)tmp_f32;         // V^T [b*8+h][64][1024], aliases tmp_f32 (dead until pout)

    dim3 tb(32, 8);

    // stats + weight prep (fused launches)
    gn_stats<<<128, 256, 0, stream>>>(x, stats);
    conv_bf16x2<<<512, 256, 0, stream>>>(pin_w, pout_w, pinB, poutB);
    convT4_bf16<<<dim3(16, 16, 4), tb, 0, stream>>>(wq, wk, wv, wo, wqT, wkT, wvT, woT);
    convT_bf16<<<dim3(128, 16), tb, 0, stream>>>(wg, wgT, 512, 4096);
    convT_bf16<<<dim3(16, 64),  tb, 0, stream>>>(wd, wdT, 2048, 512);

    // h = GN(x) transposed -> Xb (bf16)
    gn_apply_t_bf<<<dim3(32, 16, 16), tb, 0, stream>>>(x, stats, gn_w, gn_b, Xb);

    // t = h @ pin_w^T + pin_b -> t_f32
    mfma_gemm<1><<<dim3(4, 128), 256, 0, stream>>>(Xb, pinB, pin_b, t_f32, nullptr, 512, 512);
    // tn = ln1(t) -> Xb
    layer_norm_rows_bf<<<16384, 256, 0, stream>>>(t_f32, ln1_w, ln1_b, Xb);
    // q (pre-scaled by 1/8), k, v (bf16, coalesced)
    mfma_gemm<5><<<dim3(4, 128), 256, 0, stream>>>(Xb, wqT, nullptr, nullptr, qb, 512, 512);
    mfma_gemm<0><<<dim3(4, 128), 256, 0, stream>>>(Xb, wkT, nullptr, nullptr, kb, 512, 512);
    mfma_gemm<0><<<dim3(4, 128), 256, 0, stream>>>(Xb, wvT, nullptr, nullptr, vb, 512, 512);
    // per-head V transpose -> vtb
    vtrans<<<dim3(16, 8, 16), 256, 0, stream>>>(vb, vtb);
    // attention (MFMA) -> attnb (bf16)
    flash_attn_mfma<<<dim3(16, 8, 16), 256, 0, stream>>>(qb, kb, vtb, attnb);
    // t += attn @ wo + bo (in-place on t_f32)
    mfma_gemm<2><<<dim3(4, 128), 256, 0, stream>>>(attnb, woT, bo, t_f32, nullptr, 512, 512);
    // tn3 = ln3(t) -> Xb
    layer_norm_rows_bf<<<16384, 256, 0, stream>>>(t_f32, ln3_w, ln3_b, Xb);
    // ag = a * gelu(g) (bf16), aliases q/k/v/attn space
    geglu_mfma<<<dim3(32, 128), 256, 0, stream>>>(Xb, wgT, bg, ag);
    // t += ag @ wd + bd (in-place), plus bf16 copy of new t -> Xb
    mfma_gemm<3><<<dim3(4, 128), 256, 0, stream>>>(ag, wdT, bd, t_f32, Xb, 2048, 512);
    // tmp = t @ pout_w^T + pout_b -> tmp_f32
    mfma_gemm<1><<<dim3(4, 128), 256, 0, stream>>>(Xb, poutB, pout_b, tmp_f32, nullptr, 512, 512);
    // out = tmp^T + x
    final_out<<<dim3(32, 16, 16), tb, 0, stream>>>(tmp_f32, x, out);
}

// Round 18
// 506.256 us; speedup vs baseline: 1.1027x; 1.0800x over previous
//
#include <hip/hip_runtime.h>
#include <hip/hip_bf16.h>
#include <math.h>

typedef unsigned short u16;
typedef __attribute__((ext_vector_type(8))) short bf16x8;
typedef __attribute__((ext_vector_type(4))) float f32x4;

#define Bb 16
#define Cch 512
#define Ss 1024
#define NHh 8
#define DHh 64
#define CPG 64
#define EPSV 1e-5f
#define R_TOTAL (Bb*Ss)   // 16384
#define QSCL 0.18033688011112042f   // 0.125 * log2(e)

__device__ inline u16 f2bf(float f) {
    unsigned int u = __float_as_uint(f);
    unsigned int r = (u + 0x7fffu + ((u >> 16) & 1u)) >> 16;
    return (u16)r;
}
__device__ inline u16 f2bf_rz(float f) { return (u16)(__float_as_uint(f) >> 16); }
__device__ inline float bf2f(u16 v) { return __uint_as_float((unsigned)v << 16); }
__device__ inline float exp2_raw(float x) {
    float r; asm("v_exp_f32 %0, %1" : "=v"(r) : "v"(x)); return r;
}

// swizzled LDS offset (u16 units): row-stride 64, 16B chunk XOR'd by row&7
__device__ inline int swz(int row, int chunk) {
    return row * 64 + ((chunk ^ (row & 7)) * 8);
}

// ---------------- GroupNorm stats ----------------
__global__ __launch_bounds__(256) void gn_stats(const float* __restrict__ x,
                                                float* __restrict__ stats) {
    int bg = blockIdx.x;
    int b = bg >> 3, g = bg & 7;
    const float* base = x + ((size_t)b * Cch + (size_t)g * CPG) * Ss;
    float s = 0.f, ss = 0.f;
    for (int i = threadIdx.x; i < CPG * Ss; i += 256) {
        float v = base[i];
        s += v; ss += v * v;
    }
    for (int o = 32; o > 0; o >>= 1) { s += __shfl_down(s, o); ss += __shfl_down(ss, o); }
    __shared__ float red[2][4];
    int wid = threadIdx.x >> 6, lane = threadIdx.x & 63;
    if (lane == 0) { red[0][wid] = s; red[1][wid] = ss; }
    __syncthreads();
    if (threadIdx.x == 0) {
        float S1 = red[0][0] + red[0][1] + red[0][2] + red[0][3];
        float S2 = red[1][0] + red[1][1] + red[1][2] + red[1][3];
        const float inv_n = 1.0f / (CPG * Ss);
        float mu = S1 * inv_n;
        float var = S2 * inv_n - mu * mu;
        stats[bg * 2]     = mu;
        stats[bg * 2 + 1] = rsqrtf(var + EPSV);
    }
}

// ---------------- GroupNorm apply + transpose -> bf16 (B,S,C) ----------------
__global__ __launch_bounds__(256) void gn_apply_t_bf(const float* __restrict__ x,
                                                     const float* __restrict__ stats,
                                                     const float* __restrict__ gw,
                                                     const float* __restrict__ gb,
                                                     u16* __restrict__ ht) {
    __shared__ float tile[32][33];
    int b  = blockIdx.z;
    int c0 = blockIdx.y * 32;
    int s0 = blockIdx.x * 32;
    int tx = threadIdx.x, ty = threadIdx.y;
#pragma unroll
    for (int i = 0; i < 4; i++) {
        int c = c0 + ty + i * 8;
        int g = c >> 6;
        float mu = stats[(b * 8 + g) * 2];
        float rs = stats[(b * 8 + g) * 2 + 1];
        float v = x[((size_t)b * Cch + c) * Ss + s0 + tx];
        tile[ty + i * 8][tx] = (v - mu) * rs * gw[c] + gb[c];
    }
    __syncthreads();
#pragma unroll
    for (int i = 0; i < 4; i++) {
        int s = s0 + ty + i * 8;
        ht[((size_t)b * Ss + s) * Cch + c0 + tx] = f2bf(tile[tx][ty + i * 8]);
    }
}

// ---------------- fused fp32 -> bf16 convert for pin_w & pout_w ----------------
__global__ __launch_bounds__(256) void conv_bf16x2(const float* __restrict__ in0,
                                                   const float* __restrict__ in1,
                                                   u16* __restrict__ o0,
                                                   u16* __restrict__ o1) {
    for (int i = blockIdx.x * 256 + threadIdx.x; i < 524288; i += gridDim.x * 256) {
        if (i < 262144) o0[i] = f2bf(in0[i]);
        else            o1[i - 262144] = f2bf(in1[i - 262144]);
    }
}

// ---------------- transpose + convert: in (R x C) fp32 -> out (C x R) bf16 ----------------
__global__ __launch_bounds__(256) void convT_bf16(const float* __restrict__ in,
                                                  u16* __restrict__ outp, int R, int C) {
    __shared__ float tile[32][33];
    int c0 = blockIdx.x * 32, r0 = blockIdx.y * 32;
    int tx = threadIdx.x, ty = threadIdx.y;
#pragma unroll
    for (int i = 0; i < 4; i++)
        tile[ty + i * 8][tx] = in[(size_t)(r0 + ty + i * 8) * C + c0 + tx];
    __syncthreads();
#pragma unroll
    for (int i = 0; i < 4; i++)
        outp[(size_t)(c0 + ty + i * 8) * R + r0 + tx] = f2bf(tile[tx][ty + i * 8]);
}

// ---------------- fused 512x512 transpose+convert for wq(scaled)/wk/wv/wo ----------------
__global__ __launch_bounds__(256) void convT4_bf16(const float* __restrict__ w0,
                                                   const float* __restrict__ w1,
                                                   const float* __restrict__ w2,
                                                   const float* __restrict__ w3,
                                                   u16* __restrict__ o0,
                                                   u16* __restrict__ o1,
                                                   u16* __restrict__ o2,
                                                   u16* __restrict__ o3) {
    __shared__ float tile[32][33];
    const float* in; u16* outp; float scl = 1.0f;
    switch (blockIdx.z) {
        case 0: in = w0; outp = o0; scl = QSCL; break;
        case 1: in = w1; outp = o1; break;
        case 2: in = w2; outp = o2; break;
        default: in = w3; outp = o3; break;
    }
    int c0 = blockIdx.x * 32, r0 = blockIdx.y * 32;
    int tx = threadIdx.x, ty = threadIdx.y;
#pragma unroll
    for (int i = 0; i < 4; i++)
        tile[ty + i * 8][tx] = in[(size_t)(r0 + ty + i * 8) * 512 + c0 + tx] * scl;
    __syncthreads();
#pragma unroll
    for (int i = 0; i < 4; i++)
        outp[(size_t)(c0 + ty + i * 8) * 512 + r0 + tx] = f2bf(tile[tx][ty + i * 8]);
}

// ---------------- per-head V transpose: vb [b][s][512] -> vt [(b*8+h)][64][1024] ----------
__global__ __launch_bounds__(256) void vtrans(const u16* __restrict__ in,
                                              u16* __restrict__ outp) {
    __shared__ u16 tile[64][66];
    int s0 = blockIdx.x * 64, h = blockIdx.y, b = blockIdx.z;
    const u16* src = in + ((size_t)b * Ss + s0) * Cch + h * 64;
    int r = threadIdx.x >> 3, c8 = (threadIdx.x & 7) * 8;
#pragma unroll
    for (int p = 0; p < 2; p++) {
        int rr = r + p * 32;
        *(int4*)&tile[rr][c8] = *(const int4*)&src[(size_t)rr * Cch + c8];
    }
    __syncthreads();
    u16* dst = outp + ((size_t)(b * 8 + h) * 64) * Ss + s0;
#pragma unroll
    for (int p = 0; p < 2; p++) {
        int d = r + p * 32;
        u16 vals[8];
#pragma unroll
        for (int e = 0; e < 8; e++) vals[e] = tile[c8 + e][d];
        *(int4*)&dst[(size_t)d * Ss + c8] = *(int4*)vals;
    }
}

// ---------------- LayerNorm rows (bf16 in, bf16 out) ----------------
__global__ __launch_bounds__(256) void layer_norm_rows_bf(const u16* __restrict__ in,
                                                          const float* __restrict__ w,
                                                          const float* __restrict__ bb,
                                                          u16* __restrict__ outp) {
    int row = blockIdx.x;
    const u16* p = in + (size_t)row * Cch;
    int i0 = threadIdx.x * 2;
    ushort2 u = *(const ushort2*)&p[i0];
    float v0 = bf2f(u.x), v1 = bf2f(u.y);
    float s = v0 + v1, ss = v0 * v0 + v1 * v1;
    for (int o = 32; o > 0; o >>= 1) { s += __shfl_down(s, o); ss += __shfl_down(ss, o); }
    __shared__ float red[2][4];
    __shared__ float mu_s, rs_s;
    int wid = threadIdx.x >> 6, lane = threadIdx.x & 63;
    if (lane == 0) { red[0][wid] = s; red[1][wid] = ss; }
    __syncthreads();
    if (threadIdx.x == 0) {
        float S1 = red[0][0] + red[0][1] + red[0][2] + red[0][3];
        float S2 = red[1][0] + red[1][1] + red[1][2] + red[1][3];
        float mu = S1 * (1.0f / Cch);
        float var = S2 * (1.0f / Cch) - mu * mu;
        mu_s = mu; rs_s = rsqrtf(var + EPSV);
    }
    __syncthreads();
    float mu = mu_s, rs = rs_s;
    outp[(size_t)row * Cch + i0]     = f2bf((v0 - mu) * rs * w[i0] + bb[i0]);
    outp[(size_t)row * Cch + i0 + 1] = f2bf((v1 - mu) * rs * w[i0 + 1] + bb[i0 + 1]);
}

// ---------------- MFMA GEMM: out(MxN) = A(MxK bf16) @ Bt(NxK bf16)^T ----------------
// 128x128 tile, BK=32, 256 thr = 4 waves (2x2). Reg-staged with register prefetch.
// EPI: 0 = bf16; 1 = fp32 +bias; 6 = bf16 +bias; 7 = bf16 +bias + bf16 residual in-place;
//      8 = bf16 routed qkv (outb base = qb; col>>9 selects q/k/v slot, 8388608 apart).
template<int EPI>
__global__ __launch_bounds__(256) void mfma_gemm(const u16* __restrict__ A,
                                                 const u16* __restrict__ Bt,
                                                 const float* __restrict__ bias,
                                                 float* __restrict__ fout,
                                                 u16* __restrict__ outb,
                                                 int K, int N) {
    __shared__ short As[128 * 32];
    __shared__ short Bs[128 * 32];
    int tid = threadIdx.x;
    int m0 = blockIdx.y * 128, n0 = blockIdx.x * 128;
    int wave = tid >> 6, lane = tid & 63;
    int wr = wave >> 1, wc = wave & 1;
    int l15 = lane & 15, l4 = lane >> 4;

    f32x4 zero4 = {0.f, 0.f, 0.f, 0.f};
    f32x4 acc[4][4];
#pragma unroll
    for (int i = 0; i < 4; i++)
#pragma unroll
        for (int j = 0; j < 4; j++) acc[i][j] = zero4;

    int srow = tid >> 1;
    int se   = (tid & 1) * 16;

    int4 ra0, ra1, rb0, rb1;
    {
        const u16* pa = A  + (size_t)(m0 + srow) * K + se;
        ra0 = *(const int4*)pa; ra1 = *(const int4*)(pa + 8);
        const u16* pb = Bt + (size_t)(n0 + srow) * K + se;
        rb0 = *(const int4*)pb; rb1 = *(const int4*)(pb + 8);
    }
    for (int kt = 0; kt < K; kt += 32) {
        __syncthreads();
        *(int4*)&As[srow * 32 + se]     = ra0;
        *(int4*)&As[srow * 32 + se + 8] = ra1;
        *(int4*)&Bs[srow * 32 + se]     = rb0;
        *(int4*)&Bs[srow * 32 + se + 8] = rb1;
        __syncthreads();
        int kn = kt + 32;
        if (kn < K) {
            const u16* pa = A  + (size_t)(m0 + srow) * K + kn + se;
            ra0 = *(const int4*)pa; ra1 = *(const int4*)(pa + 8);
            const u16* pb = Bt + (size_t)(n0 + srow) * K + kn + se;
            rb0 = *(const int4*)pb; rb1 = *(const int4*)(pb + 8);
        }
        bf16x8 af[4], bfr[4];
#pragma unroll
        for (int mi = 0; mi < 4; mi++)
            af[mi] = *(const bf16x8*)&As[(wr * 64 + mi * 16 + l15) * 32 + l4 * 8];
#pragma unroll
        for (int nj = 0; nj < 4; nj++)
            bfr[nj] = *(const bf16x8*)&Bs[(wc * 64 + nj * 16 + l15) * 32 + l4 * 8];
#pragma unroll
        for (int mi = 0; mi < 4; mi++)
#pragma unroll
            for (int nj = 0; nj < 4; nj++)
                acc[mi][nj] = __builtin_amdgcn_mfma_f32_16x16x32_bf16(af[mi], bfr[nj], acc[mi][nj], 0, 0, 0);
    }

#pragma unroll
    for (int mi = 0; mi < 4; mi++)
#pragma unroll
        for (int nj = 0; nj < 4; nj++)
#pragma unroll
            for (int r = 0; r < 4; r++) {
                int row = m0 + wr * 64 + mi * 16 + l4 * 4 + r;
                int col = n0 + wc * 64 + nj * 16 + l15;
                float v = acc[mi][nj][r];
                if constexpr (EPI == 0) {
                    outb[(size_t)row * N + col] = f2bf(v);
                } else if constexpr (EPI == 1) {
                    fout[(size_t)row * N + col] = v + bias[col];
                } else if constexpr (EPI == 6) {
                    outb[(size_t)row * N + col] = f2bf(v + bias[col]);
                } else if constexpr (EPI == 7) {
                    size_t idx = (size_t)row * N + col;
                    v += bias[col] + bf2f(outb[idx]);
                    outb[idx] = f2bf(v);
                } else if constexpr (EPI == 8) {
                    size_t idx = (size_t)(col >> 9) * 8388608 + (size_t)row * 512 + (col & 511);
                    outb[idx] = f2bf(v);
                }
            }
}

// ---------------- GEGLU MFMA: both halves of tn3 @ wg, fused exact GELU, bf16 out --------
__global__ __launch_bounds__(256) void geglu_mfma(const u16* __restrict__ A,
                                                  const u16* __restrict__ WgT,  // [4096][512]
                                                  const float* __restrict__ bg,
                                                  u16* __restrict__ ag) {
    __shared__ short As[128 * 32];
    __shared__ short Bs1[64 * 32];
    __shared__ short Bs2[64 * 32];
    const int K = 512;
    int tid = threadIdx.x;
    int m0 = blockIdx.y * 128, n0 = blockIdx.x * 64;
    int wave = tid >> 6, lane = tid & 63;
    int wr = wave >> 1, wc = wave & 1;
    int l15 = lane & 15, l4 = lane >> 4;

    f32x4 zero4 = {0.f, 0.f, 0.f, 0.f};
    f32x4 accA[4][2], accG[4][2];
#pragma unroll
    for (int i = 0; i < 4; i++) { accA[i][0] = zero4; accA[i][1] = zero4; accG[i][0] = zero4; accG[i][1] = zero4; }

    int srow = tid >> 1;
    int se   = (tid & 1) * 16;
    int brow = tid >> 2;
    int bqe  = (tid & 3) * 8;

    int4 ra0, ra1, rb1, rb2;
    {
        const u16* pa = A + (size_t)(m0 + srow) * K + se;
        ra0 = *(const int4*)pa; ra1 = *(const int4*)(pa + 8);
        rb1 = *(const int4*)(WgT + (size_t)(n0 + brow) * K + bqe);
        rb2 = *(const int4*)(WgT + (size_t)(2048 + n0 + brow) * K + bqe);
    }
    for (int kt = 0; kt < K; kt += 32) {
        __syncthreads();
        *(int4*)&As[srow * 32 + se]     = ra0;
        *(int4*)&As[srow * 32 + se + 8] = ra1;
        *(int4*)&Bs1[brow * 32 + bqe]   = rb1;
        *(int4*)&Bs2[brow * 32 + bqe]   = rb2;
        __syncthreads();
        int kn = kt + 32;
        if (kn < K) {
            const u16* pa = A + (size_t)(m0 + srow) * K + kn + se;
            ra0 = *(const int4*)pa; ra1 = *(const int4*)(pa + 8);
            rb1 = *(const int4*)(WgT + (size_t)(n0 + brow) * K + kn + bqe);
            rb2 = *(const int4*)(WgT + (size_t)(2048 + n0 + brow) * K + kn + bqe);
        }
        bf16x8 af[4], b1[2], b2[2];
#pragma unroll
        for (int mi = 0; mi < 4; mi++)
            af[mi] = *(const bf16x8*)&As[(wr * 64 + mi * 16 + l15) * 32 + l4 * 8];
#pragma unroll
        for (int nj = 0; nj < 2; nj++) {
            b1[nj] = *(const bf16x8*)&Bs1[(wc * 32 + nj * 16 + l15) * 32 + l4 * 8];
            b2[nj] = *(const bf16x8*)&Bs2[(wc * 32 + nj * 16 + l15) * 32 + l4 * 8];
        }
#pragma unroll
        for (int mi = 0; mi < 4; mi++)
#pragma unroll
            for (int nj = 0; nj < 2; nj++) {
                accA[mi][nj] = __builtin_amdgcn_mfma_f32_16x16x32_bf16(af[mi], b1[nj], accA[mi][nj], 0, 0, 0);
                accG[mi][nj] = __builtin_amdgcn_mfma_f32_16x16x32_bf16(af[mi], b2[nj], accG[mi][nj], 0, 0, 0);
            }
    }

#pragma unroll
    for (int mi = 0; mi < 4; mi++)
#pragma unroll
        for (int nj = 0; nj < 2; nj++)
#pragma unroll
            for (int r = 0; r < 4; r++) {
                int row = m0 + wr * 64 + mi * 16 + l4 * 4 + r;
                int col = n0 + wc * 32 + nj * 16 + l15;
                float a = accA[mi][nj][r] + bg[col];
                float g = accG[mi][nj][r] + bg[2048 + col];
                float ge = 0.5f * g * (1.0f + erff(g * 0.70710678118654752f));
                ag[(size_t)row * 2048 + col] = f2bf(a * ge);
            }
}

// ---------------- MFMA flash attention (log2-domain softmax, raw v_exp) ----------------
// Q pre-scaled by 0.125*log2(e) in weight prep -> scores in log2 domain.
// Per-lane deferred l partials (one cross-lane reduce at finalize).
// Defer-max: wave-uniform skip of rescale when no row's max grew.
__global__ __launch_bounds__(256) void flash_attn_mfma(const u16* __restrict__ q,
                                                       const u16* __restrict__ k,
                                                       const u16* __restrict__ vt,  // [b*8+h][64][1024]
                                                       u16* __restrict__ o) {
    __shared__ u16 Ps[64 * 64];      // Q staging -> P -> O staging
    __shared__ u16 Ks[64 * 64];
    __shared__ u16 Vt[64 * 64];
    const int tid = threadIdx.x;
    const int h = blockIdx.y, b = blockIdx.z;
    const int q0 = blockIdx.x * 64;
    const size_t hb  = (size_t)b * Ss * Cch + (size_t)h * DHh;
    const size_t vhb = ((size_t)(b * NHh + h) * DHh) * Ss;

    const int wq = tid >> 6;
    const int lane = tid & 63;
    const int l15 = lane & 15, l4 = lane >> 4;

    {
        int r = tid >> 2, ch = (tid & 3) * 2;
        const u16* src = q + hb + (size_t)(q0 + r) * Cch + ch * 8;
        *(int4*)&Ps[swz(r, ch)]     = *(const int4*)src;
        *(int4*)&Ps[swz(r, ch + 1)] = *(const int4*)(src + 8);
    }
    __syncthreads();
    bf16x8 aq[2];
    aq[0] = *(const bf16x8*)&Ps[swz(wq * 16 + l15, 0 * 4 + l4)];
    aq[1] = *(const bf16x8*)&Ps[swz(wq * 16 + l15, 1 * 4 + l4)];

    f32x4 zero4 = {0.f, 0.f, 0.f, 0.f};
    f32x4 oacc[4];
    float m_[4], l_[4];
#pragma unroll
    for (int j = 0; j < 4; j++) oacc[j] = zero4;
#pragma unroll
    for (int r = 0; r < 4; r++) { m_[r] = -1e30f; l_[r] = 0.f; }

    for (int t0 = 0; t0 < Ss; t0 += 64) {
        __syncthreads();
        {
            int r = tid >> 2, ch = (tid & 3) * 2;
            const u16* ksrc = k + hb + (size_t)(t0 + r) * Cch + ch * 8;
            *(int4*)&Ks[swz(r, ch)]     = *(const int4*)ksrc;
            *(int4*)&Ks[swz(r, ch + 1)] = *(const int4*)(ksrc + 8);
            const u16* vsrc = vt + vhb + (size_t)r * Ss + t0 + ch * 8;
            *(int4*)&Vt[swz(r, ch)]     = *(const int4*)vsrc;
            *(int4*)&Vt[swz(r, ch + 1)] = *(const int4*)(vsrc + 8);
        }
        __syncthreads();

        // QK^T (log2-scaled): wave's 16 q-rows x 64 t-cols
        f32x4 sacc[4];
#pragma unroll
        for (int j = 0; j < 4; j++) sacc[j] = zero4;
#pragma unroll
        for (int ks = 0; ks < 2; ks++) {
#pragma unroll
            for (int j = 0; j < 4; j++) {
                bf16x8 bk = *(const bf16x8*)&Ks[swz(j * 16 + l15, ks * 4 + l4)];
                sacc[j] = __builtin_amdgcn_mfma_f32_16x16x32_bf16(aq[ks], bk, sacc[j], 0, 0, 0);
            }
        }

        // tile max per row + defer-max decision (wave-uniform)
        float tmv[4];
        int grew = 0;
#pragma unroll
        for (int r = 0; r < 4; r++) {
            float tm = fmaxf(fmaxf(sacc[0][r], sacc[1][r]), fmaxf(sacc[2][r], sacc[3][r]));
            tm = fmaxf(tm, __shfl_xor(tm, 1));
            tm = fmaxf(tm, __shfl_xor(tm, 2));
            tm = fmaxf(tm, __shfl_xor(tm, 4));
            tm = fmaxf(tm, __shfl_xor(tm, 8));
            tmv[r] = tm;
            grew |= (tm > m_[r]);
        }

        if (__any(grew)) {
#pragma unroll
            for (int r = 0; r < 4; r++) {
                float nm = fmaxf(m_[r], tmv[r]);
                float sc = exp2_raw(m_[r] - nm);
                m_[r] = nm;
                float p0 = exp2_raw(sacc[0][r] - nm), p1 = exp2_raw(sacc[1][r] - nm);
                float p2 = exp2_raw(sacc[2][r] - nm), p3 = exp2_raw(sacc[3][r] - nm);
                int row = wq * 16 + l4 * 4 + r;
                int rx = row & 7, base = row * 64, wi = l15 & 7, hi = l15 >> 3;
                Ps[base + (((0 + hi) ^ rx) * 8) + wi] = f2bf_rz(p0);
                Ps[base + (((2 + hi) ^ rx) * 8) + wi] = f2bf_rz(p1);
                Ps[base + (((4 + hi) ^ rx) * 8) + wi] = f2bf_rz(p2);
                Ps[base + (((6 + hi) ^ rx) * 8) + wi] = f2bf_rz(p3);
                l_[r] = l_[r] * sc + (p0 + p1 + p2 + p3);
#pragma unroll
                for (int j = 0; j < 4; j++) oacc[j][r] *= sc;
            }
        } else {
#pragma unroll
            for (int r = 0; r < 4; r++) {
                float nm = m_[r];
                float p0 = exp2_raw(sacc[0][r] - nm), p1 = exp2_raw(sacc[1][r] - nm);
                float p2 = exp2_raw(sacc[2][r] - nm), p3 = exp2_raw(sacc[3][r] - nm);
                int row = wq * 16 + l4 * 4 + r;
                int rx = row & 7, base = row * 64, wi = l15 & 7, hi = l15 >> 3;
                Ps[base + (((0 + hi) ^ rx) * 8) + wi] = f2bf_rz(p0);
                Ps[base + (((2 + hi) ^ rx) * 8) + wi] = f2bf_rz(p1);
                Ps[base + (((4 + hi) ^ rx) * 8) + wi] = f2bf_rz(p2);
                Ps[base + (((6 + hi) ^ rx) * 8) + wi] = f2bf_rz(p3);
                l_[r] += p0 + p1 + p2 + p3;
            }
        }

        // PV: A=Ps (own rows, same-wave dep), Bt=Vt[d][t]
#pragma unroll
        for (int ks = 0; ks < 2; ks++) {
            bf16x8 pa = *(const bf16x8*)&Ps[swz(wq * 16 + l15, ks * 4 + l4)];
#pragma unroll
            for (int j = 0; j < 4; j++) {
                bf16x8 bv = *(const bf16x8*)&Vt[swz(j * 16 + l15, ks * 4 + l4)];
                oacc[j] = __builtin_amdgcn_mfma_f32_16x16x32_bf16(pa, bv, oacc[j], 0, 0, 0);
            }
        }
    }

    // finalize: reduce per-lane l partials, O /= l, stage via Ps, coalesced store
#pragma unroll
    for (int r = 0; r < 4; r++) {
        float lt = l_[r];
        lt += __shfl_xor(lt, 1);
        lt += __shfl_xor(lt, 2);
        lt += __shfl_xor(lt, 4);
        lt += __shfl_xor(lt, 8);
        float inv = 1.0f / lt;
        int row = wq * 16 + l4 * 4 + r;
        int rx = row & 7, base = row * 64, wi = l15 & 7, hi = l15 >> 3;
        Ps[base + (((0 + hi) ^ rx) * 8) + wi] = f2bf(oacc[0][r] * inv);
        Ps[base + (((2 + hi) ^ rx) * 8) + wi] = f2bf(oacc[1][r] * inv);
        Ps[base + (((4 + hi) ^ rx) * 8) + wi] = f2bf(oacc[2][r] * inv);
        Ps[base + (((6 + hi) ^ rx) * 8) + wi] = f2bf(oacc[3][r] * inv);
    }
    __syncthreads();
    {
        int r = tid >> 2, ch = (tid & 3) * 2;
        u16* dst = o + hb + (size_t)(q0 + r) * Cch + ch * 8;
        *(int4*)dst       = *(const int4*)&Ps[swz(r, ch)];
        *(int4*)(dst + 8) = *(const int4*)&Ps[swz(r, ch + 1)];
    }
}

// ---------------- final: out(B,C,S) = tmp(B,S,C)^T + x ----------------
__global__ __launch_bounds__(256) void final_out(const float* __restrict__ tmp,
                                                 const float* __restrict__ x,
                                                 float* __restrict__ outp) {
    __shared__ float tile[32][33];
    int b = blockIdx.z, c0 = blockIdx.y * 32, s0 = blockIdx.x * 32;
    int tx = threadIdx.x, ty = threadIdx.y;
#pragma unroll
    for (int i = 0; i < 4; i++) {
        int s = s0 + ty + i * 8;
        tile[ty + i * 8][tx] = tmp[((size_t)b * Ss + s) * Cch + c0 + tx];
    }
    __syncthreads();
#pragma unroll
    for (int i = 0; i < 4; i++) {
        int c = c0 + ty + i * 8;
        size_t idx = ((size_t)b * Cch + c) * Ss + s0 + tx;
        outp[idx] = tile[tx][ty + i * 8] + x[idx];
    }
}

extern "C" void kernel_launch(void* const* d_in, const int* in_sizes, int n_in,
                              void* d_out, int out_size, void* d_ws, size_t ws_size,
                              hipStream_t stream) {
    (void)in_sizes; (void)n_in; (void)out_size; (void)ws_size;
    const float* x      = (const float*)d_in[0];
    const float* gn_w   = (const float*)d_in[1];
    const float* gn_b   = (const float*)d_in[2];
    const float* pin_w  = (const float*)d_in[3];
    const float* pin_b  = (const float*)d_in[4];
    const float* ln1_w  = (const float*)d_in[5];
    const float* ln1_b  = (const float*)d_in[6];
    const float* wq     = (const float*)d_in[7];
    const float* wk     = (const float*)d_in[8];
    const float* wv     = (const float*)d_in[9];
    const float* wo     = (const float*)d_in[10];
    const float* bo     = (const float*)d_in[11];
    const float* ln3_w  = (const float*)d_in[12];
    const float* ln3_b  = (const float*)d_in[13];
    const float* wg     = (const float*)d_in[14];
    const float* bg     = (const float*)d_in[15];
    const float* wd     = (const float*)d_in[16];
    const float* bd     = (const float*)d_in[17];
    const float* pout_w = (const float*)d_in[18];
    const float* pout_b = (const float*)d_in[19];
    float* out = (float*)d_out;

    // ---- workspace layout (bytes) ----
    char* W = (char*)d_ws;
    u16* tb        = (u16*)W;                                     // t residual, bf16, 16.78 MB
    float* tmp_f32 = (float*)(W + 33554432);                      // 33.55 MB
    u16* qb    = (u16*)(W + 67108864);                            // 16.78 MB (qb,kb,vb contiguous!)
    u16* kb    = qb + 8388608;
    u16* vb    = kb + 8388608;
    u16* attnb = vb + 8388608;
    u16* Xb    = attnb + 8388608;                                 // 16.78 MB
    float* stats = (float*)(W + 67108864 + 5ull * 16777216);      // 1 KB
    u16* wbase = (u16*)(W + 67108864 + 5ull * 16777216 + 1024);
    u16* pinB  = wbase;                 // 512*512  (already [N][K])
    u16* poutB = pinB  + 262144;
    u16* wqT   = poutB + 262144;        // [512][512] transposed, scaled by QSCL
    u16* wkT   = wqT   + 262144;        // contiguous with wqT -> [1536][512] for fused qkv
    u16* wvT   = wkT   + 262144;
    u16* woT   = wvT   + 262144;
    u16* wgT   = woT   + 262144;        // [4096][512]
    u16* wdT   = wgT   + 2097152;       // [512][2048]
    u16* ag    = qb;                    // R x 2048 bf16, aliases qb..attnb (dead by then)
    u16* vtb   = (u16*)tmp_f32;         // V^T [b*8+h][64][1024], aliases tmp_f32 (dead until pout)

    dim3 tb8(32, 8);

    // stats + weight prep (fused launches)
    gn_stats<<<128, 256, 0, stream>>>(x, stats);
    conv_bf16x2<<<512, 256, 0, stream>>>(pin_w, pout_w, pinB, poutB);
    convT4_bf16<<<dim3(16, 16, 4), tb8, 0, stream>>>(wq, wk, wv, wo, wqT, wkT, wvT, woT);
    convT_bf16<<<dim3(128, 16), tb8, 0, stream>>>(wg, wgT, 512, 4096);
    convT_bf16<<<dim3(16, 64),  tb8, 0, stream>>>(wd, wdT, 2048, 512);

    // h = GN(x) transposed -> Xb (bf16)
    gn_apply_t_bf<<<dim3(32, 16, 16), tb8, 0, stream>>>(x, stats, gn_w, gn_b, Xb);

    // t = h @ pin_w^T + pin_b -> tb (bf16)
    mfma_gemm<6><<<dim3(4, 128), 256, 0, stream>>>(Xb, pinB, pin_b, nullptr, tb, 512, 512);
    // tn = ln1(t) -> Xb
    layer_norm_rows_bf<<<16384, 256, 0, stream>>>(tb, ln1_w, ln1_b, Xb);
    // fused q(scaled)/k/v: N=1536, routed to qb/kb/vb
    mfma_gemm<8><<<dim3(12, 128), 256, 0, stream>>>(Xb, wqT, nullptr, nullptr, qb, 512, 1536);
    // per-head V transpose -> vtb
    vtrans<<<dim3(16, 8, 16), 256, 0, stream>>>(vb, vtb);
    // attention (MFMA) -> attnb (bf16)
    flash_attn_mfma<<<dim3(16, 8, 16), 256, 0, stream>>>(qb, kb, vtb, attnb);
    // t += attn @ wo + bo (bf16 in-place on tb)
    mfma_gemm<7><<<dim3(4, 128), 256, 0, stream>>>(attnb, woT, bo, nullptr, tb, 512, 512);
    // tn3 = ln3(t) -> Xb
    layer_norm_rows_bf<<<16384, 256, 0, stream>>>(tb, ln3_w, ln3_b, Xb);
    // ag = a * gelu(g) (bf16), aliases q/k/v/attn space
    geglu_mfma<<<dim3(32, 128), 256, 0, stream>>>(Xb, wgT, bg, ag);
    // t += ag @ wd + bd (bf16 in-place on tb)
    mfma_gemm<7><<<dim3(4, 128), 256, 0, stream>>>(ag, wdT, bd, nullptr, tb, 2048, 512);
    // tmp = t @ pout_w^T + pout_b -> tmp_f32
    mfma_gemm<1><<<dim3(4, 128), 256, 0, stream>>>(tb, poutB, pout_b, tmp_f32, nullptr, 512, 512);
    // out = tmp^T + x
    final_out<<<dim3(32, 16, 16), tb8, 0, stream>>>(tmp_f32, x, out);
}

// Round 19
// 502.139 us; speedup vs baseline: 1.1117x; 1.0082x over previous
//
#include <hip/hip_runtime.h>
#include <hip/hip_bf16.h>
#include <math.h>

typedef unsigned short u16;
typedef __attribute__((ext_vector_type(8))) short bf16x8;
typedef __attribute__((ext_vector_type(4))) float f32x4;

#define Bb 16
#define Cch 512
#define Ss 1024
#define NHh 8
#define DHh 64
#define CPG 64
#define EPSV 1e-5f
#define R_TOTAL (Bb*Ss)   // 16384
#define QSCL 0.18033688011112042f   // 0.125 * log2(e)

__device__ inline u16 f2bf(float f) {
    unsigned int u = __float_as_uint(f);
    unsigned int r = (u + 0x7fffu + ((u >> 16) & 1u)) >> 16;
    return (u16)r;
}
__device__ inline u16 f2bf_rz(float f) { return (u16)(__float_as_uint(f) >> 16); }
__device__ inline float bf2f(u16 v) { return __uint_as_float((unsigned)v << 16); }
__device__ inline float exp2_raw(float x) {
    float r; asm("v_exp_f32 %0, %1" : "=v"(r) : "v"(x)); return r;
}

// attention swizzle: row-stride 64 u16, 16B chunk XOR'd by row&7
__device__ inline int swz(int row, int chunk) {
    return row * 64 + ((chunk ^ (row & 7)) * 8);
}
// GEMM-tile swizzle: [R][32]-u16 tile viewed as [R/2 spans][64 u16];
// logical row r, 16B chunk c (0..3) -> c8 = (r&1)*4+c, XOR span&7.
// Fragment reads (16 l15-rows, fixed chunk) land 2 lanes/bank-group = free.
__device__ inline int swzg(int r, int c) {
    int span = r >> 1;
    int c8 = ((r & 1) << 2) | c;
    return span * 64 + ((c8 ^ (span & 7)) * 8);
}

// ---------------- GroupNorm stats ----------------
__global__ __launch_bounds__(256) void gn_stats(const float* __restrict__ x,
                                                float* __restrict__ stats) {
    int bg = blockIdx.x;
    int b = bg >> 3, g = bg & 7;
    const float* base = x + ((size_t)b * Cch + (size_t)g * CPG) * Ss;
    float s = 0.f, ss = 0.f;
    for (int i = threadIdx.x; i < CPG * Ss; i += 256) {
        float v = base[i];
        s += v; ss += v * v;
    }
    for (int o = 32; o > 0; o >>= 1) { s += __shfl_down(s, o); ss += __shfl_down(ss, o); }
    __shared__ float red[2][4];
    int wid = threadIdx.x >> 6, lane = threadIdx.x & 63;
    if (lane == 0) { red[0][wid] = s; red[1][wid] = ss; }
    __syncthreads();
    if (threadIdx.x == 0) {
        float S1 = red[0][0] + red[0][1] + red[0][2] + red[0][3];
        float S2 = red[1][0] + red[1][1] + red[1][2] + red[1][3];
        const float inv_n = 1.0f / (CPG * Ss);
        float mu = S1 * inv_n;
        float var = S2 * inv_n - mu * mu;
        stats[bg * 2]     = mu;
        stats[bg * 2 + 1] = rsqrtf(var + EPSV);
    }
}

// ---------------- GroupNorm apply + transpose -> bf16 (B,S,C) ----------------
__global__ __launch_bounds__(256) void gn_apply_t_bf(const float* __restrict__ x,
                                                     const float* __restrict__ stats,
                                                     const float* __restrict__ gw,
                                                     const float* __restrict__ gb,
                                                     u16* __restrict__ ht) {
    __shared__ float tile[32][33];
    int b  = blockIdx.z;
    int c0 = blockIdx.y * 32;
    int s0 = blockIdx.x * 32;
    int tx = threadIdx.x, ty = threadIdx.y;
#pragma unroll
    for (int i = 0; i < 4; i++) {
        int c = c0 + ty + i * 8;
        int g = c >> 6;
        float mu = stats[(b * 8 + g) * 2];
        float rs = stats[(b * 8 + g) * 2 + 1];
        float v = x[((size_t)b * Cch + c) * Ss + s0 + tx];
        tile[ty + i * 8][tx] = (v - mu) * rs * gw[c] + gb[c];
    }
    __syncthreads();
#pragma unroll
    for (int i = 0; i < 4; i++) {
        int s = s0 + ty + i * 8;
        ht[((size_t)b * Ss + s) * Cch + c0 + tx] = f2bf(tile[tx][ty + i * 8]);
    }
}

// ---------------- fused fp32 -> bf16 convert for pin_w & pout_w ----------------
__global__ __launch_bounds__(256) void conv_bf16x2(const float* __restrict__ in0,
                                                   const float* __restrict__ in1,
                                                   u16* __restrict__ o0,
                                                   u16* __restrict__ o1) {
    for (int i = blockIdx.x * 256 + threadIdx.x; i < 524288; i += gridDim.x * 256) {
        if (i < 262144) o0[i] = f2bf(in0[i]);
        else            o1[i - 262144] = f2bf(in1[i - 262144]);
    }
}

// ---------------- transpose + convert: in (R x C) fp32 -> out (C x R) bf16 ----------------
__global__ __launch_bounds__(256) void convT_bf16(const float* __restrict__ in,
                                                  u16* __restrict__ outp, int R, int C) {
    __shared__ float tile[32][33];
    int c0 = blockIdx.x * 32, r0 = blockIdx.y * 32;
    int tx = threadIdx.x, ty = threadIdx.y;
#pragma unroll
    for (int i = 0; i < 4; i++)
        tile[ty + i * 8][tx] = in[(size_t)(r0 + ty + i * 8) * C + c0 + tx];
    __syncthreads();
#pragma unroll
    for (int i = 0; i < 4; i++)
        outp[(size_t)(c0 + ty + i * 8) * R + r0 + tx] = f2bf(tile[tx][ty + i * 8]);
}

// ---------------- fused 512x512 transpose+convert for wq(scaled)/wk/wv/wo ----------------
__global__ __launch_bounds__(256) void convT4_bf16(const float* __restrict__ w0,
                                                   const float* __restrict__ w1,
                                                   const float* __restrict__ w2,
                                                   const float* __restrict__ w3,
                                                   u16* __restrict__ o0,
                                                   u16* __restrict__ o1,
                                                   u16* __restrict__ o2,
                                                   u16* __restrict__ o3) {
    __shared__ float tile[32][33];
    const float* in; u16* outp; float scl = 1.0f;
    switch (blockIdx.z) {
        case 0: in = w0; outp = o0; scl = QSCL; break;
        case 1: in = w1; outp = o1; break;
        case 2: in = w2; outp = o2; break;
        default: in = w3; outp = o3; break;
    }
    int c0 = blockIdx.x * 32, r0 = blockIdx.y * 32;
    int tx = threadIdx.x, ty = threadIdx.y;
#pragma unroll
    for (int i = 0; i < 4; i++)
        tile[ty + i * 8][tx] = in[(size_t)(r0 + ty + i * 8) * 512 + c0 + tx] * scl;
    __syncthreads();
#pragma unroll
    for (int i = 0; i < 4; i++)
        outp[(size_t)(c0 + ty + i * 8) * 512 + r0 + tx] = f2bf(tile[tx][ty + i * 8]);
}

// ---------------- per-head V transpose: vb [b][s][512] -> vt [(b*8+h)][64][1024] ----------
__global__ __launch_bounds__(256) void vtrans(const u16* __restrict__ in,
                                              u16* __restrict__ outp) {
    __shared__ u16 tile[64][66];
    int s0 = blockIdx.x * 64, h = blockIdx.y, b = blockIdx.z;
    const u16* src = in + ((size_t)b * Ss + s0) * Cch + h * 64;
    int r = threadIdx.x >> 3, c8 = (threadIdx.x & 7) * 8;
#pragma unroll
    for (int p = 0; p < 2; p++) {
        int rr = r + p * 32;
        *(int4*)&tile[rr][c8] = *(const int4*)&src[(size_t)rr * Cch + c8];
    }
    __syncthreads();
    u16* dst = outp + ((size_t)(b * 8 + h) * 64) * Ss + s0;
#pragma unroll
    for (int p = 0; p < 2; p++) {
        int d = r + p * 32;
        u16 vals[8];
#pragma unroll
        for (int e = 0; e < 8; e++) vals[e] = tile[c8 + e][d];
        *(int4*)&dst[(size_t)d * Ss + c8] = *(int4*)vals;
    }
}

// ---------------- LayerNorm rows (bf16 in, bf16 out) ----------------
__global__ __launch_bounds__(256) void layer_norm_rows_bf(const u16* __restrict__ in,
                                                          const float* __restrict__ w,
                                                          const float* __restrict__ bb,
                                                          u16* __restrict__ outp) {
    int row = blockIdx.x;
    const u16* p = in + (size_t)row * Cch;
    int i0 = threadIdx.x * 2;
    ushort2 u = *(const ushort2*)&p[i0];
    float v0 = bf2f(u.x), v1 = bf2f(u.y);
    float s = v0 + v1, ss = v0 * v0 + v1 * v1;
    for (int o = 32; o > 0; o >>= 1) { s += __shfl_down(s, o); ss += __shfl_down(ss, o); }
    __shared__ float red[2][4];
    __shared__ float mu_s, rs_s;
    int wid = threadIdx.x >> 6, lane = threadIdx.x & 63;
    if (lane == 0) { red[0][wid] = s; red[1][wid] = ss; }
    __syncthreads();
    if (threadIdx.x == 0) {
        float S1 = red[0][0] + red[0][1] + red[0][2] + red[0][3];
        float S2 = red[1][0] + red[1][1] + red[1][2] + red[1][3];
        float mu = S1 * (1.0f / Cch);
        float var = S2 * (1.0f / Cch) - mu * mu;
        mu_s = mu; rs_s = rsqrtf(var + EPSV);
    }
    __syncthreads();
    float mu = mu_s, rs = rs_s;
    outp[(size_t)row * Cch + i0]     = f2bf((v0 - mu) * rs * w[i0] + bb[i0]);
    outp[(size_t)row * Cch + i0 + 1] = f2bf((v1 - mu) * rs * w[i0 + 1] + bb[i0 + 1]);
}

// ---------------- MFMA GEMM: out(MxN) = A(MxK bf16) @ Bt(NxK bf16)^T ----------------
// 128x128 tile, BK=32, 256 thr = 4 waves (2x2). Reg-staged prefetch + swizzled LDS
// (swzg: 2-way-free fragment reads; was 8-way conflict at linear [128][32]).
// EPI: 0 = bf16; 1 = fp32 +bias; 6 = bf16 +bias; 7 = bf16 +bias + bf16 residual in-place;
//      8 = bf16 routed qkv (outb base = qb; col>>9 selects q/k/v slot, 8388608 apart).
template<int EPI>
__global__ __launch_bounds__(256) void mfma_gemm(const u16* __restrict__ A,
                                                 const u16* __restrict__ Bt,
                                                 const float* __restrict__ bias,
                                                 float* __restrict__ fout,
                                                 u16* __restrict__ outb,
                                                 int K, int N) {
    __shared__ u16 As[128 * 32];
    __shared__ u16 Bs[128 * 32];
    int tid = threadIdx.x;
    int m0 = blockIdx.y * 128, n0 = blockIdx.x * 128;
    int wave = tid >> 6, lane = tid & 63;
    int wr = wave >> 1, wc = wave & 1;
    int l15 = lane & 15, l4 = lane >> 4;

    f32x4 zero4 = {0.f, 0.f, 0.f, 0.f};
    f32x4 acc[4][4];
#pragma unroll
    for (int i = 0; i < 4; i++)
#pragma unroll
        for (int j = 0; j < 4; j++) acc[i][j] = zero4;

    int srow = tid >> 1;
    int sc0  = (tid & 1) * 2;          // 16B chunk pair {sc0, sc0+1}
    int se   = sc0 * 8;                // element offset

    int4 ra0, ra1, rb0, rb1;
    {
        const u16* pa = A  + (size_t)(m0 + srow) * K + se;
        ra0 = *(const int4*)pa; ra1 = *(const int4*)(pa + 8);
        const u16* pb = Bt + (size_t)(n0 + srow) * K + se;
        rb0 = *(const int4*)pb; rb1 = *(const int4*)(pb + 8);
    }
    for (int kt = 0; kt < K; kt += 32) {
        __syncthreads();
        *(int4*)&As[swzg(srow, sc0)]     = ra0;
        *(int4*)&As[swzg(srow, sc0 + 1)] = ra1;
        *(int4*)&Bs[swzg(srow, sc0)]     = rb0;
        *(int4*)&Bs[swzg(srow, sc0 + 1)] = rb1;
        __syncthreads();
        int kn = kt + 32;
        if (kn < K) {
            const u16* pa = A  + (size_t)(m0 + srow) * K + kn + se;
            ra0 = *(const int4*)pa; ra1 = *(const int4*)(pa + 8);
            const u16* pb = Bt + (size_t)(n0 + srow) * K + kn + se;
            rb0 = *(const int4*)pb; rb1 = *(const int4*)(pb + 8);
        }
        bf16x8 af[4], bfr[4];
#pragma unroll
        for (int mi = 0; mi < 4; mi++)
            af[mi] = *(const bf16x8*)&As[swzg(wr * 64 + mi * 16 + l15, l4)];
#pragma unroll
        for (int nj = 0; nj < 4; nj++)
            bfr[nj] = *(const bf16x8*)&Bs[swzg(wc * 64 + nj * 16 + l15, l4)];
#pragma unroll
        for (int mi = 0; mi < 4; mi++)
#pragma unroll
            for (int nj = 0; nj < 4; nj++)
                acc[mi][nj] = __builtin_amdgcn_mfma_f32_16x16x32_bf16(af[mi], bfr[nj], acc[mi][nj], 0, 0, 0);
    }

#pragma unroll
    for (int mi = 0; mi < 4; mi++)
#pragma unroll
        for (int nj = 0; nj < 4; nj++)
#pragma unroll
            for (int r = 0; r < 4; r++) {
                int row = m0 + wr * 64 + mi * 16 + l4 * 4 + r;
                int col = n0 + wc * 64 + nj * 16 + l15;
                float v = acc[mi][nj][r];
                if constexpr (EPI == 0) {
                    outb[(size_t)row * N + col] = f2bf(v);
                } else if constexpr (EPI == 1) {
                    fout[(size_t)row * N + col] = v + bias[col];
                } else if constexpr (EPI == 6) {
                    outb[(size_t)row * N + col] = f2bf(v + bias[col]);
                } else if constexpr (EPI == 7) {
                    size_t idx = (size_t)row * N + col;
                    v += bias[col] + bf2f(outb[idx]);
                    outb[idx] = f2bf(v);
                } else if constexpr (EPI == 8) {
                    size_t idx = (size_t)(col >> 9) * 8388608 + (size_t)row * 512 + (col & 511);
                    outb[idx] = f2bf(v);
                }
            }
}

// ---------------- GEGLU MFMA: both halves of tn3 @ wg, fused exact GELU, bf16 out --------
__global__ __launch_bounds__(256) void geglu_mfma(const u16* __restrict__ A,
                                                  const u16* __restrict__ WgT,  // [4096][512]
                                                  const float* __restrict__ bg,
                                                  u16* __restrict__ ag) {
    __shared__ u16 As[128 * 32];
    __shared__ u16 Bs1[64 * 32];
    __shared__ u16 Bs2[64 * 32];
    const int K = 512;
    int tid = threadIdx.x;
    int m0 = blockIdx.y * 128, n0 = blockIdx.x * 64;
    int wave = tid >> 6, lane = tid & 63;
    int wr = wave >> 1, wc = wave & 1;
    int l15 = lane & 15, l4 = lane >> 4;

    f32x4 zero4 = {0.f, 0.f, 0.f, 0.f};
    f32x4 accA[4][2], accG[4][2];
#pragma unroll
    for (int i = 0; i < 4; i++) { accA[i][0] = zero4; accA[i][1] = zero4; accG[i][0] = zero4; accG[i][1] = zero4; }

    int srow = tid >> 1;
    int sc0  = (tid & 1) * 2;
    int se   = sc0 * 8;
    int brow = tid >> 2;
    int bch  = tid & 3;
    int bqe  = bch * 8;

    int4 ra0, ra1, rb1, rb2;
    {
        const u16* pa = A + (size_t)(m0 + srow) * K + se;
        ra0 = *(const int4*)pa; ra1 = *(const int4*)(pa + 8);
        rb1 = *(const int4*)(WgT + (size_t)(n0 + brow) * K + bqe);
        rb2 = *(const int4*)(WgT + (size_t)(2048 + n0 + brow) * K + bqe);
    }
    for (int kt = 0; kt < K; kt += 32) {
        __syncthreads();
        *(int4*)&As[swzg(srow, sc0)]     = ra0;
        *(int4*)&As[swzg(srow, sc0 + 1)] = ra1;
        *(int4*)&Bs1[swzg(brow, bch)]    = rb1;
        *(int4*)&Bs2[swzg(brow, bch)]    = rb2;
        __syncthreads();
        int kn = kt + 32;
        if (kn < K) {
            const u16* pa = A + (size_t)(m0 + srow) * K + kn + se;
            ra0 = *(const int4*)pa; ra1 = *(const int4*)(pa + 8);
            rb1 = *(const int4*)(WgT + (size_t)(n0 + brow) * K + kn + bqe);
            rb2 = *(const int4*)(WgT + (size_t)(2048 + n0 + brow) * K + kn + bqe);
        }
        bf16x8 af[4], b1[2], b2[2];
#pragma unroll
        for (int mi = 0; mi < 4; mi++)
            af[mi] = *(const bf16x8*)&As[swzg(wr * 64 + mi * 16 + l15, l4)];
#pragma unroll
        for (int nj = 0; nj < 2; nj++) {
            b1[nj] = *(const bf16x8*)&Bs1[swzg(wc * 32 + nj * 16 + l15, l4)];
            b2[nj] = *(const bf16x8*)&Bs2[swzg(wc * 32 + nj * 16 + l15, l4)];
        }
#pragma unroll
        for (int mi = 0; mi < 4; mi++)
#pragma unroll
            for (int nj = 0; nj < 2; nj++) {
                accA[mi][nj] = __builtin_amdgcn_mfma_f32_16x16x32_bf16(af[mi], b1[nj], accA[mi][nj], 0, 0, 0);
                accG[mi][nj] = __builtin_amdgcn_mfma_f32_16x16x32_bf16(af[mi], b2[nj], accG[mi][nj], 0, 0, 0);
            }
    }

#pragma unroll
    for (int mi = 0; mi < 4; mi++)
#pragma unroll
        for (int nj = 0; nj < 2; nj++)
#pragma unroll
            for (int r = 0; r < 4; r++) {
                int row = m0 + wr * 64 + mi * 16 + l4 * 4 + r;
                int col = n0 + wc * 32 + nj * 16 + l15;
                float a = accA[mi][nj][r] + bg[col];
                float g = accG[mi][nj][r] + bg[2048 + col];
                float ge = 0.5f * g * (1.0f + erff(g * 0.70710678118654752f));
                ag[(size_t)row * 2048 + col] = f2bf(a * ge);
            }
}

// ---------------- MFMA flash attention (log2-domain softmax, raw v_exp) ----------------
__global__ __launch_bounds__(256) void flash_attn_mfma(const u16* __restrict__ q,
                                                       const u16* __restrict__ k,
                                                       const u16* __restrict__ vt,  // [b*8+h][64][1024]
                                                       u16* __restrict__ o) {
    __shared__ u16 Ps[64 * 64];      // Q staging -> P -> O staging
    __shared__ u16 Ks[64 * 64];
    __shared__ u16 Vt[64 * 64];
    const int tid = threadIdx.x;
    const int h = blockIdx.y, b = blockIdx.z;
    const int q0 = blockIdx.x * 64;
    const size_t hb  = (size_t)b * Ss * Cch + (size_t)h * DHh;
    const size_t vhb = ((size_t)(b * NHh + h) * DHh) * Ss;

    const int wq = tid >> 6;
    const int lane = tid & 63;
    const int l15 = lane & 15, l4 = lane >> 4;

    {
        int r = tid >> 2, ch = (tid & 3) * 2;
        const u16* src = q + hb + (size_t)(q0 + r) * Cch + ch * 8;
        *(int4*)&Ps[swz(r, ch)]     = *(const int4*)src;
        *(int4*)&Ps[swz(r, ch + 1)] = *(const int4*)(src + 8);
    }
    __syncthreads();
    bf16x8 aq[2];
    aq[0] = *(const bf16x8*)&Ps[swz(wq * 16 + l15, 0 * 4 + l4)];
    aq[1] = *(const bf16x8*)&Ps[swz(wq * 16 + l15, 1 * 4 + l4)];

    f32x4 zero4 = {0.f, 0.f, 0.f, 0.f};
    f32x4 oacc[4];
    float m_[4], l_[4];
#pragma unroll
    for (int j = 0; j < 4; j++) oacc[j] = zero4;
#pragma unroll
    for (int r = 0; r < 4; r++) { m_[r] = -1e30f; l_[r] = 0.f; }

    for (int t0 = 0; t0 < Ss; t0 += 64) {
        __syncthreads();
        {
            int r = tid >> 2, ch = (tid & 3) * 2;
            const u16* ksrc = k + hb + (size_t)(t0 + r) * Cch + ch * 8;
            *(int4*)&Ks[swz(r, ch)]     = *(const int4*)ksrc;
            *(int4*)&Ks[swz(r, ch + 1)] = *(const int4*)(ksrc + 8);
            const u16* vsrc = vt + vhb + (size_t)r * Ss + t0 + ch * 8;
            *(int4*)&Vt[swz(r, ch)]     = *(const int4*)vsrc;
            *(int4*)&Vt[swz(r, ch + 1)] = *(const int4*)(vsrc + 8);
        }
        __syncthreads();

        f32x4 sacc[4];
#pragma unroll
        for (int j = 0; j < 4; j++) sacc[j] = zero4;
#pragma unroll
        for (int ks = 0; ks < 2; ks++) {
#pragma unroll
            for (int j = 0; j < 4; j++) {
                bf16x8 bk = *(const bf16x8*)&Ks[swz(j * 16 + l15, ks * 4 + l4)];
                sacc[j] = __builtin_amdgcn_mfma_f32_16x16x32_bf16(aq[ks], bk, sacc[j], 0, 0, 0);
            }
        }

        float tmv[4];
        int grew = 0;
#pragma unroll
        for (int r = 0; r < 4; r++) {
            float tm = fmaxf(fmaxf(sacc[0][r], sacc[1][r]), fmaxf(sacc[2][r], sacc[3][r]));
            tm = fmaxf(tm, __shfl_xor(tm, 1));
            tm = fmaxf(tm, __shfl_xor(tm, 2));
            tm = fmaxf(tm, __shfl_xor(tm, 4));
            tm = fmaxf(tm, __shfl_xor(tm, 8));
            tmv[r] = tm;
            grew |= (tm > m_[r]);
        }

        if (__any(grew)) {
#pragma unroll
            for (int r = 0; r < 4; r++) {
                float nm = fmaxf(m_[r], tmv[r]);
                float sc = exp2_raw(m_[r] - nm);
                m_[r] = nm;
                float p0 = exp2_raw(sacc[0][r] - nm), p1 = exp2_raw(sacc[1][r] - nm);
                float p2 = exp2_raw(sacc[2][r] - nm), p3 = exp2_raw(sacc[3][r] - nm);
                int row = wq * 16 + l4 * 4 + r;
                int rx = row & 7, base = row * 64, wi = l15 & 7, hi = l15 >> 3;
                Ps[base + (((0 + hi) ^ rx) * 8) + wi] = f2bf_rz(p0);
                Ps[base + (((2 + hi) ^ rx) * 8) + wi] = f2bf_rz(p1);
                Ps[base + (((4 + hi) ^ rx) * 8) + wi] = f2bf_rz(p2);
                Ps[base + (((6 + hi) ^ rx) * 8) + wi] = f2bf_rz(p3);
                l_[r] = l_[r] * sc + (p0 + p1 + p2 + p3);
#pragma unroll
                for (int j = 0; j < 4; j++) oacc[j][r] *= sc;
            }
        } else {
#pragma unroll
            for (int r = 0; r < 4; r++) {
                float nm = m_[r];
                float p0 = exp2_raw(sacc[0][r] - nm), p1 = exp2_raw(sacc[1][r] - nm);
                float p2 = exp2_raw(sacc[2][r] - nm), p3 = exp2_raw(sacc[3][r] - nm);
                int row = wq * 16 + l4 * 4 + r;
                int rx = row & 7, base = row * 64, wi = l15 & 7, hi = l15 >> 3;
                Ps[base + (((0 + hi) ^ rx) * 8) + wi] = f2bf_rz(p0);
                Ps[base + (((2 + hi) ^ rx) * 8) + wi] = f2bf_rz(p1);
                Ps[base + (((4 + hi) ^ rx) * 8) + wi] = f2bf_rz(p2);
                Ps[base + (((6 + hi) ^ rx) * 8) + wi] = f2bf_rz(p3);
                l_[r] += p0 + p1 + p2 + p3;
            }
        }

#pragma unroll
        for (int ks = 0; ks < 2; ks++) {
            bf16x8 pa = *(const bf16x8*)&Ps[swz(wq * 16 + l15, ks * 4 + l4)];
#pragma unroll
            for (int j = 0; j < 4; j++) {
                bf16x8 bv = *(const bf16x8*)&Vt[swz(j * 16 + l15, ks * 4 + l4)];
                oacc[j] = __builtin_amdgcn_mfma_f32_16x16x32_bf16(pa, bv, oacc[j], 0, 0, 0);
            }
        }
    }

#pragma unroll
    for (int r = 0; r < 4; r++) {
        float lt = l_[r];
        lt += __shfl_xor(lt, 1);
        lt += __shfl_xor(lt, 2);
        lt += __shfl_xor(lt, 4);
        lt += __shfl_xor(lt, 8);
        float inv = 1.0f / lt;
        int row = wq * 16 + l4 * 4 + r;
        int rx = row & 7, base = row * 64, wi = l15 & 7, hi = l15 >> 3;
        Ps[base + (((0 + hi) ^ rx) * 8) + wi] = f2bf(oacc[0][r] * inv);
        Ps[base + (((2 + hi) ^ rx) * 8) + wi] = f2bf(oacc[1][r] * inv);
        Ps[base + (((4 + hi) ^ rx) * 8) + wi] = f2bf(oacc[2][r] * inv);
        Ps[base + (((6 + hi) ^ rx) * 8) + wi] = f2bf(oacc[3][r] * inv);
    }
    __syncthreads();
    {
        int r = tid >> 2, ch = (tid & 3) * 2;
        u16* dst = o + hb + (size_t)(q0 + r) * Cch + ch * 8;
        *(int4*)dst       = *(const int4*)&Ps[swz(r, ch)];
        *(int4*)(dst + 8) = *(const int4*)&Ps[swz(r, ch + 1)];
    }
}

// ---------------- final: out(B,C,S) = tmp(B,S,C)^T + x ----------------
__global__ __launch_bounds__(256) void final_out(const float* __restrict__ tmp,
                                                 const float* __restrict__ x,
                                                 float* __restrict__ outp) {
    __shared__ float tile[32][33];
    int b = blockIdx.z, c0 = blockIdx.y * 32, s0 = blockIdx.x * 32;
    int tx = threadIdx.x, ty = threadIdx.y;
#pragma unroll
    for (int i = 0; i < 4; i++) {
        int s = s0 + ty + i * 8;
        tile[ty + i * 8][tx] = tmp[((size_t)b * Ss + s) * Cch + c0 + tx];
    }
    __syncthreads();
#pragma unroll
    for (int i = 0; i < 4; i++) {
        int c = c0 + ty + i * 8;
        size_t idx = ((size_t)b * Cch + c) * Ss + s0 + tx;
        outp[idx] = tile[tx][ty + i * 8] + x[idx];
    }
}

extern "C" void kernel_launch(void* const* d_in, const int* in_sizes, int n_in,
                              void* d_out, int out_size, void* d_ws, size_t ws_size,
                              hipStream_t stream) {
    (void)in_sizes; (void)n_in; (void)out_size; (void)ws_size;
    const float* x      = (const float*)d_in[0];
    const float* gn_w   = (const float*)d_in[1];
    const float* gn_b   = (const float*)d_in[2];
    const float* pin_w  = (const float*)d_in[3];
    const float* pin_b  = (const float*)d_in[4];
    const float* ln1_w  = (const float*)d_in[5];
    const float* ln1_b  = (const float*)d_in[6];
    const float* wq     = (const float*)d_in[7];
    const float* wk     = (const float*)d_in[8];
    const float* wv     = (const float*)d_in[9];
    const float* wo     = (const float*)d_in[10];
    const float* bo     = (const float*)d_in[11];
    const float* ln3_w  = (const float*)d_in[12];
    const float* ln3_b  = (const float*)d_in[13];
    const float* wg     = (const float*)d_in[14];
    const float* bg     = (const float*)d_in[15];
    const float* wd     = (const float*)d_in[16];
    const float* bd     = (const float*)d_in[17];
    const float* pout_w = (const float*)d_in[18];
    const float* pout_b = (const float*)d_in[19];
    float* out = (float*)d_out;

    // ---- workspace layout (bytes) ----
    char* W = (char*)d_ws;
    u16* tb        = (u16*)W;                                     // t residual, bf16, 16.78 MB
    float* tmp_f32 = (float*)(W + 33554432);                      // 33.55 MB
    u16* qb    = (u16*)(W + 67108864);                            // 16.78 MB (qb,kb,vb contiguous!)
    u16* kb    = qb + 8388608;
    u16* vb    = kb + 8388608;
    u16* attnb = vb + 8388608;
    u16* Xb    = attnb + 8388608;                                 // 16.78 MB
    float* stats = (float*)(W + 67108864 + 5ull * 16777216);      // 1 KB
    u16* wbase = (u16*)(W + 67108864 + 5ull * 16777216 + 1024);
    u16* pinB  = wbase;                 // 512*512  (already [N][K])
    u16* poutB = pinB  + 262144;
    u16* wqT   = poutB + 262144;        // [512][512] transposed, scaled by QSCL
    u16* wkT   = wqT   + 262144;        // contiguous with wqT -> [1536][512] for fused qkv
    u16* wvT   = wkT   + 262144;
    u16* woT   = wvT   + 262144;
    u16* wgT   = woT   + 262144;        // [4096][512]
    u16* wdT   = wgT   + 2097152;       // [512][2048]
    u16* ag    = qb;                    // R x 2048 bf16, aliases qb..attnb (dead by then)
    u16* vtb   = (u16*)tmp_f32;         // V^T [b*8+h][64][1024], aliases tmp_f32 (dead until pout)

    dim3 tb8(32, 8);

    // stats + weight prep (fused launches)
    gn_stats<<<128, 256, 0, stream>>>(x, stats);
    conv_bf16x2<<<512, 256, 0, stream>>>(pin_w, pout_w, pinB, poutB);
    convT4_bf16<<<dim3(16, 16, 4), tb8, 0, stream>>>(wq, wk, wv, wo, wqT, wkT, wvT, woT);
    convT_bf16<<<dim3(128, 16), tb8, 0, stream>>>(wg, wgT, 512, 4096);
    convT_bf16<<<dim3(16, 64),  tb8, 0, stream>>>(wd, wdT, 2048, 512);

    // h = GN(x) transposed -> Xb (bf16)
    gn_apply_t_bf<<<dim3(32, 16, 16), tb8, 0, stream>>>(x, stats, gn_w, gn_b, Xb);

    // t = h @ pin_w^T + pin_b -> tb (bf16)
    mfma_gemm<6><<<dim3(4, 128), 256, 0, stream>>>(Xb, pinB, pin_b, nullptr, tb, 512, 512);
    // tn = ln1(t) -> Xb
    layer_norm_rows_bf<<<16384, 256, 0, stream>>>(tb, ln1_w, ln1_b, Xb);
    // fused q(scaled)/k/v: N=1536, routed to qb/kb/vb
    mfma_gemm<8><<<dim3(12, 128), 256, 0, stream>>>(Xb, wqT, nullptr, nullptr, qb, 512, 1536);
    // per-head V transpose -> vtb
    vtrans<<<dim3(16, 8, 16), 256, 0, stream>>>(vb, vtb);
    // attention (MFMA) -> attnb (bf16)
    flash_attn_mfma<<<dim3(16, 8, 16), 256, 0, stream>>>(qb, kb, vtb, attnb);
    // t += attn @ wo + bo (bf16 in-place on tb)
    mfma_gemm<7><<<dim3(4, 128), 256, 0, stream>>>(attnb, woT, bo, nullptr, tb, 512, 512);
    // tn3 = ln3(t) -> Xb
    layer_norm_rows_bf<<<16384, 256, 0, stream>>>(tb, ln3_w, ln3_b, Xb);
    // ag = a * gelu(g) (bf16), aliases q/k/v/attn space
    geglu_mfma<<<dim3(32, 128), 256, 0, stream>>>(Xb, wgT, bg, ag);
    // t += ag @ wd + bd (bf16 in-place on tb)
    mfma_gemm<7><<<dim3(4, 128), 256, 0, stream>>>(ag, wdT, bd, nullptr, tb, 2048, 512);
    // tmp = t @ pout_w^T + pout_b -> tmp_f32
    mfma_gemm<1><<<dim3(4, 128), 256, 0, stream>>>(tb, poutB, pout_b, tmp_f32, nullptr, 512, 512);
    // out = tmp^T + x
    final_out<<<dim3(32, 16, 16), tb8, 0, stream>>>(tmp_f32, x, out);
}

// Round 20
// 461.486 us; speedup vs baseline: 1.2096x; 1.0881x over previous
//
#include <hip/hip_runtime.h>
#include <hip/hip_bf16.h>
#include <math.h>

typedef unsigned short u16;
typedef __attribute__((ext_vector_type(8))) short bf16x8;
typedef __attribute__((ext_vector_type(4))) float f32x4;

#define Bb 16
#define Cch 512
#define Ss 1024
#define NHh 8
#define DHh 64
#define CPG 64
#define EPSV 1e-5f
#define R_TOTAL (Bb*Ss)   // 16384
#define QSCL 0.18033688011112042f   // 0.125 * log2(e)

__device__ inline u16 f2bf(float f) {
    unsigned int u = __float_as_uint(f);
    unsigned int r = (u + 0x7fffu + ((u >> 16) & 1u)) >> 16;
    return (u16)r;
}
__device__ inline u16 f2bf_rz(float f) { return (u16)(__float_as_uint(f) >> 16); }
__device__ inline float bf2f(u16 v) { return __uint_as_float((unsigned)v << 16); }
__device__ inline float exp2_raw(float x) {
    float r; asm("v_exp_f32 %0, %1" : "=v"(r) : "v"(x)); return r;
}

// swizzles: 16B chunk XOR'd by row&7 (conflict-free fragment reads, measured r14/r19)
__device__ inline int swz(int row, int chunk) {      // row stride 64 u16 (8 chunks)
    return row * 64 + ((chunk ^ (row & 7)) * 8);
}
__device__ inline int swz128(int row, int chunk) {   // row stride 128 u16 (16 chunks)
    return row * 128 + ((chunk ^ (row & 7)) * 8);
}
__device__ inline int swzg(int r, int c) {           // GEMM [R][32] tile
    int span = r >> 1;
    int c8 = ((r & 1) << 2) | c;
    return span * 64 + ((c8 ^ (span & 7)) * 8);
}

// ---------------- GroupNorm stats (float4 loads) ----------------
__global__ __launch_bounds__(256) void gn_stats(const float* __restrict__ x,
                                                float* __restrict__ stats) {
    int bg = blockIdx.x;
    int b = bg >> 3, g = bg & 7;
    const float4* base = (const float4*)(x + ((size_t)b * Cch + (size_t)g * CPG) * Ss);
    float s = 0.f, ss = 0.f;
    for (int i = threadIdx.x; i < CPG * Ss / 4; i += 256) {
        float4 v = base[i];
        s  += v.x + v.y + v.z + v.w;
        ss += v.x * v.x + v.y * v.y + v.z * v.z + v.w * v.w;
    }
    for (int o = 32; o > 0; o >>= 1) { s += __shfl_down(s, o); ss += __shfl_down(ss, o); }
    __shared__ float red[2][4];
    int wid = threadIdx.x >> 6, lane = threadIdx.x & 63;
    if (lane == 0) { red[0][wid] = s; red[1][wid] = ss; }
    __syncthreads();
    if (threadIdx.x == 0) {
        float S1 = red[0][0] + red[0][1] + red[0][2] + red[0][3];
        float S2 = red[1][0] + red[1][1] + red[1][2] + red[1][3];
        const float inv_n = 1.0f / (CPG * Ss);
        float mu = S1 * inv_n;
        float var = S2 * inv_n - mu * mu;
        stats[bg * 2]     = mu;
        stats[bg * 2 + 1] = rsqrtf(var + EPSV);
    }
}

// ---------------- GroupNorm apply + transpose -> bf16 (B,S,C) ----------------
__global__ __launch_bounds__(256) void gn_apply_t_bf(const float* __restrict__ x,
                                                     const float* __restrict__ stats,
                                                     const float* __restrict__ gw,
                                                     const float* __restrict__ gb,
                                                     u16* __restrict__ ht) {
    __shared__ float tile[32][33];
    int b  = blockIdx.z;
    int c0 = blockIdx.y * 32;
    int s0 = blockIdx.x * 32;
    int tx = threadIdx.x, ty = threadIdx.y;
#pragma unroll
    for (int i = 0; i < 4; i++) {
        int c = c0 + ty + i * 8;
        int g = c >> 6;
        float mu = stats[(b * 8 + g) * 2];
        float rs = stats[(b * 8 + g) * 2 + 1];
        float v = x[((size_t)b * Cch + c) * Ss + s0 + tx];
        tile[ty + i * 8][tx] = (v - mu) * rs * gw[c] + gb[c];
    }
    __syncthreads();
#pragma unroll
    for (int i = 0; i < 4; i++) {
        int s = s0 + ty + i * 8;
        ht[((size_t)b * Ss + s) * Cch + c0 + tx] = f2bf(tile[tx][ty + i * 8]);
    }
}

// ---------------- fused weight prep: ALL conversions/transposes in 1 launch ----------
// blocks [0,512):    pin_w/pout_w straight convert (float4)
// blocks [512,1536): wq(scaled)/wk/wv/wo 512x512 transpose  (4 x 256)
// blocks [1536,3584): wg transpose (4096 cols x 512 rows -> [4096][512])
// blocks [3584,4608): wd transpose (512 cols x 2048 rows -> [512][2048])
__global__ __launch_bounds__(256) void prep_all(const float* __restrict__ pin_w,
                                                const float* __restrict__ pout_w,
                                                u16* __restrict__ pinB,
                                                u16* __restrict__ poutB,
                                                const float* __restrict__ wq,
                                                const float* __restrict__ wk,
                                                const float* __restrict__ wv,
                                                const float* __restrict__ wo,
                                                u16* __restrict__ wqT,
                                                u16* __restrict__ wkT,
                                                u16* __restrict__ wvT,
                                                u16* __restrict__ woT,
                                                const float* __restrict__ wg,
                                                u16* __restrict__ wgT,
                                                const float* __restrict__ wd,
                                                u16* __restrict__ wdT) {
    __shared__ float tile[32][33];
    int bid = blockIdx.x;
    int tx = threadIdx.x, ty = threadIdx.y;
    int tid = ty * 32 + tx;
    if (bid < 512) {
        int base = bid * 1024 + tid * 4;
        const float* src; u16* dst; int off;
        if (base < 262144) { src = pin_w;  dst = pinB;  off = base; }
        else               { src = pout_w; dst = poutB; off = base - 262144; }
        float4 v = *(const float4*)&src[off];
        ushort4 o;
        o.x = f2bf(v.x); o.y = f2bf(v.y); o.z = f2bf(v.z); o.w = f2bf(v.w);
        *(ushort4*)&dst[off] = o;
        return;
    }
    const float* in; u16* outp; int c0, r0, C, R; float scl = 1.0f;
    if (bid < 1536) {
        int z = (bid - 512) >> 8, rem = (bid - 512) & 255;
        switch (z) {
            case 0: in = wq; outp = wqT; scl = QSCL; break;
            case 1: in = wk; outp = wkT; break;
            case 2: in = wv; outp = wvT; break;
            default: in = wo; outp = woT; break;
        }
        c0 = (rem & 15) * 32; r0 = (rem >> 4) * 32; C = 512; R = 512;
    } else if (bid < 3584) {
        int rem = bid - 1536;
        in = wg; outp = wgT; C = 4096; R = 512;
        c0 = (rem & 127) * 32; r0 = (rem >> 7) * 32;
    } else {
        int rem = bid - 3584;
        in = wd; outp = wdT; C = 512; R = 2048;
        c0 = (rem & 15) * 32; r0 = (rem >> 4) * 32;
    }
#pragma unroll
    for (int i = 0; i < 4; i++)
        tile[ty + i * 8][tx] = in[(size_t)(r0 + ty + i * 8) * C + c0 + tx] * scl;
    __syncthreads();
#pragma unroll
    for (int i = 0; i < 4; i++)
        outp[(size_t)(c0 + ty + i * 8) * R + r0 + tx] = f2bf(tile[tx][ty + i * 8]);
}

// ---------------- per-head V transpose: vb [b][s][512] -> vt [(b*8+h)][64][1024] ----------
__global__ __launch_bounds__(256) void vtrans(const u16* __restrict__ in,
                                              u16* __restrict__ outp) {
    __shared__ u16 tile[64][66];
    int s0 = blockIdx.x * 64, h = blockIdx.y, b = blockIdx.z;
    const u16* src = in + ((size_t)b * Ss + s0) * Cch + h * 64;
    int r = threadIdx.x >> 3, c8 = (threadIdx.x & 7) * 8;
#pragma unroll
    for (int p = 0; p < 2; p++) {
        int rr = r + p * 32;
        *(int4*)&tile[rr][c8] = *(const int4*)&src[(size_t)rr * Cch + c8];
    }
    __syncthreads();
    u16* dst = outp + ((size_t)(b * 8 + h) * 64) * Ss + s0;
#pragma unroll
    for (int p = 0; p < 2; p++) {
        int d = r + p * 32;
        u16 vals[8];
#pragma unroll
        for (int e = 0; e < 8; e++) vals[e] = tile[c8 + e][d];
        *(int4*)&dst[(size_t)d * Ss + c8] = *(int4*)vals;
    }
}

// ---------------- LayerNorm rows (bf16 in, bf16 out) ----------------
__global__ __launch_bounds__(256) void layer_norm_rows_bf(const u16* __restrict__ in,
                                                          const float* __restrict__ w,
                                                          const float* __restrict__ bb,
                                                          u16* __restrict__ outp) {
    int row = blockIdx.x;
    const u16* p = in + (size_t)row * Cch;
    int i0 = threadIdx.x * 2;
    ushort2 u = *(const ushort2*)&p[i0];
    float v0 = bf2f(u.x), v1 = bf2f(u.y);
    float s = v0 + v1, ss = v0 * v0 + v1 * v1;
    for (int o = 32; o > 0; o >>= 1) { s += __shfl_down(s, o); ss += __shfl_down(ss, o); }
    __shared__ float red[2][4];
    __shared__ float mu_s, rs_s;
    int wid = threadIdx.x >> 6, lane = threadIdx.x & 63;
    if (lane == 0) { red[0][wid] = s; red[1][wid] = ss; }
    __syncthreads();
    if (threadIdx.x == 0) {
        float S1 = red[0][0] + red[0][1] + red[0][2] + red[0][3];
        float S2 = red[1][0] + red[1][1] + red[1][2] + red[1][3];
        float mu = S1 * (1.0f / Cch);
        float var = S2 * (1.0f / Cch) - mu * mu;
        mu_s = mu; rs_s = rsqrtf(var + EPSV);
    }
    __syncthreads();
    float mu = mu_s, rs = rs_s;
    outp[(size_t)row * Cch + i0]     = f2bf((v0 - mu) * rs * w[i0] + bb[i0]);
    outp[(size_t)row * Cch + i0 + 1] = f2bf((v1 - mu) * rs * w[i0 + 1] + bb[i0 + 1]);
}

// ---------------- MFMA GEMM: out(MxN) = A(MxK bf16) @ Bt(NxK bf16)^T ----------------
// 128x128 tile, BK=32, 4 waves (2x2). Reg-staged prefetch + swizzled LDS (swzg).
// EPI: 0 = bf16; 1 = fp32 +bias; 6 = bf16 +bias; 7 = bf16 +bias + bf16 residual in-place;
//      8 = bf16 routed qkv (outb base = qb; col>>9 selects q/k/v slot, 8388608 apart).
template<int EPI>
__global__ __launch_bounds__(256) void mfma_gemm(const u16* __restrict__ A,
                                                 const u16* __restrict__ Bt,
                                                 const float* __restrict__ bias,
                                                 float* __restrict__ fout,
                                                 u16* __restrict__ outb,
                                                 int K, int N) {
    __shared__ u16 As[128 * 32];
    __shared__ u16 Bs[128 * 32];
    int tid = threadIdx.x;
    int m0 = blockIdx.y * 128, n0 = blockIdx.x * 128;
    int wave = tid >> 6, lane = tid & 63;
    int wr = wave >> 1, wc = wave & 1;
    int l15 = lane & 15, l4 = lane >> 4;

    f32x4 zero4 = {0.f, 0.f, 0.f, 0.f};
    f32x4 acc[4][4];
#pragma unroll
    for (int i = 0; i < 4; i++)
#pragma unroll
        for (int j = 0; j < 4; j++) acc[i][j] = zero4;

    int srow = tid >> 1;
    int sc0  = (tid & 1) * 2;
    int se   = sc0 * 8;

    int4 ra0, ra1, rb0, rb1;
    {
        const u16* pa = A  + (size_t)(m0 + srow) * K + se;
        ra0 = *(const int4*)pa; ra1 = *(const int4*)(pa + 8);
        const u16* pb = Bt + (size_t)(n0 + srow) * K + se;
        rb0 = *(const int4*)pb; rb1 = *(const int4*)(pb + 8);
    }
    for (int kt = 0; kt < K; kt += 32) {
        __syncthreads();
        *(int4*)&As[swzg(srow, sc0)]     = ra0;
        *(int4*)&As[swzg(srow, sc0 + 1)] = ra1;
        *(int4*)&Bs[swzg(srow, sc0)]     = rb0;
        *(int4*)&Bs[swzg(srow, sc0 + 1)] = rb1;
        __syncthreads();
        int kn = kt + 32;
        if (kn < K) {
            const u16* pa = A  + (size_t)(m0 + srow) * K + kn + se;
            ra0 = *(const int4*)pa; ra1 = *(const int4*)(pa + 8);
            const u16* pb = Bt + (size_t)(n0 + srow) * K + kn + se;
            rb0 = *(const int4*)pb; rb1 = *(const int4*)(pb + 8);
        }
        bf16x8 af[4], bfr[4];
#pragma unroll
        for (int mi = 0; mi < 4; mi++)
            af[mi] = *(const bf16x8*)&As[swzg(wr * 64 + mi * 16 + l15, l4)];
#pragma unroll
        for (int nj = 0; nj < 4; nj++)
            bfr[nj] = *(const bf16x8*)&Bs[swzg(wc * 64 + nj * 16 + l15, l4)];
#pragma unroll
        for (int mi = 0; mi < 4; mi++)
#pragma unroll
            for (int nj = 0; nj < 4; nj++)
                acc[mi][nj] = __builtin_amdgcn_mfma_f32_16x16x32_bf16(af[mi], bfr[nj], acc[mi][nj], 0, 0, 0);
    }

#pragma unroll
    for (int mi = 0; mi < 4; mi++)
#pragma unroll
        for (int nj = 0; nj < 4; nj++)
#pragma unroll
            for (int r = 0; r < 4; r++) {
                int row = m0 + wr * 64 + mi * 16 + l4 * 4 + r;
                int col = n0 + wc * 64 + nj * 16 + l15;
                float v = acc[mi][nj][r];
                if constexpr (EPI == 0) {
                    outb[(size_t)row * N + col] = f2bf(v);
                } else if constexpr (EPI == 1) {
                    fout[(size_t)row * N + col] = v + bias[col];
                } else if constexpr (EPI == 6) {
                    outb[(size_t)row * N + col] = f2bf(v + bias[col]);
                } else if constexpr (EPI == 7) {
                    size_t idx = (size_t)row * N + col;
                    v += bias[col] + bf2f(outb[idx]);
                    outb[idx] = f2bf(v);
                } else if constexpr (EPI == 8) {
                    size_t idx = (size_t)(col >> 9) * 8388608 + (size_t)row * 512 + (col & 511);
                    outb[idx] = f2bf(v);
                }
            }
}

// ---------------- GEGLU MFMA: both halves of tn3 @ wg, fused exact GELU, bf16 out --------
__global__ __launch_bounds__(256) void geglu_mfma(const u16* __restrict__ A,
                                                  const u16* __restrict__ WgT,  // [4096][512]
                                                  const float* __restrict__ bg,
                                                  u16* __restrict__ ag) {
    __shared__ u16 As[128 * 32];
    __shared__ u16 Bs1[64 * 32];
    __shared__ u16 Bs2[64 * 32];
    const int K = 512;
    int tid = threadIdx.x;
    int m0 = blockIdx.y * 128, n0 = blockIdx.x * 64;
    int wave = tid >> 6, lane = tid & 63;
    int wr = wave >> 1, wc = wave & 1;
    int l15 = lane & 15, l4 = lane >> 4;

    f32x4 zero4 = {0.f, 0.f, 0.f, 0.f};
    f32x4 accA[4][2], accG[4][2];
#pragma unroll
    for (int i = 0; i < 4; i++) { accA[i][0] = zero4; accA[i][1] = zero4; accG[i][0] = zero4; accG[i][1] = zero4; }

    int srow = tid >> 1;
    int sc0  = (tid & 1) * 2;
    int se   = sc0 * 8;
    int brow = tid >> 2;
    int bch  = tid & 3;
    int bqe  = bch * 8;

    int4 ra0, ra1, rb1, rb2;
    {
        const u16* pa = A + (size_t)(m0 + srow) * K + se;
        ra0 = *(const int4*)pa; ra1 = *(const int4*)(pa + 8);
        rb1 = *(const int4*)(WgT + (size_t)(n0 + brow) * K + bqe);
        rb2 = *(const int4*)(WgT + (size_t)(2048 + n0 + brow) * K + bqe);
    }
    for (int kt = 0; kt < K; kt += 32) {
        __syncthreads();
        *(int4*)&As[swzg(srow, sc0)]     = ra0;
        *(int4*)&As[swzg(srow, sc0 + 1)] = ra1;
        *(int4*)&Bs1[swzg(brow, bch)]    = rb1;
        *(int4*)&Bs2[swzg(brow, bch)]    = rb2;
        __syncthreads();
        int kn = kt + 32;
        if (kn < K) {
            const u16* pa = A + (size_t)(m0 + srow) * K + kn + se;
            ra0 = *(const int4*)pa; ra1 = *(const int4*)(pa + 8);
            rb1 = *(const int4*)(WgT + (size_t)(n0 + brow) * K + kn + bqe);
            rb2 = *(const int4*)(WgT + (size_t)(2048 + n0 + brow) * K + kn + bqe);
        }
        bf16x8 af[4], b1[2], b2[2];
#pragma unroll
        for (int mi = 0; mi < 4; mi++)
            af[mi] = *(const bf16x8*)&As[swzg(wr * 64 + mi * 16 + l15, l4)];
#pragma unroll
        for (int nj = 0; nj < 2; nj++) {
            b1[nj] = *(const bf16x8*)&Bs1[swzg(wc * 32 + nj * 16 + l15, l4)];
            b2[nj] = *(const bf16x8*)&Bs2[swzg(wc * 32 + nj * 16 + l15, l4)];
        }
#pragma unroll
        for (int mi = 0; mi < 4; mi++)
#pragma unroll
            for (int nj = 0; nj < 2; nj++) {
                accA[mi][nj] = __builtin_amdgcn_mfma_f32_16x16x32_bf16(af[mi], b1[nj], accA[mi][nj], 0, 0, 0);
                accG[mi][nj] = __builtin_amdgcn_mfma_f32_16x16x32_bf16(af[mi], b2[nj], accG[mi][nj], 0, 0, 0);
            }
    }

#pragma unroll
    for (int mi = 0; mi < 4; mi++)
#pragma unroll
        for (int nj = 0; nj < 2; nj++)
#pragma unroll
            for (int r = 0; r < 4; r++) {
                int row = m0 + wr * 64 + mi * 16 + l4 * 4 + r;
                int col = n0 + wc * 32 + nj * 16 + l15;
                float a = accA[mi][nj][r] + bg[col];
                float g = accG[mi][nj][r] + bg[2048 + col];
                float ge = 0.5f * g * (1.0f + erff(g * 0.70710678118654752f));
                ag[(size_t)row * 2048 + col] = f2bf(a * ge);
            }
}

// ---------------- MFMA flash attention: KVBLK=128, log2 softmax, swizzled LDS ------------
// 8 KV-tiles of 128 (was 16 of 64): halves barriers + shuffle-max reductions.
// LDS 48 KB: Ps[64][128] (Q stage -> P -> O stage), Ks[128][64], Vt[64][128].
__global__ __launch_bounds__(256) void flash_attn_mfma(const u16* __restrict__ q,
                                                       const u16* __restrict__ k,
                                                       const u16* __restrict__ vt,  // [b*8+h][64][1024]
                                                       u16* __restrict__ o) {
    __shared__ u16 Ps[64 * 128];
    __shared__ u16 Ks[128 * 64];
    __shared__ u16 Vt[64 * 128];
    const int tid = threadIdx.x;
    const int h = blockIdx.y, b = blockIdx.z;
    const int q0 = blockIdx.x * 64;
    const size_t hb  = (size_t)b * Ss * Cch + (size_t)h * DHh;
    const size_t vhb = ((size_t)(b * NHh + h) * DHh) * Ss;

    const int wq = tid >> 6;
    const int lane = tid & 63;
    const int l15 = lane & 15, l4 = lane >> 4;

    // stage Q (64x64) into Ps (row stride 128, chunks 0..7), coalesced
    {
        int r = tid >> 2, ch = (tid & 3) * 2;
        const u16* src = q + hb + (size_t)(q0 + r) * Cch + ch * 8;
        *(int4*)&Ps[swz128(r, ch)]     = *(const int4*)src;
        *(int4*)&Ps[swz128(r, ch + 1)] = *(const int4*)(src + 8);
    }
    __syncthreads();
    bf16x8 aq[2];
    aq[0] = *(const bf16x8*)&Ps[swz128(wq * 16 + l15, 0 * 4 + l4)];
    aq[1] = *(const bf16x8*)&Ps[swz128(wq * 16 + l15, 1 * 4 + l4)];

    f32x4 zero4 = {0.f, 0.f, 0.f, 0.f};
    f32x4 oacc[4];
    float m_[4], l_[4];
#pragma unroll
    for (int j = 0; j < 4; j++) oacc[j] = zero4;
#pragma unroll
    for (int r = 0; r < 4; r++) { m_[r] = -1e30f; l_[r] = 0.f; }

    for (int t0 = 0; t0 < Ss; t0 += 128) {
        __syncthreads();
        {
            // K: 128 rows x 64 u16; thread: row tid>>1, chunks (tid&1)*4 .. +3
            int r = tid >> 1, c4 = (tid & 1) * 4;
            const u16* ksrc = k + hb + (size_t)(t0 + r) * Cch + c4 * 8;
            *(int4*)&Ks[swz(r, c4)]     = *(const int4*)ksrc;
            *(int4*)&Ks[swz(r, c4 + 1)] = *(const int4*)(ksrc + 8);
            *(int4*)&Ks[swz(r, c4 + 2)] = *(const int4*)(ksrc + 16);
            *(int4*)&Ks[swz(r, c4 + 3)] = *(const int4*)(ksrc + 24);
            // V: 64 rows x 128 u16; thread: row tid>>2, chunks (tid&3)*4 .. +3
            int d = tid >> 2, cv = (tid & 3) * 4;
            const u16* vsrc = vt + vhb + (size_t)d * Ss + t0 + cv * 8;
            *(int4*)&Vt[swz128(d, cv)]     = *(const int4*)vsrc;
            *(int4*)&Vt[swz128(d, cv + 1)] = *(const int4*)(vsrc + 8);
            *(int4*)&Vt[swz128(d, cv + 2)] = *(const int4*)(vsrc + 16);
            *(int4*)&Vt[swz128(d, cv + 3)] = *(const int4*)(vsrc + 24);
        }
        __syncthreads();

        // QK^T (log2-scaled): wave's 16 q-rows x 128 t-cols
        f32x4 sacc[8];
#pragma unroll
        for (int j = 0; j < 8; j++) sacc[j] = zero4;
#pragma unroll
        for (int ks = 0; ks < 2; ks++) {
#pragma unroll
            for (int j = 0; j < 8; j++) {
                bf16x8 bk = *(const bf16x8*)&Ks[swz(j * 16 + l15, ks * 4 + l4)];
                sacc[j] = __builtin_amdgcn_mfma_f32_16x16x32_bf16(aq[ks], bk, sacc[j], 0, 0, 0);
            }
        }

        // per-row tile max + defer-max decision
        float tmv[4];
        int grew = 0;
#pragma unroll
        for (int r = 0; r < 4; r++) {
            float tm = fmaxf(fmaxf(fmaxf(sacc[0][r], sacc[1][r]), fmaxf(sacc[2][r], sacc[3][r])),
                             fmaxf(fmaxf(sacc[4][r], sacc[5][r]), fmaxf(sacc[6][r], sacc[7][r])));
            tm = fmaxf(tm, __shfl_xor(tm, 1));
            tm = fmaxf(tm, __shfl_xor(tm, 2));
            tm = fmaxf(tm, __shfl_xor(tm, 4));
            tm = fmaxf(tm, __shfl_xor(tm, 8));
            tmv[r] = tm;
            grew |= (tm > m_[r]);
        }

        if (__any(grew)) {
#pragma unroll
            for (int r = 0; r < 4; r++) {
                float nm = fmaxf(m_[r], tmv[r]);
                float sc = exp2_raw(m_[r] - nm);
                m_[r] = nm;
                int row = wq * 16 + l4 * 4 + r;
                int rx = row & 7, base = row * 128, wi = l15 & 7, hi = l15 >> 3;
                float rs = 0.f;
#pragma unroll
                for (int j = 0; j < 8; j++) {
                    float p = exp2_raw(sacc[j][r] - nm);
                    Ps[base + (((2 * j + hi) ^ rx) * 8) + wi] = f2bf_rz(p);
                    rs += p;
                }
                l_[r] = l_[r] * sc + rs;
#pragma unroll
                for (int j = 0; j < 4; j++) oacc[j][r] *= sc;
            }
        } else {
#pragma unroll
            for (int r = 0; r < 4; r++) {
                float nm = m_[r];
                int row = wq * 16 + l4 * 4 + r;
                int rx = row & 7, base = row * 128, wi = l15 & 7, hi = l15 >> 3;
                float rs = 0.f;
#pragma unroll
                for (int j = 0; j < 8; j++) {
                    float p = exp2_raw(sacc[j][r] - nm);
                    Ps[base + (((2 * j + hi) ^ rx) * 8) + wi] = f2bf_rz(p);
                    rs += p;
                }
                l_[r] += rs;
            }
        }

        // PV: A=Ps (wave-private rows, k=128 -> 4 ks), Bt=Vt[d][t]
#pragma unroll
        for (int ks = 0; ks < 4; ks++) {
            bf16x8 pa = *(const bf16x8*)&Ps[swz128(wq * 16 + l15, ks * 4 + l4)];
#pragma unroll
            for (int j = 0; j < 4; j++) {
                bf16x8 bv = *(const bf16x8*)&Vt[swz128(j * 16 + l15, ks * 4 + l4)];
                oacc[j] = __builtin_amdgcn_mfma_f32_16x16x32_bf16(pa, bv, oacc[j], 0, 0, 0);
            }
        }
    }

    // finalize: reduce per-lane l partials, O /= l, stage via Ps, coalesced store
#pragma unroll
    for (int r = 0; r < 4; r++) {
        float lt = l_[r];
        lt += __shfl_xor(lt, 1);
        lt += __shfl_xor(lt, 2);
        lt += __shfl_xor(lt, 4);
        lt += __shfl_xor(lt, 8);
        float inv = 1.0f / lt;
        int row = wq * 16 + l4 * 4 + r;
        int rx = row & 7, base = row * 128, wi = l15 & 7, hi = l15 >> 3;
#pragma unroll
        for (int j = 0; j < 4; j++)
            Ps[base + (((2 * j + hi) ^ rx) * 8) + wi] = f2bf(oacc[j][r] * inv);
    }
    __syncthreads();
    {
        int r = tid >> 2, ch = (tid & 3) * 2;
        u16* dst = o + hb + (size_t)(q0 + r) * Cch + ch * 8;
        *(int4*)dst       = *(const int4*)&Ps[swz128(r, ch)];
        *(int4*)(dst + 8) = *(const int4*)&Ps[swz128(r, ch + 1)];
    }
}

// ---------------- final: out(B,C,S) = tmp(B,S,C)^T + x ----------------
__global__ __launch_bounds__(256) void final_out(const float* __restrict__ tmp,
                                                 const float* __restrict__ x,
                                                 float* __restrict__ outp) {
    __shared__ float tile[32][33];
    int b = blockIdx.z, c0 = blockIdx.y * 32, s0 = blockIdx.x * 32;
    int tx = threadIdx.x, ty = threadIdx.y;
#pragma unroll
    for (int i = 0; i < 4; i++) {
        int s = s0 + ty + i * 8;
        tile[ty + i * 8][tx] = tmp[((size_t)b * Ss + s) * Cch + c0 + tx];
    }
    __syncthreads();
#pragma unroll
    for (int i = 0; i < 4; i++) {
        int c = c0 + ty + i * 8;
        size_t idx = ((size_t)b * Cch + c) * Ss + s0 + tx;
        outp[idx] = tile[tx][ty + i * 8] + x[idx];
    }
}

extern "C" void kernel_launch(void* const* d_in, const int* in_sizes, int n_in,
                              void* d_out, int out_size, void* d_ws, size_t ws_size,
                              hipStream_t stream) {
    (void)in_sizes; (void)n_in; (void)out_size; (void)ws_size;
    const float* x      = (const float*)d_in[0];
    const float* gn_w   = (const float*)d_in[1];
    const float* gn_b   = (const float*)d_in[2];
    const float* pin_w  = (const float*)d_in[3];
    const float* pin_b  = (const float*)d_in[4];
    const float* ln1_w  = (const float*)d_in[5];
    const float* ln1_b  = (const float*)d_in[6];
    const float* wq     = (const float*)d_in[7];
    const float* wk     = (const float*)d_in[8];
    const float* wv     = (const float*)d_in[9];
    const float* wo     = (const float*)d_in[10];
    const float* bo     = (const float*)d_in[11];
    const float* ln3_w  = (const float*)d_in[12];
    const float* ln3_b  = (const float*)d_in[13];
    const float* wg     = (const float*)d_in[14];
    const float* bg     = (const float*)d_in[15];
    const float* wd     = (const float*)d_in[16];
    const float* bd     = (const float*)d_in[17];
    const float* pout_w = (const float*)d_in[18];
    const float* pout_b = (const float*)d_in[19];
    float* out = (float*)d_out;

    // ---- workspace layout (bytes) ----
    char* W = (char*)d_ws;
    u16* tb        = (u16*)W;                                     // t residual, bf16, 16.78 MB
    float* tmp_f32 = (float*)(W + 33554432);                      // 33.55 MB
    u16* qb    = (u16*)(W + 67108864);                            // 16.78 MB (qb,kb,vb contiguous)
    u16* kb    = qb + 8388608;
    u16* vb    = kb + 8388608;
    u16* attnb = vb + 8388608;
    u16* Xb    = attnb + 8388608;                                 // 16.78 MB
    float* stats = (float*)(W + 67108864 + 5ull * 16777216);      // 1 KB
    u16* wbase = (u16*)(W + 67108864 + 5ull * 16777216 + 1024);
    u16* pinB  = wbase;                 // 512*512  (already [N][K])
    u16* poutB = pinB  + 262144;
    u16* wqT   = poutB + 262144;        // [512][512] transposed, scaled by QSCL
    u16* wkT   = wqT   + 262144;        // contiguous with wqT -> [1536][512] for fused qkv
    u16* wvT   = wkT   + 262144;
    u16* woT   = wvT   + 262144;
    u16* wgT   = woT   + 262144;        // [4096][512]
    u16* wdT   = wgT   + 2097152;       // [512][2048]
    u16* ag    = qb;                    // R x 2048 bf16, aliases qb..attnb (dead by then)
    u16* vtb   = (u16*)tmp_f32;         // V^T [b*8+h][64][1024], aliases tmp_f32 (dead until pout)

    dim3 tb8(32, 8);

    // stats + fused weight prep (2 launches)
    gn_stats<<<128, 256, 0, stream>>>(x, stats);
    prep_all<<<4608, tb8, 0, stream>>>(pin_w, pout_w, pinB, poutB,
                                       wq, wk, wv, wo, wqT, wkT, wvT, woT,
                                       wg, wgT, wd, wdT);

    // h = GN(x) transposed -> Xb (bf16)
    gn_apply_t_bf<<<dim3(32, 16, 16), tb8, 0, stream>>>(x, stats, gn_w, gn_b, Xb);

    // t = h @ pin_w^T + pin_b -> tb (bf16)
    mfma_gemm<6><<<dim3(4, 128), 256, 0, stream>>>(Xb, pinB, pin_b, nullptr, tb, 512, 512);
    // tn = ln1(t) -> Xb
    layer_norm_rows_bf<<<16384, 256, 0, stream>>>(tb, ln1_w, ln1_b, Xb);
    // fused q(scaled)/k/v: N=1536, routed to qb/kb/vb
    mfma_gemm<8><<<dim3(12, 128), 256, 0, stream>>>(Xb, wqT, nullptr, nullptr, qb, 512, 1536);
    // per-head V transpose -> vtb
    vtrans<<<dim3(16, 8, 16), 256, 0, stream>>>(vb, vtb);
    // attention (MFMA, KVBLK=128) -> attnb (bf16)
    flash_attn_mfma<<<dim3(16, 8, 16), 256, 0, stream>>>(qb, kb, vtb, attnb);
    // t += attn @ wo + bo (bf16 in-place on tb)
    mfma_gemm<7><<<dim3(4, 128), 256, 0, stream>>>(attnb, woT, bo, nullptr, tb, 512, 512);
    // tn3 = ln3(t) -> Xb
    layer_norm_rows_bf<<<16384, 256, 0, stream>>>(tb, ln3_w, ln3_b, Xb);
    // ag = a * gelu(g) (bf16), aliases q/k/v/attn space
    geglu_mfma<<<dim3(32, 128), 256, 0, stream>>>(Xb, wgT, bg, ag);
    // t += ag @ wd + bd (bf16 in-place on tb)
    mfma_gemm<7><<<dim3(4, 128), 256, 0, stream>>>(ag, wdT, bd, nullptr, tb, 2048, 512);
    // tmp = t @ pout_w^T + pout_b -> tmp_f32
    mfma_gemm<1><<<dim3(4, 128), 256, 0, stream>>>(tb, poutB, pout_b, tmp_f32, nullptr, 512, 512);
    // out = tmp^T + x
    final_out<<<dim3(32, 16, 16), tb8, 0, stream>>>(tmp_f32, x, out);
}

// Round 23
// 446.429 us; speedup vs baseline: 1.2504x; 1.0337x over previous
//
#include <hip/hip_runtime.h>
#include <hip/hip_bf16.h>
#include <math.h>

typedef unsigned short u16;
typedef __attribute__((ext_vector_type(8))) short bf16x8;
typedef __attribute__((ext_vector_type(4))) float f32x4;

#define Bb 16
#define Cch 512
#define Ss 1024
#define NHh 8
#define DHh 64
#define CPG 64
#define EPSV 1e-5f
#define R_TOTAL (Bb*Ss)   // 16384
#define QSCL 0.18033688011112042f   // 0.125 * log2(e)

__device__ inline u16 f2bf(float f) {
    unsigned int u = __float_as_uint(f);
    unsigned int r = (u + 0x7fffu + ((u >> 16) & 1u)) >> 16;
    return (u16)r;
}
__device__ inline u16 f2bf_rz(float f) { return (u16)(__float_as_uint(f) >> 16); }
__device__ inline float bf2f(u16 v) { return __uint_as_float((unsigned)v << 16); }
__device__ inline float exp2_raw(float x) {
    float r; asm("v_exp_f32 %0, %1" : "=v"(r) : "v"(x)); return r;
}

// swizzles: 16B chunk XOR'd by row&7 (conflict-free fragment reads, measured r14/r19)
__device__ inline int swz(int row, int chunk) {      // row stride 64 u16 (8 chunks)
    return row * 64 + ((chunk ^ (row & 7)) * 8);
}
__device__ inline int swz128(int row, int chunk) {   // row stride 128 u16 (16 chunks)
    return row * 128 + ((chunk ^ (row & 7)) * 8);
}
__device__ inline int swzg(int r, int c) {           // GEMM [R][32] tile
    int span = r >> 1;
    int c8 = ((r & 1) << 2) | c;
    return span * 64 + ((c8 ^ (span & 7)) * 8);
}

// ---------------- GroupNorm stats (float4 loads) ----------------
__global__ __launch_bounds__(256) void gn_stats(const float* __restrict__ x,
                                                float* __restrict__ stats) {
    int bg = blockIdx.x;
    int b = bg >> 3, g = bg & 7;
    const float4* base = (const float4*)(x + ((size_t)b * Cch + (size_t)g * CPG) * Ss);
    float s = 0.f, ss = 0.f;
    for (int i = threadIdx.x; i < CPG * Ss / 4; i += 256) {
        float4 v = base[i];
        s  += v.x + v.y + v.z + v.w;
        ss += v.x * v.x + v.y * v.y + v.z * v.z + v.w * v.w;
    }
    for (int o = 32; o > 0; o >>= 1) { s += __shfl_down(s, o); ss += __shfl_down(ss, o); }
    __shared__ float red[2][4];
    int wid = threadIdx.x >> 6, lane = threadIdx.x & 63;
    if (lane == 0) { red[0][wid] = s; red[1][wid] = ss; }
    __syncthreads();
    if (threadIdx.x == 0) {
        float S1 = red[0][0] + red[0][1] + red[0][2] + red[0][3];
        float S2 = red[1][0] + red[1][1] + red[1][2] + red[1][3];
        const float inv_n = 1.0f / (CPG * Ss);
        float mu = S1 * inv_n;
        float var = S2 * inv_n - mu * mu;
        stats[bg * 2]     = mu;
        stats[bg * 2 + 1] = rsqrtf(var + EPSV);
    }
}

// ---------------- GroupNorm apply + transpose -> bf16 (B,S,C) ----------------
__global__ __launch_bounds__(256) void gn_apply_t_bf(const float* __restrict__ x,
                                                     const float* __restrict__ stats,
                                                     const float* __restrict__ gw,
                                                     const float* __restrict__ gb,
                                                     u16* __restrict__ ht) {
    __shared__ float tile[32][33];
    int b  = blockIdx.z;
    int c0 = blockIdx.y * 32;
    int s0 = blockIdx.x * 32;
    int tx = threadIdx.x, ty = threadIdx.y;
#pragma unroll
    for (int i = 0; i < 4; i++) {
        int c = c0 + ty + i * 8;
        int g = c >> 6;
        float mu = stats[(b * 8 + g) * 2];
        float rs = stats[(b * 8 + g) * 2 + 1];
        float v = x[((size_t)b * Cch + c) * Ss + s0 + tx];
        tile[ty + i * 8][tx] = (v - mu) * rs * gw[c] + gb[c];
    }
    __syncthreads();
#pragma unroll
    for (int i = 0; i < 4; i++) {
        int s = s0 + ty + i * 8;
        ht[((size_t)b * Ss + s) * Cch + c0 + tx] = f2bf(tile[tx][ty + i * 8]);
    }
}

// ---------------- fused weight prep: ALL conversions/transposes in 1 launch ----------
__global__ __launch_bounds__(256) void prep_all(const float* __restrict__ pin_w,
                                                const float* __restrict__ pout_w,
                                                u16* __restrict__ pinB,
                                                u16* __restrict__ poutB,
                                                const float* __restrict__ wq,
                                                const float* __restrict__ wk,
                                                const float* __restrict__ wv,
                                                const float* __restrict__ wo,
                                                u16* __restrict__ wqT,
                                                u16* __restrict__ wkT,
                                                u16* __restrict__ wvT,
                                                u16* __restrict__ woT,
                                                const float* __restrict__ wg,
                                                u16* __restrict__ wgT,
                                                const float* __restrict__ wd,
                                                u16* __restrict__ wdT) {
    __shared__ float tile[32][33];
    int bid = blockIdx.x;
    int tx = threadIdx.x, ty = threadIdx.y;
    int tid = ty * 32 + tx;
    if (bid < 512) {
        int base = bid * 1024 + tid * 4;
        const float* src; u16* dst; int off;
        if (base < 262144) { src = pin_w;  dst = pinB;  off = base; }
        else               { src = pout_w; dst = poutB; off = base - 262144; }
        float4 v = *(const float4*)&src[off];
        ushort4 o;
        o.x = f2bf(v.x); o.y = f2bf(v.y); o.z = f2bf(v.z); o.w = f2bf(v.w);
        *(ushort4*)&dst[off] = o;
        return;
    }
    const float* in; u16* outp; int c0, r0, C, R; float scl = 1.0f;
    if (bid < 1536) {
        int z = (bid - 512) >> 8, rem = (bid - 512) & 255;
        switch (z) {
            case 0: in = wq; outp = wqT; scl = QSCL; break;
            case 1: in = wk; outp = wkT; break;
            case 2: in = wv; outp = wvT; break;
            default: in = wo; outp = woT; break;
        }
        c0 = (rem & 15) * 32; r0 = (rem >> 4) * 32; C = 512; R = 512;
    } else if (bid < 3584) {
        int rem = bid - 1536;
        in = wg; outp = wgT; C = 4096; R = 512;
        c0 = (rem & 127) * 32; r0 = (rem >> 7) * 32;
    } else {
        int rem = bid - 3584;
        in = wd; outp = wdT; C = 512; R = 2048;
        c0 = (rem & 15) * 32; r0 = (rem >> 4) * 32;
    }
#pragma unroll
    for (int i = 0; i < 4; i++)
        tile[ty + i * 8][tx] = in[(size_t)(r0 + ty + i * 8) * C + c0 + tx] * scl;
    __syncthreads();
#pragma unroll
    for (int i = 0; i < 4; i++)
        outp[(size_t)(c0 + ty + i * 8) * R + r0 + tx] = f2bf(tile[tx][ty + i * 8]);
}

// ---------------- per-head V transpose: vb [b][s][512] -> vt [(b*8+h)][64][1024] ----------
__global__ __launch_bounds__(256) void vtrans(const u16* __restrict__ in,
                                              u16* __restrict__ outp) {
    __shared__ u16 tile[64][66];
    int s0 = blockIdx.x * 64, h = blockIdx.y, b = blockIdx.z;
    const u16* src = in + ((size_t)b * Ss + s0) * Cch + h * 64;
    int r = threadIdx.x >> 3, c8 = (threadIdx.x & 7) * 8;
#pragma unroll
    for (int p = 0; p < 2; p++) {
        int rr = r + p * 32;
        *(int4*)&tile[rr][c8] = *(const int4*)&src[(size_t)rr * Cch + c8];
    }
    __syncthreads();
    u16* dst = outp + ((size_t)(b * 8 + h) * 64) * Ss + s0;
#pragma unroll
    for (int p = 0; p < 2; p++) {
        int d = r + p * 32;
        u16 vals[8];
#pragma unroll
        for (int e = 0; e < 8; e++) vals[e] = tile[c8 + e][d];
        *(int4*)&dst[(size_t)d * Ss + c8] = *(int4*)vals;
    }
}

// ---------------- LayerNorm rows (bf16 in, bf16 out) ----------------
__global__ __launch_bounds__(256) void layer_norm_rows_bf(const u16* __restrict__ in,
                                                          const float* __restrict__ w,
                                                          const float* __restrict__ bb,
                                                          u16* __restrict__ outp) {
    int row = blockIdx.x;
    const u16* p = in + (size_t)row * Cch;
    int i0 = threadIdx.x * 2;
    ushort2 u = *(const ushort2*)&p[i0];
    float v0 = bf2f(u.x), v1 = bf2f(u.y);
    float s = v0 + v1, ss = v0 * v0 + v1 * v1;
    for (int o = 32; o > 0; o >>= 1) { s += __shfl_down(s, o); ss += __shfl_down(ss, o); }
    __shared__ float red[2][4];
    __shared__ float mu_s, rs_s;
    int wid = threadIdx.x >> 6, lane = threadIdx.x & 63;
    if (lane == 0) { red[0][wid] = s; red[1][wid] = ss; }
    __syncthreads();
    if (threadIdx.x == 0) {
        float S1 = red[0][0] + red[0][1] + red[0][2] + red[0][3];
        float S2 = red[1][0] + red[1][1] + red[1][2] + red[1][3];
        float mu = S1 * (1.0f / Cch);
        float var = S2 * (1.0f / Cch) - mu * mu;
        mu_s = mu; rs_s = rsqrtf(var + EPSV);
    }
    __syncthreads();
    float mu = mu_s, rs = rs_s;
    outp[(size_t)row * Cch + i0]     = f2bf((v0 - mu) * rs * w[i0] + bb[i0]);
    outp[(size_t)row * Cch + i0 + 1] = f2bf((v1 - mu) * rs * w[i0 + 1] + bb[i0 + 1]);
}

// ---------------- MFMA GEMM: out(MxN) = A(MxK bf16) @ Bt(NxK bf16)^T ----------------
// 256x128 tile, BK=32, 512 thr = 8 waves (4x2). Per-wave 64x64 (same verified fragment
// code as 128-tile version); 2x MFMA per barrier pair vs BM=128.
// EPI: 0 = bf16; 1 = fp32 +bias; 6 = bf16 +bias; 7 = bf16 +bias + bf16 residual in-place;
//      8 = bf16 routed qkv (outb base = qb; col>>9 selects q/k/v slot, 8388608 apart).
template<int EPI>
__global__ __launch_bounds__(512) void mfma_gemm(const u16* __restrict__ A,
                                                 const u16* __restrict__ Bt,
                                                 const float* __restrict__ bias,
                                                 float* __restrict__ fout,
                                                 u16* __restrict__ outb,
                                                 int K, int N) {
    __shared__ u16 As[256 * 32];
    __shared__ u16 Bs[128 * 32];
    int tid = threadIdx.x;
    int m0 = blockIdx.y * 256, n0 = blockIdx.x * 128;
    int wave = tid >> 6, lane = tid & 63;
    int wr = wave >> 1, wc = wave & 1;      // 4x2 wave grid
    int l15 = lane & 15, l4 = lane >> 4;

    f32x4 zero4 = {0.f, 0.f, 0.f, 0.f};
    f32x4 acc[4][4];
#pragma unroll
    for (int i = 0; i < 4; i++)
#pragma unroll
        for (int j = 0; j < 4; j++) acc[i][j] = zero4;

    // A staging: 256 rows x 32; thread -> row tid>>1, chunks {sc0, sc0+1}
    int srow = tid >> 1;
    int sc0  = (tid & 1) * 2;
    int se   = sc0 * 8;
    // B staging: 128 rows x 32; thread -> row tid>>2, chunk tid&3
    int brow = tid >> 2;
    int bch  = tid & 3;
    int bqe  = bch * 8;

    int4 ra0, ra1, rb0;
    {
        const u16* pa = A  + (size_t)(m0 + srow) * K + se;
        ra0 = *(const int4*)pa; ra1 = *(const int4*)(pa + 8);
        rb0 = *(const int4*)(Bt + (size_t)(n0 + brow) * K + bqe);
    }
    for (int kt = 0; kt < K; kt += 32) {
        __syncthreads();
        *(int4*)&As[swzg(srow, sc0)]     = ra0;
        *(int4*)&As[swzg(srow, sc0 + 1)] = ra1;
        *(int4*)&Bs[swzg(brow, bch)]     = rb0;
        __syncthreads();
        int kn = kt + 32;
        if (kn < K) {
            const u16* pa = A  + (size_t)(m0 + srow) * K + kn + se;
            ra0 = *(const int4*)pa; ra1 = *(const int4*)(pa + 8);
            rb0 = *(const int4*)(Bt + (size_t)(n0 + brow) * K + kn + bqe);
        }
        bf16x8 af[4], bfr[4];
#pragma unroll
        for (int mi = 0; mi < 4; mi++)
            af[mi] = *(const bf16x8*)&As[swzg(wr * 64 + mi * 16 + l15, l4)];
#pragma unroll
        for (int nj = 0; nj < 4; nj++)
            bfr[nj] = *(const bf16x8*)&Bs[swzg(wc * 64 + nj * 16 + l15, l4)];
#pragma unroll
        for (int mi = 0; mi < 4; mi++)
#pragma unroll
            for (int nj = 0; nj < 4; nj++)
                acc[mi][nj] = __builtin_amdgcn_mfma_f32_16x16x32_bf16(af[mi], bfr[nj], acc[mi][nj], 0, 0, 0);
    }

#pragma unroll
    for (int mi = 0; mi < 4; mi++)
#pragma unroll
        for (int nj = 0; nj < 4; nj++)
#pragma unroll
            for (int r = 0; r < 4; r++) {
                int row = m0 + wr * 64 + mi * 16 + l4 * 4 + r;
                int col = n0 + wc * 64 + nj * 16 + l15;
                float v = acc[mi][nj][r];
                if constexpr (EPI == 0) {
                    outb[(size_t)row * N + col] = f2bf(v);
                } else if constexpr (EPI == 1) {
                    fout[(size_t)row * N + col] = v + bias[col];
                } else if constexpr (EPI == 6) {
                    outb[(size_t)row * N + col] = f2bf(v + bias[col]);
                } else if constexpr (EPI == 7) {
                    size_t idx = (size_t)row * N + col;
                    v += bias[col] + bf2f(outb[idx]);
                    outb[idx] = f2bf(v);
                } else if constexpr (EPI == 8) {
                    size_t idx = (size_t)(col >> 9) * 8388608 + (size_t)row * 512 + (col & 511);
                    outb[idx] = f2bf(v);
                }
            }
}

// ---------------- GEGLU MFMA: 256x64(x2 halves) tile, 8 waves, fused exact GELU --------
__global__ __launch_bounds__(512) void geglu_mfma(const u16* __restrict__ A,
                                                  const u16* __restrict__ WgT,  // [4096][512]
                                                  const float* __restrict__ bg,
                                                  u16* __restrict__ ag) {
    __shared__ u16 As[256 * 32];
    __shared__ u16 Bs1[64 * 32];
    __shared__ u16 Bs2[64 * 32];
    const int K = 512;
    int tid = threadIdx.x;
    int m0 = blockIdx.y * 256, n0 = blockIdx.x * 64;
    int wave = tid >> 6, lane = tid & 63;
    int wr = wave >> 1, wc = wave & 1;      // 4x2 wave grid; wave: 64 rows x 32 cols/half
    int l15 = lane & 15, l4 = lane >> 4;

    f32x4 zero4 = {0.f, 0.f, 0.f, 0.f};
    f32x4 accA[4][2], accG[4][2];
#pragma unroll
    for (int i = 0; i < 4; i++) { accA[i][0] = zero4; accA[i][1] = zero4; accG[i][0] = zero4; accG[i][1] = zero4; }

    // A staging: 256 rows
    int srow = tid >> 1;
    int sc0  = (tid & 1) * 2;
    int se   = sc0 * 8;
    // B staging: 64 rows each half; 256 threads per half, 1 int4 each
    int bsel = tid >> 8;                    // 0 -> Bs1 (a-half), 1 -> Bs2 (g-half)
    int bt   = tid & 255;
    int brow = bt >> 2;
    int bch  = bt & 3;
    int bqe  = bch * 8;
    const u16* gbp = WgT + (size_t)(bsel * 2048 + n0 + brow) * K + bqe;

    int4 ra0, ra1, rb;
    {
        const u16* pa = A + (size_t)(m0 + srow) * K + se;
        ra0 = *(const int4*)pa; ra1 = *(const int4*)(pa + 8);
        rb = *(const int4*)gbp;
    }
    for (int kt = 0; kt < K; kt += 32) {
        __syncthreads();
        *(int4*)&As[swzg(srow, sc0)]     = ra0;
        *(int4*)&As[swzg(srow, sc0 + 1)] = ra1;
        if (bsel == 0) *(int4*)&Bs1[swzg(brow, bch)] = rb;
        else           *(int4*)&Bs2[swzg(brow, bch)] = rb;
        __syncthreads();
        int kn = kt + 32;
        if (kn < K) {
            const u16* pa = A + (size_t)(m0 + srow) * K + kn + se;
            ra0 = *(const int4*)pa; ra1 = *(const int4*)(pa + 8);
            rb = *(const int4*)(gbp + kn);
        }
        bf16x8 af[4], b1[2], b2[2];
#pragma unroll
        for (int mi = 0; mi < 4; mi++)
            af[mi] = *(const bf16x8*)&As[swzg(wr * 64 + mi * 16 + l15, l4)];
#pragma unroll
        for (int nj = 0; nj < 2; nj++) {
            b1[nj] = *(const bf16x8*)&Bs1[swzg(wc * 32 + nj * 16 + l15, l4)];
            b2[nj] = *(const bf16x8*)&Bs2[swzg(wc * 32 + nj * 16 + l15, l4)];
        }
#pragma unroll
        for (int mi = 0; mi < 4; mi++)
#pragma unroll
            for (int nj = 0; nj < 2; nj++) {
                accA[mi][nj] = __builtin_amdgcn_mfma_f32_16x16x32_bf16(af[mi], b1[nj], accA[mi][nj], 0, 0, 0);
                accG[mi][nj] = __builtin_amdgcn_mfma_f32_16x16x32_bf16(af[mi], b2[nj], accG[mi][nj], 0, 0, 0);
            }
    }

#pragma unroll
    for (int mi = 0; mi < 4; mi++)
#pragma unroll
        for (int nj = 0; nj < 2; nj++)
#pragma unroll
            for (int r = 0; r < 4; r++) {
                int row = m0 + wr * 64 + mi * 16 + l4 * 4 + r;
                int col = n0 + wc * 32 + nj * 16 + l15;
                float a = accA[mi][nj][r] + bg[col];
                float g = accG[mi][nj][r] + bg[2048 + col];
                float ge = 0.5f * g * (1.0f + erff(g * 0.70710678118654752f));
                ag[(size_t)row * 2048 + col] = f2bf(a * ge);
            }
}

// ---------------- MFMA flash attention: KVBLK=128, log2 softmax, swizzled LDS ------------
__global__ __launch_bounds__(256) void flash_attn_mfma(const u16* __restrict__ q,
                                                       const u16* __restrict__ k,
                                                       const u16* __restrict__ vt,  // [b*8+h][64][1024]
                                                       u16* __restrict__ o) {
    __shared__ u16 Ps[64 * 128];
    __shared__ u16 Ks[128 * 64];
    __shared__ u16 Vt[64 * 128];
    const int tid = threadIdx.x;
    const int h = blockIdx.y, b = blockIdx.z;
    const int q0 = blockIdx.x * 64;
    const size_t hb  = (size_t)b * Ss * Cch + (size_t)h * DHh;
    const size_t vhb = ((size_t)(b * NHh + h) * DHh) * Ss;

    const int wq = tid >> 6;
    const int lane = tid & 63;
    const int l15 = lane & 15, l4 = lane >> 4;

    {
        int r = tid >> 2, ch = (tid & 3) * 2;
        const u16* src = q + hb + (size_t)(q0 + r) * Cch + ch * 8;
        *(int4*)&Ps[swz128(r, ch)]     = *(const int4*)src;
        *(int4*)&Ps[swz128(r, ch + 1)] = *(const int4*)(src + 8);
    }
    __syncthreads();
    bf16x8 aq[2];
    aq[0] = *(const bf16x8*)&Ps[swz128(wq * 16 + l15, 0 * 4 + l4)];
    aq[1] = *(const bf16x8*)&Ps[swz128(wq * 16 + l15, 1 * 4 + l4)];

    f32x4 zero4 = {0.f, 0.f, 0.f, 0.f};
    f32x4 oacc[4];
    float m_[4], l_[4];
#pragma unroll
    for (int j = 0; j < 4; j++) oacc[j] = zero4;
#pragma unroll
    for (int r = 0; r < 4; r++) { m_[r] = -1e30f; l_[r] = 0.f; }

    for (int t0 = 0; t0 < Ss; t0 += 128) {
        __syncthreads();
        {
            int r = tid >> 1, c4 = (tid & 1) * 4;
            const u16* ksrc = k + hb + (size_t)(t0 + r) * Cch + c4 * 8;
            *(int4*)&Ks[swz(r, c4)]     = *(const int4*)ksrc;
            *(int4*)&Ks[swz(r, c4 + 1)] = *(const int4*)(ksrc + 8);
            *(int4*)&Ks[swz(r, c4 + 2)] = *(const int4*)(ksrc + 16);
            *(int4*)&Ks[swz(r, c4 + 3)] = *(const int4*)(ksrc + 24);
            int d = tid >> 2, cv = (tid & 3) * 4;
            const u16* vsrc = vt + vhb + (size_t)d * Ss + t0 + cv * 8;
            *(int4*)&Vt[swz128(d, cv)]     = *(const int4*)vsrc;
            *(int4*)&Vt[swz128(d, cv + 1)] = *(const int4*)(vsrc + 8);
            *(int4*)&Vt[swz128(d, cv + 2)] = *(const int4*)(vsrc + 16);
            *(int4*)&Vt[swz128(d, cv + 3)] = *(const int4*)(vsrc + 24);
        }
        __syncthreads();

        f32x4 sacc[8];
#pragma unroll
        for (int j = 0; j < 8; j++) sacc[j] = zero4;
#pragma unroll
        for (int ks = 0; ks < 2; ks++) {
#pragma unroll
            for (int j = 0; j < 8; j++) {
                bf16x8 bk = *(const bf16x8*)&Ks[swz(j * 16 + l15, ks * 4 + l4)];
                sacc[j] = __builtin_amdgcn_mfma_f32_16x16x32_bf16(aq[ks], bk, sacc[j], 0, 0, 0);
            }
        }

        float tmv[4];
        int grew = 0;
#pragma unroll
        for (int r = 0; r < 4; r++) {
            float tm = fmaxf(fmaxf(fmaxf(sacc[0][r], sacc[1][r]), fmaxf(sacc[2][r], sacc[3][r])),
                             fmaxf(fmaxf(sacc[4][r], sacc[5][r]), fmaxf(sacc[6][r], sacc[7][r])));
            tm = fmaxf(tm, __shfl_xor(tm, 1));
            tm = fmaxf(tm, __shfl_xor(tm, 2));
            tm = fmaxf(tm, __shfl_xor(tm, 4));
            tm = fmaxf(tm, __shfl_xor(tm, 8));
            tmv[r] = tm;
            grew |= (tm > m_[r]);
        }

        if (__any(grew)) {
#pragma unroll
            for (int r = 0; r < 4; r++) {
                float nm = fmaxf(m_[r], tmv[r]);
                float sc = exp2_raw(m_[r] - nm);
                m_[r] = nm;
                int row = wq * 16 + l4 * 4 + r;
                int rx = row & 7, base = row * 128, wi = l15 & 7, hi = l15 >> 3;
                float rs = 0.f;
#pragma unroll
                for (int j = 0; j < 8; j++) {
                    float p = exp2_raw(sacc[j][r] - nm);
                    Ps[base + (((2 * j + hi) ^ rx) * 8) + wi] = f2bf_rz(p);
                    rs += p;
                }
                l_[r] = l_[r] * sc + rs;
#pragma unroll
                for (int j = 0; j < 4; j++) oacc[j][r] *= sc;
            }
        } else {
#pragma unroll
            for (int r = 0; r < 4; r++) {
                float nm = m_[r];
                int row = wq * 16 + l4 * 4 + r;
                int rx = row & 7, base = row * 128, wi = l15 & 7, hi = l15 >> 3;
                float rs = 0.f;
#pragma unroll
                for (int j = 0; j < 8; j++) {
                    float p = exp2_raw(sacc[j][r] - nm);
                    Ps[base + (((2 * j + hi) ^ rx) * 8) + wi] = f2bf_rz(p);
                    rs += p;
                }
                l_[r] += rs;
            }
        }

#pragma unroll
        for (int ks = 0; ks < 4; ks++) {
            bf16x8 pa = *(const bf16x8*)&Ps[swz128(wq * 16 + l15, ks * 4 + l4)];
#pragma unroll
            for (int j = 0; j < 4; j++) {
                bf16x8 bv = *(const bf16x8*)&Vt[swz128(j * 16 + l15, ks * 4 + l4)];
                oacc[j] = __builtin_amdgcn_mfma_f32_16x16x32_bf16(pa, bv, oacc[j], 0, 0, 0);
            }
        }
    }

#pragma unroll
    for (int r = 0; r < 4; r++) {
        float lt = l_[r];
        lt += __shfl_xor(lt, 1);
        lt += __shfl_xor(lt, 2);
        lt += __shfl_xor(lt, 4);
        lt += __shfl_xor(lt, 8);
        float inv = 1.0f / lt;
        int row = wq * 16 + l4 * 4 + r;
        int rx = row & 7, base = row * 128, wi = l15 & 7, hi = l15 >> 3;
#pragma unroll
        for (int j = 0; j < 4; j++)
            Ps[base + (((2 * j + hi) ^ rx) * 8) + wi] = f2bf(oacc[j][r] * inv);
    }
    __syncthreads();
    {
        int r = tid >> 2, ch = (tid & 3) * 2;
        u16* dst = o + hb + (size_t)(q0 + r) * Cch + ch * 8;
        *(int4*)dst       = *(const int4*)&Ps[swz128(r, ch)];
        *(int4*)(dst + 8) = *(const int4*)&Ps[swz128(r, ch + 1)];
    }
}

// ---------------- final: out(B,C,S) = tmp(B,S,C)^T + x ----------------
__global__ __launch_bounds__(256) void final_out(const float* __restrict__ tmp,
                                                 const float* __restrict__ x,
                                                 float* __restrict__ outp) {
    __shared__ float tile[32][33];
    int b = blockIdx.z, c0 = blockIdx.y * 32, s0 = blockIdx.x * 32;
    int tx = threadIdx.x, ty = threadIdx.y;
#pragma unroll
    for (int i = 0; i < 4; i++) {
        int s = s0 + ty + i * 8;
        tile[ty + i * 8][tx] = tmp[((size_t)b * Ss + s) * Cch + c0 + tx];
    }
    __syncthreads();
#pragma unroll
    for (int i = 0; i < 4; i++) {
        int c = c0 + ty + i * 8;
        size_t idx = ((size_t)b * Cch + c) * Ss + s0 + tx;
        outp[idx] = tile[tx][ty + i * 8] + x[idx];
    }
}

extern "C" void kernel_launch(void* const* d_in, const int* in_sizes, int n_in,
                              void* d_out, int out_size, void* d_ws, size_t ws_size,
                              hipStream_t stream) {
    (void)in_sizes; (void)n_in; (void)out_size; (void)ws_size;
    const float* x      = (const float*)d_in[0];
    const float* gn_w   = (const float*)d_in[1];
    const float* gn_b   = (const float*)d_in[2];
    const float* pin_w  = (const float*)d_in[3];
    const float* pin_b  = (const float*)d_in[4];
    const float* ln1_w  = (const float*)d_in[5];
    const float* ln1_b  = (const float*)d_in[6];
    const float* wq     = (const float*)d_in[7];
    const float* wk     = (const float*)d_in[8];
    const float* wv     = (const float*)d_in[9];
    const float* wo     = (const float*)d_in[10];
    const float* bo     = (const float*)d_in[11];
    const float* ln3_w  = (const float*)d_in[12];
    const float* ln3_b  = (const float*)d_in[13];
    const float* wg     = (const float*)d_in[14];
    const float* bg     = (const float*)d_in[15];
    const float* wd     = (const float*)d_in[16];
    const float* bd     = (const float*)d_in[17];
    const float* pout_w = (const float*)d_in[18];
    const float* pout_b = (const float*)d_in[19];
    float* out = (float*)d_out;

    // ---- workspace layout (bytes) ----
    char* W = (char*)d_ws;
    u16* tb        = (u16*)W;                                     // t residual, bf16, 16.78 MB
    float* tmp_f32 = (float*)(W + 33554432);                      // 33.55 MB
    u16* qb    = (u16*)(W + 67108864);                            // 16.78 MB (qb,kb,vb contiguous)
    u16* kb    = qb + 8388608;
    u16* vb    = kb + 8388608;
    u16* attnb = vb + 8388608;
    u16* Xb    = attnb + 8388608;                                 // 16.78 MB
    float* stats = (float*)(W + 67108864 + 5ull * 16777216);      // 1 KB
    u16* wbase = (u16*)(W + 67108864 + 5ull * 16777216 + 1024);
    u16* pinB  = wbase;                 // 512*512  (already [N][K])
    u16* poutB = pinB  + 262144;
    u16* wqT   = poutB + 262144;        // [512][512] transposed, scaled by QSCL
    u16* wkT   = wqT   + 262144;        // contiguous with wqT -> [1536][512] for fused qkv
    u16* wvT   = wkT   + 262144;
    u16* woT   = wvT   + 262144;
    u16* wgT   = woT   + 262144;        // [4096][512]
    u16* wdT   = wgT   + 2097152;       // [512][2048]
    u16* ag    = qb;                    // R x 2048 bf16, aliases qb..attnb (dead by then)
    u16* vtb   = (u16*)tmp_f32;         // V^T [b*8+h][64][1024], aliases tmp_f32 (dead until pout)

    dim3 tb8(32, 8);

    // stats + fused weight prep (2 launches)
    gn_stats<<<128, 256, 0, stream>>>(x, stats);
    prep_all<<<4608, tb8, 0, stream>>>(pin_w, pout_w, pinB, poutB,
                                       wq, wk, wv, wo, wqT, wkT, wvT, woT,
                                       wg, wgT, wd, wdT);

    // h = GN(x) transposed -> Xb (bf16)
    gn_apply_t_bf<<<dim3(32, 16, 16), tb8, 0, stream>>>(x, stats, gn_w, gn_b, Xb);

    // t = h @ pin_w^T + pin_b -> tb (bf16)
    mfma_gemm<6><<<dim3(4, 64), 512, 0, stream>>>(Xb, pinB, pin_b, nullptr, tb, 512, 512);
    // tn = ln1(t) -> Xb
    layer_norm_rows_bf<<<16384, 256, 0, stream>>>(tb, ln1_w, ln1_b, Xb);
    // fused q(scaled)/k/v: N=1536, routed to qb/kb/vb
    mfma_gemm<8><<<dim3(12, 64), 512, 0, stream>>>(Xb, wqT, nullptr, nullptr, qb, 512, 1536);
    // per-head V transpose -> vtb
    vtrans<<<dim3(16, 8, 16), 256, 0, stream>>>(vb, vtb);
    // attention (MFMA, KVBLK=128) -> attnb (bf16)
    flash_attn_mfma<<<dim3(16, 8, 16), 256, 0, stream>>>(qb, kb, vtb, attnb);
    // t += attn @ wo + bo (bf16 in-place on tb)
    mfma_gemm<7><<<dim3(4, 64), 512, 0, stream>>>(attnb, woT, bo, nullptr, tb, 512, 512);
    // tn3 = ln3(t) -> Xb
    layer_norm_rows_bf<<<16384, 256, 0, stream>>>(tb, ln3_w, ln3_b, Xb);
    // ag = a * gelu(g) (bf16), aliases q/k/v/attn space
    geglu_mfma<<<dim3(32, 64), 512, 0, stream>>>(Xb, wgT, bg, ag);
    // t += ag @ wd + bd (bf16 in-place on tb)
    mfma_gemm<7><<<dim3(4, 64), 512, 0, stream>>>(ag, wdT, bd, nullptr, tb, 2048, 512);
    // tmp = t @ pout_w^T + pout_b -> tmp_f32
    mfma_gemm<1><<<dim3(4, 64), 512, 0, stream>>>(tb, poutB, pout_b, tmp_f32, nullptr, 512, 512);
    // out = tmp^T + x
    final_out<<<dim3(32, 16, 16), tb8, 0, stream>>>(tmp_f32, x, out);
}

// Round 24
// 440.952 us; speedup vs baseline: 1.2660x; 1.0124x over previous
//
#include <hip/hip_runtime.h>
#include <hip/hip_bf16.h>
#include <math.h>

typedef unsigned short u16;
typedef __attribute__((ext_vector_type(8))) short bf16x8;
typedef __attribute__((ext_vector_type(4))) float f32x4;

#define Bb 16
#define Cch 512
#define Ss 1024
#define NHh 8
#define DHh 64
#define CPG 64
#define EPSV 1e-5f
#define R_TOTAL (Bb*Ss)   // 16384
#define QSCL 0.18033688011112042f   // 0.125 * log2(e)

__device__ inline u16 f2bf(float f) {
    unsigned int u = __float_as_uint(f);
    unsigned int r = (u + 0x7fffu + ((u >> 16) & 1u)) >> 16;
    return (u16)r;
}
__device__ inline u16 f2bf_rz(float f) { return (u16)(__float_as_uint(f) >> 16); }
__device__ inline float bf2f(u16 v) { return __uint_as_float((unsigned)v << 16); }
__device__ inline float exp2_raw(float x) {
    float r; asm("v_exp_f32 %0, %1" : "=v"(r) : "v"(x)); return r;
}

// swizzles: 16B chunk XOR'd by row&7 (conflict-free fragment reads, measured r14/r19)
__device__ inline int swz(int row, int chunk) {      // row stride 64 u16 (8 chunks)
    return row * 64 + ((chunk ^ (row & 7)) * 8);
}
__device__ inline int swz128(int row, int chunk) {   // row stride 128 u16 (16 chunks)
    return row * 128 + ((chunk ^ (row & 7)) * 8);
}
__device__ inline int swzg(int r, int c) {           // GEMM [R][32] tile
    int span = r >> 1;
    int c8 = ((r & 1) << 2) | c;
    return span * 64 + ((c8 ^ (span & 7)) * 8);
}

// ---------------- GroupNorm stats (float4 loads) ----------------
__global__ __launch_bounds__(256) void gn_stats(const float* __restrict__ x,
                                                float* __restrict__ stats) {
    int bg = blockIdx.x;
    int b = bg >> 3, g = bg & 7;
    const float4* base = (const float4*)(x + ((size_t)b * Cch + (size_t)g * CPG) * Ss);
    float s = 0.f, ss = 0.f;
    for (int i = threadIdx.x; i < CPG * Ss / 4; i += 256) {
        float4 v = base[i];
        s  += v.x + v.y + v.z + v.w;
        ss += v.x * v.x + v.y * v.y + v.z * v.z + v.w * v.w;
    }
    for (int o = 32; o > 0; o >>= 1) { s += __shfl_down(s, o); ss += __shfl_down(ss, o); }
    __shared__ float red[2][4];
    int wid = threadIdx.x >> 6, lane = threadIdx.x & 63;
    if (lane == 0) { red[0][wid] = s; red[1][wid] = ss; }
    __syncthreads();
    if (threadIdx.x == 0) {
        float S1 = red[0][0] + red[0][1] + red[0][2] + red[0][3];
        float S2 = red[1][0] + red[1][1] + red[1][2] + red[1][3];
        const float inv_n = 1.0f / (CPG * Ss);
        float mu = S1 * inv_n;
        float var = S2 * inv_n - mu * mu;
        stats[bg * 2]     = mu;
        stats[bg * 2 + 1] = rsqrtf(var + EPSV);
    }
}

// ---------------- GroupNorm apply + transpose -> bf16 (B,S,C) ----------------
__global__ __launch_bounds__(256) void gn_apply_t_bf(const float* __restrict__ x,
                                                     const float* __restrict__ stats,
                                                     const float* __restrict__ gw,
                                                     const float* __restrict__ gb,
                                                     u16* __restrict__ ht) {
    __shared__ float tile[32][33];
    int b  = blockIdx.z;
    int c0 = blockIdx.y * 32;
    int s0 = blockIdx.x * 32;
    int tx = threadIdx.x, ty = threadIdx.y;
#pragma unroll
    for (int i = 0; i < 4; i++) {
        int c = c0 + ty + i * 8;
        int g = c >> 6;
        float mu = stats[(b * 8 + g) * 2];
        float rs = stats[(b * 8 + g) * 2 + 1];
        float v = x[((size_t)b * Cch + c) * Ss + s0 + tx];
        tile[ty + i * 8][tx] = (v - mu) * rs * gw[c] + gb[c];
    }
    __syncthreads();
#pragma unroll
    for (int i = 0; i < 4; i++) {
        int s = s0 + ty + i * 8;
        ht[((size_t)b * Ss + s) * Cch + c0 + tx] = f2bf(tile[tx][ty + i * 8]);
    }
}

// ---------------- fused weight prep: ALL conversions/transposes in 1 launch ----------
__global__ __launch_bounds__(256) void prep_all(const float* __restrict__ pin_w,
                                                const float* __restrict__ pout_w,
                                                u16* __restrict__ pinB,
                                                u16* __restrict__ poutB,
                                                const float* __restrict__ wq,
                                                const float* __restrict__ wk,
                                                const float* __restrict__ wv,
                                                const float* __restrict__ wo,
                                                u16* __restrict__ wqT,
                                                u16* __restrict__ wkT,
                                                u16* __restrict__ wvT,
                                                u16* __restrict__ woT,
                                                const float* __restrict__ wg,
                                                u16* __restrict__ wgT,
                                                const float* __restrict__ wd,
                                                u16* __restrict__ wdT) {
    __shared__ float tile[32][33];
    int bid = blockIdx.x;
    int tx = threadIdx.x, ty = threadIdx.y;
    int tid = ty * 32 + tx;
    if (bid < 512) {
        int base = bid * 1024 + tid * 4;
        const float* src; u16* dst; int off;
        if (base < 262144) { src = pin_w;  dst = pinB;  off = base; }
        else               { src = pout_w; dst = poutB; off = base - 262144; }
        float4 v = *(const float4*)&src[off];
        ushort4 o;
        o.x = f2bf(v.x); o.y = f2bf(v.y); o.z = f2bf(v.z); o.w = f2bf(v.w);
        *(ushort4*)&dst[off] = o;
        return;
    }
    const float* in; u16* outp; int c0, r0, C, R; float scl = 1.0f;
    if (bid < 1536) {
        int z = (bid - 512) >> 8, rem = (bid - 512) & 255;
        switch (z) {
            case 0: in = wq; outp = wqT; scl = QSCL; break;
            case 1: in = wk; outp = wkT; break;
            case 2: in = wv; outp = wvT; break;
            default: in = wo; outp = woT; break;
        }
        c0 = (rem & 15) * 32; r0 = (rem >> 4) * 32; C = 512; R = 512;
    } else if (bid < 3584) {
        int rem = bid - 1536;
        in = wg; outp = wgT; C = 4096; R = 512;
        c0 = (rem & 127) * 32; r0 = (rem >> 7) * 32;
    } else {
        int rem = bid - 3584;
        in = wd; outp = wdT; C = 512; R = 2048;
        c0 = (rem & 15) * 32; r0 = (rem >> 4) * 32;
    }
#pragma unroll
    for (int i = 0; i < 4; i++)
        tile[ty + i * 8][tx] = in[(size_t)(r0 + ty + i * 8) * C + c0 + tx] * scl;
    __syncthreads();
#pragma unroll
    for (int i = 0; i < 4; i++)
        outp[(size_t)(c0 + ty + i * 8) * R + r0 + tx] = f2bf(tile[tx][ty + i * 8]);
}

// ---------------- per-head V transpose: vb [b][s][512] -> vt [(b*8+h)][64][1024] ----------
__global__ __launch_bounds__(256) void vtrans(const u16* __restrict__ in,
                                              u16* __restrict__ outp) {
    __shared__ u16 tile[64][66];
    int s0 = blockIdx.x * 64, h = blockIdx.y, b = blockIdx.z;
    const u16* src = in + ((size_t)b * Ss + s0) * Cch + h * 64;
    int r = threadIdx.x >> 3, c8 = (threadIdx.x & 7) * 8;
#pragma unroll
    for (int p = 0; p < 2; p++) {
        int rr = r + p * 32;
        *(int4*)&tile[rr][c8] = *(const int4*)&src[(size_t)rr * Cch + c8];
    }
    __syncthreads();
    u16* dst = outp + ((size_t)(b * 8 + h) * 64) * Ss + s0;
#pragma unroll
    for (int p = 0; p < 2; p++) {
        int d = r + p * 32;
        u16 vals[8];
#pragma unroll
        for (int e = 0; e < 8; e++) vals[e] = tile[c8 + e][d];
        *(int4*)&dst[(size_t)d * Ss + c8] = *(int4*)vals;
    }
}

// ---------------- LayerNorm rows (bf16 in, bf16 out) ----------------
__global__ __launch_bounds__(256) void layer_norm_rows_bf(const u16* __restrict__ in,
                                                          const float* __restrict__ w,
                                                          const float* __restrict__ bb,
                                                          u16* __restrict__ outp) {
    int row = blockIdx.x;
    const u16* p = in + (size_t)row * Cch;
    int i0 = threadIdx.x * 2;
    ushort2 u = *(const ushort2*)&p[i0];
    float v0 = bf2f(u.x), v1 = bf2f(u.y);
    float s = v0 + v1, ss = v0 * v0 + v1 * v1;
    for (int o = 32; o > 0; o >>= 1) { s += __shfl_down(s, o); ss += __shfl_down(ss, o); }
    __shared__ float red[2][4];
    __shared__ float mu_s, rs_s;
    int wid = threadIdx.x >> 6, lane = threadIdx.x & 63;
    if (lane == 0) { red[0][wid] = s; red[1][wid] = ss; }
    __syncthreads();
    if (threadIdx.x == 0) {
        float S1 = red[0][0] + red[0][1] + red[0][2] + red[0][3];
        float S2 = red[1][0] + red[1][1] + red[1][2] + red[1][3];
        float mu = S1 * (1.0f / Cch);
        float var = S2 * (1.0f / Cch) - mu * mu;
        mu_s = mu; rs_s = rsqrtf(var + EPSV);
    }
    __syncthreads();
    float mu = mu_s, rs = rs_s;
    outp[(size_t)row * Cch + i0]     = f2bf((v0 - mu) * rs * w[i0] + bb[i0]);
    outp[(size_t)row * Cch + i0 + 1] = f2bf((v1 - mu) * rs * w[i0 + 1] + bb[i0 + 1]);
}

// ---------------- MFMA GEMM: out(MxN) = A(MxK bf16) @ Bt(NxK bf16)^T ----------------
// 256x128 tile, BK=32, 512 thr = 8 waves (4x2). Per-wave 64x64; swizzled LDS (swzg).
// EPI: 0 = bf16; 1 = fp32 +bias; 6 = bf16 +bias; 7 = bf16 +bias + bf16 residual in-place;
//      8 = bf16 routed qkv (outb base = qb; col>>9 selects q/k/v slot, 8388608 apart).
template<int EPI>
__global__ __launch_bounds__(512) void mfma_gemm(const u16* __restrict__ A,
                                                 const u16* __restrict__ Bt,
                                                 const float* __restrict__ bias,
                                                 float* __restrict__ fout,
                                                 u16* __restrict__ outb,
                                                 int K, int N) {
    __shared__ u16 As[256 * 32];
    __shared__ u16 Bs[128 * 32];
    int tid = threadIdx.x;
    int m0 = blockIdx.y * 256, n0 = blockIdx.x * 128;
    int wave = tid >> 6, lane = tid & 63;
    int wr = wave >> 1, wc = wave & 1;      // 4x2 wave grid
    int l15 = lane & 15, l4 = lane >> 4;

    f32x4 zero4 = {0.f, 0.f, 0.f, 0.f};
    f32x4 acc[4][4];
#pragma unroll
    for (int i = 0; i < 4; i++)
#pragma unroll
        for (int j = 0; j < 4; j++) acc[i][j] = zero4;

    int srow = tid >> 1;
    int sc0  = (tid & 1) * 2;
    int se   = sc0 * 8;
    int brow = tid >> 2;
    int bch  = tid & 3;
    int bqe  = bch * 8;

    int4 ra0, ra1, rb0;
    {
        const u16* pa = A  + (size_t)(m0 + srow) * K + se;
        ra0 = *(const int4*)pa; ra1 = *(const int4*)(pa + 8);
        rb0 = *(const int4*)(Bt + (size_t)(n0 + brow) * K + bqe);
    }
    for (int kt = 0; kt < K; kt += 32) {
        __syncthreads();
        *(int4*)&As[swzg(srow, sc0)]     = ra0;
        *(int4*)&As[swzg(srow, sc0 + 1)] = ra1;
        *(int4*)&Bs[swzg(brow, bch)]     = rb0;
        __syncthreads();
        int kn = kt + 32;
        if (kn < K) {
            const u16* pa = A  + (size_t)(m0 + srow) * K + kn + se;
            ra0 = *(const int4*)pa; ra1 = *(const int4*)(pa + 8);
            rb0 = *(const int4*)(Bt + (size_t)(n0 + brow) * K + kn + bqe);
        }
        bf16x8 af[4], bfr[4];
#pragma unroll
        for (int mi = 0; mi < 4; mi++)
            af[mi] = *(const bf16x8*)&As[swzg(wr * 64 + mi * 16 + l15, l4)];
#pragma unroll
        for (int nj = 0; nj < 4; nj++)
            bfr[nj] = *(const bf16x8*)&Bs[swzg(wc * 64 + nj * 16 + l15, l4)];
#pragma unroll
        for (int mi = 0; mi < 4; mi++)
#pragma unroll
            for (int nj = 0; nj < 4; nj++)
                acc[mi][nj] = __builtin_amdgcn_mfma_f32_16x16x32_bf16(af[mi], bfr[nj], acc[mi][nj], 0, 0, 0);
    }

#pragma unroll
    for (int mi = 0; mi < 4; mi++)
#pragma unroll
        for (int nj = 0; nj < 4; nj++)
#pragma unroll
            for (int r = 0; r < 4; r++) {
                int row = m0 + wr * 64 + mi * 16 + l4 * 4 + r;
                int col = n0 + wc * 64 + nj * 16 + l15;
                float v = acc[mi][nj][r];
                if constexpr (EPI == 0) {
                    outb[(size_t)row * N + col] = f2bf(v);
                } else if constexpr (EPI == 1) {
                    fout[(size_t)row * N + col] = v + bias[col];
                } else if constexpr (EPI == 6) {
                    outb[(size_t)row * N + col] = f2bf(v + bias[col]);
                } else if constexpr (EPI == 7) {
                    size_t idx = (size_t)row * N + col;
                    v += bias[col] + bf2f(outb[idx]);
                    outb[idx] = f2bf(v);
                } else if constexpr (EPI == 8) {
                    size_t idx = (size_t)(col >> 9) * 8388608 + (size_t)row * 512 + (col & 511);
                    outb[idx] = f2bf(v);
                }
            }
}

// ---------------- GEGLU MFMA: 256x64(x2 halves) tile, 8 waves, fused exact GELU --------
__global__ __launch_bounds__(512) void geglu_mfma(const u16* __restrict__ A,
                                                  const u16* __restrict__ WgT,  // [4096][512]
                                                  const float* __restrict__ bg,
                                                  u16* __restrict__ ag) {
    __shared__ u16 As[256 * 32];
    __shared__ u16 Bs1[64 * 32];
    __shared__ u16 Bs2[64 * 32];
    const int K = 512;
    int tid = threadIdx.x;
    int m0 = blockIdx.y * 256, n0 = blockIdx.x * 64;
    int wave = tid >> 6, lane = tid & 63;
    int wr = wave >> 1, wc = wave & 1;
    int l15 = lane & 15, l4 = lane >> 4;

    f32x4 zero4 = {0.f, 0.f, 0.f, 0.f};
    f32x4 accA[4][2], accG[4][2];
#pragma unroll
    for (int i = 0; i < 4; i++) { accA[i][0] = zero4; accA[i][1] = zero4; accG[i][0] = zero4; accG[i][1] = zero4; }

    int srow = tid >> 1;
    int sc0  = (tid & 1) * 2;
    int se   = sc0 * 8;
    int bsel = tid >> 8;
    int bt   = tid & 255;
    int brow = bt >> 2;
    int bch  = bt & 3;
    int bqe  = bch * 8;
    const u16* gbp = WgT + (size_t)(bsel * 2048 + n0 + brow) * K + bqe;

    int4 ra0, ra1, rb;
    {
        const u16* pa = A + (size_t)(m0 + srow) * K + se;
        ra0 = *(const int4*)pa; ra1 = *(const int4*)(pa + 8);
        rb = *(const int4*)gbp;
    }
    for (int kt = 0; kt < K; kt += 32) {
        __syncthreads();
        *(int4*)&As[swzg(srow, sc0)]     = ra0;
        *(int4*)&As[swzg(srow, sc0 + 1)] = ra1;
        if (bsel == 0) *(int4*)&Bs1[swzg(brow, bch)] = rb;
        else           *(int4*)&Bs2[swzg(brow, bch)] = rb;
        __syncthreads();
        int kn = kt + 32;
        if (kn < K) {
            const u16* pa = A + (size_t)(m0 + srow) * K + kn + se;
            ra0 = *(const int4*)pa; ra1 = *(const int4*)(pa + 8);
            rb = *(const int4*)(gbp + kn);
        }
        bf16x8 af[4], b1[2], b2[2];
#pragma unroll
        for (int mi = 0; mi < 4; mi++)
            af[mi] = *(const bf16x8*)&As[swzg(wr * 64 + mi * 16 + l15, l4)];
#pragma unroll
        for (int nj = 0; nj < 2; nj++) {
            b1[nj] = *(const bf16x8*)&Bs1[swzg(wc * 32 + nj * 16 + l15, l4)];
            b2[nj] = *(const bf16x8*)&Bs2[swzg(wc * 32 + nj * 16 + l15, l4)];
        }
#pragma unroll
        for (int mi = 0; mi < 4; mi++)
#pragma unroll
            for (int nj = 0; nj < 2; nj++) {
                accA[mi][nj] = __builtin_amdgcn_mfma_f32_16x16x32_bf16(af[mi], b1[nj], accA[mi][nj], 0, 0, 0);
                accG[mi][nj] = __builtin_amdgcn_mfma_f32_16x16x32_bf16(af[mi], b2[nj], accG[mi][nj], 0, 0, 0);
            }
    }

#pragma unroll
    for (int mi = 0; mi < 4; mi++)
#pragma unroll
        for (int nj = 0; nj < 2; nj++)
#pragma unroll
            for (int r = 0; r < 4; r++) {
                int row = m0 + wr * 64 + mi * 16 + l4 * 4 + r;
                int col = n0 + wc * 32 + nj * 16 + l15;
                float a = accA[mi][nj][r] + bg[col];
                float g = accG[mi][nj][r] + bg[2048 + col];
                float ge = 0.5f * g * (1.0f + erff(g * 0.70710678118654752f));
                ag[(size_t)row * 2048 + col] = f2bf(a * ge);
            }
}

// ---------------- MFMA flash attention: QBLK=128 (8 waves), KVBLK=128 ------------
// Conflict-free staging maps: within-row lanes hit distinct bank groups.
// LDS 64 KB: Ps[128][128] (Q stage -> P -> O stage), Ks[128][64], Vt[64][128].
__global__ __launch_bounds__(512) void flash_attn_mfma(const u16* __restrict__ q,
                                                       const u16* __restrict__ k,
                                                       const u16* __restrict__ vt,  // [b*8+h][64][1024]
                                                       u16* __restrict__ o) {
    __shared__ u16 Ps[128 * 128];
    __shared__ u16 Ks[128 * 64];
    __shared__ u16 Vt[64 * 128];
    const int tid = threadIdx.x;
    const int h = blockIdx.y, b = blockIdx.z;
    const int q0 = blockIdx.x * 128;
    const size_t hb  = (size_t)b * Ss * Cch + (size_t)h * DHh;
    const size_t vhb = ((size_t)(b * NHh + h) * DHh) * Ss;

    const int wq = tid >> 6;               // 0..7: wave owns q-rows wq*16..wq*16+15
    const int lane = tid & 63;
    const int l15 = lane & 15, l4 = lane >> 4;

    // stage Q (128x64) into Ps chunks 0..7, conflict-free map
    {
        int r = tid >> 2, ch = (tid & 3) * 2;
        const u16* src = q + hb + (size_t)(q0 + r) * Cch;
        *(int4*)&Ps[swz128(r, ch)]     = *(const int4*)(src + ch * 8);
        *(int4*)&Ps[swz128(r, ch + 1)] = *(const int4*)(src + (ch + 1) * 8);
    }
    __syncthreads();
    bf16x8 aq[2];
    aq[0] = *(const bf16x8*)&Ps[swz128(wq * 16 + l15, 0 * 4 + l4)];
    aq[1] = *(const bf16x8*)&Ps[swz128(wq * 16 + l15, 1 * 4 + l4)];

    f32x4 zero4 = {0.f, 0.f, 0.f, 0.f};
    f32x4 oacc[4];
    float m_[4], l_[4];
#pragma unroll
    for (int j = 0; j < 4; j++) oacc[j] = zero4;
#pragma unroll
    for (int r = 0; r < 4; r++) { m_[r] = -1e30f; l_[r] = 0.f; }

    for (int t0 = 0; t0 < Ss; t0 += 128) {
        __syncthreads();
        {
            // K: 128 rows x 64 u16; thread -> row tid>>2, chunk pair {2c, 2c+1}
            int r = tid >> 2, ck = (tid & 3) * 2;
            const u16* ksrc = k + hb + (size_t)(t0 + r) * Cch;
            *(int4*)&Ks[swz(r, ck)]     = *(const int4*)(ksrc + ck * 8);
            *(int4*)&Ks[swz(r, ck + 1)] = *(const int4*)(ksrc + (ck + 1) * 8);
            // V: 64 rows x 128 u16; thread -> row tid>>3, chunks {cv, cv+8}
            int d = tid >> 3, cv = tid & 7;
            const u16* vsrc = vt + vhb + (size_t)d * Ss + t0;
            *(int4*)&Vt[swz128(d, cv)]     = *(const int4*)(vsrc + cv * 8);
            *(int4*)&Vt[swz128(d, cv + 8)] = *(const int4*)(vsrc + (cv + 8) * 8);
        }
        __syncthreads();

        // QK^T (log2-scaled): wave's 16 q-rows x 128 t-cols
        f32x4 sacc[8];
#pragma unroll
        for (int j = 0; j < 8; j++) sacc[j] = zero4;
#pragma unroll
        for (int ks = 0; ks < 2; ks++) {
#pragma unroll
            for (int j = 0; j < 8; j++) {
                bf16x8 bk = *(const bf16x8*)&Ks[swz(j * 16 + l15, ks * 4 + l4)];
                sacc[j] = __builtin_amdgcn_mfma_f32_16x16x32_bf16(aq[ks], bk, sacc[j], 0, 0, 0);
            }
        }

        float tmv[4];
        int grew = 0;
#pragma unroll
        for (int r = 0; r < 4; r++) {
            float tm = fmaxf(fmaxf(fmaxf(sacc[0][r], sacc[1][r]), fmaxf(sacc[2][r], sacc[3][r])),
                             fmaxf(fmaxf(sacc[4][r], sacc[5][r]), fmaxf(sacc[6][r], sacc[7][r])));
            tm = fmaxf(tm, __shfl_xor(tm, 1));
            tm = fmaxf(tm, __shfl_xor(tm, 2));
            tm = fmaxf(tm, __shfl_xor(tm, 4));
            tm = fmaxf(tm, __shfl_xor(tm, 8));
            tmv[r] = tm;
            grew |= (tm > m_[r]);
        }

        if (__any(grew)) {
#pragma unroll
            for (int r = 0; r < 4; r++) {
                float nm = fmaxf(m_[r], tmv[r]);
                float sc = exp2_raw(m_[r] - nm);
                m_[r] = nm;
                int row = wq * 16 + l4 * 4 + r;
                int rx = row & 7, base = row * 128, wi = l15 & 7, hi = l15 >> 3;
                float rs = 0.f;
#pragma unroll
                for (int j = 0; j < 8; j++) {
                    float p = exp2_raw(sacc[j][r] - nm);
                    Ps[base + (((2 * j + hi) ^ rx) * 8) + wi] = f2bf_rz(p);
                    rs += p;
                }
                l_[r] = l_[r] * sc + rs;
#pragma unroll
                for (int j = 0; j < 4; j++) oacc[j][r] *= sc;
            }
        } else {
#pragma unroll
            for (int r = 0; r < 4; r++) {
                float nm = m_[r];
                int row = wq * 16 + l4 * 4 + r;
                int rx = row & 7, base = row * 128, wi = l15 & 7, hi = l15 >> 3;
                float rs = 0.f;
#pragma unroll
                for (int j = 0; j < 8; j++) {
                    float p = exp2_raw(sacc[j][r] - nm);
                    Ps[base + (((2 * j + hi) ^ rx) * 8) + wi] = f2bf_rz(p);
                    rs += p;
                }
                l_[r] += rs;
            }
        }

        // PV: A=Ps (wave-private rows, k=128 -> 4 ks), Bt=Vt[d][t]
#pragma unroll
        for (int ks = 0; ks < 4; ks++) {
            bf16x8 pa = *(const bf16x8*)&Ps[swz128(wq * 16 + l15, ks * 4 + l4)];
#pragma unroll
            for (int j = 0; j < 4; j++) {
                bf16x8 bv = *(const bf16x8*)&Vt[swz128(j * 16 + l15, ks * 4 + l4)];
                oacc[j] = __builtin_amdgcn_mfma_f32_16x16x32_bf16(pa, bv, oacc[j], 0, 0, 0);
            }
        }
    }

    // finalize: reduce per-lane l partials, O /= l, stage via Ps, coalesced store
#pragma unroll
    for (int r = 0; r < 4; r++) {
        float lt = l_[r];
        lt += __shfl_xor(lt, 1);
        lt += __shfl_xor(lt, 2);
        lt += __shfl_xor(lt, 4);
        lt += __shfl_xor(lt, 8);
        float inv = 1.0f / lt;
        int row = wq * 16 + l4 * 4 + r;
        int rx = row & 7, base = row * 128, wi = l15 & 7, hi = l15 >> 3;
#pragma unroll
        for (int j = 0; j < 4; j++)
            Ps[base + (((2 * j + hi) ^ rx) * 8) + wi] = f2bf(oacc[j][r] * inv);
    }
    __syncthreads();
    {
        int r = tid >> 2, ch = (tid & 3) * 2;
        u16* dst = o + hb + (size_t)(q0 + r) * Cch;
        *(int4*)(dst + ch * 8)       = *(const int4*)&Ps[swz128(r, ch)];
        *(int4*)(dst + (ch + 1) * 8) = *(const int4*)&Ps[swz128(r, ch + 1)];
    }
}

// ---------------- final: out(B,C,S) = tmp(B,S,C)^T + x ----------------
__global__ __launch_bounds__(256) void final_out(const float* __restrict__ tmp,
                                                 const float* __restrict__ x,
                                                 float* __restrict__ outp) {
    __shared__ float tile[32][33];
    int b = blockIdx.z, c0 = blockIdx.y * 32, s0 = blockIdx.x * 32;
    int tx = threadIdx.x, ty = threadIdx.y;
#pragma unroll
    for (int i = 0; i < 4; i++) {
        int s = s0 + ty + i * 8;
        tile[ty + i * 8][tx] = tmp[((size_t)b * Ss + s) * Cch + c0 + tx];
    }
    __syncthreads();
#pragma unroll
    for (int i = 0; i < 4; i++) {
        int c = c0 + ty + i * 8;
        size_t idx = ((size_t)b * Cch + c) * Ss + s0 + tx;
        outp[idx] = tile[tx][ty + i * 8] + x[idx];
    }
}

extern "C" void kernel_launch(void* const* d_in, const int* in_sizes, int n_in,
                              void* d_out, int out_size, void* d_ws, size_t ws_size,
                              hipStream_t stream) {
    (void)in_sizes; (void)n_in; (void)out_size; (void)ws_size;
    const float* x      = (const float*)d_in[0];
    const float* gn_w   = (const float*)d_in[1];
    const float* gn_b   = (const float*)d_in[2];
    const float* pin_w  = (const float*)d_in[3];
    const float* pin_b  = (const float*)d_in[4];
    const float* ln1_w  = (const float*)d_in[5];
    const float* ln1_b  = (const float*)d_in[6];
    const float* wq     = (const float*)d_in[7];
    const float* wk     = (const float*)d_in[8];
    const float* wv     = (const float*)d_in[9];
    const float* wo     = (const float*)d_in[10];
    const float* bo     = (const float*)d_in[11];
    const float* ln3_w  = (const float*)d_in[12];
    const float* ln3_b  = (const float*)d_in[13];
    const float* wg     = (const float*)d_in[14];
    const float* bg     = (const float*)d_in[15];
    const float* wd     = (const float*)d_in[16];
    const float* bd     = (const float*)d_in[17];
    const float* pout_w = (const float*)d_in[18];
    const float* pout_b = (const float*)d_in[19];
    float* out = (float*)d_out;

    // ---- workspace layout (bytes) ----
    char* W = (char*)d_ws;
    u16* tb        = (u16*)W;                                     // t residual, bf16, 16.78 MB
    float* tmp_f32 = (float*)(W + 33554432);                      // 33.55 MB
    u16* qb    = (u16*)(W + 67108864);                            // 16.78 MB (qb,kb,vb contiguous)
    u16* kb    = qb + 8388608;
    u16* vb    = kb + 8388608;
    u16* attnb = vb + 8388608;
    u16* Xb    = attnb + 8388608;                                 // 16.78 MB
    float* stats = (float*)(W + 67108864 + 5ull * 16777216);      // 1 KB
    u16* wbase = (u16*)(W + 67108864 + 5ull * 16777216 + 1024);
    u16* pinB  = wbase;                 // 512*512  (already [N][K])
    u16* poutB = pinB  + 262144;
    u16* wqT   = poutB + 262144;        // [512][512] transposed, scaled by QSCL
    u16* wkT   = wqT   + 262144;        // contiguous with wqT -> [1536][512] for fused qkv
    u16* wvT   = wkT   + 262144;
    u16* woT   = wvT   + 262144;
    u16* wgT   = woT   + 262144;        // [4096][512]
    u16* wdT   = wgT   + 2097152;       // [512][2048]
    u16* ag    = qb;                    // R x 2048 bf16, aliases qb..attnb (dead by then)
    u16* vtb   = (u16*)tmp_f32;         // V^T [b*8+h][64][1024], aliases tmp_f32 (dead until pout)

    dim3 tb8(32, 8);

    // stats + fused weight prep (2 launches)
    gn_stats<<<128, 256, 0, stream>>>(x, stats);
    prep_all<<<4608, tb8, 0, stream>>>(pin_w, pout_w, pinB, poutB,
                                       wq, wk, wv, wo, wqT, wkT, wvT, woT,
                                       wg, wgT, wd, wdT);

    // h = GN(x) transposed -> Xb (bf16)
    gn_apply_t_bf<<<dim3(32, 16, 16), tb8, 0, stream>>>(x, stats, gn_w, gn_b, Xb);

    // t = h @ pin_w^T + pin_b -> tb (bf16)
    mfma_gemm<6><<<dim3(4, 64), 512, 0, stream>>>(Xb, pinB, pin_b, nullptr, tb, 512, 512);
    // tn = ln1(t) -> Xb
    layer_norm_rows_bf<<<16384, 256, 0, stream>>>(tb, ln1_w, ln1_b, Xb);
    // fused q(scaled)/k/v: N=1536, routed to qb/kb/vb
    mfma_gemm<8><<<dim3(12, 64), 512, 0, stream>>>(Xb, wqT, nullptr, nullptr, qb, 512, 1536);
    // per-head V transpose -> vtb
    vtrans<<<dim3(16, 8, 16), 256, 0, stream>>>(vb, vtb);
    // attention (MFMA, QBLK=128, KVBLK=128) -> attnb (bf16)
    flash_attn_mfma<<<dim3(8, 8, 16), 512, 0, stream>>>(qb, kb, vtb, attnb);
    // t += attn @ wo + bo (bf16 in-place on tb)
    mfma_gemm<7><<<dim3(4, 64), 512, 0, stream>>>(attnb, woT, bo, nullptr, tb, 512, 512);
    // tn3 = ln3(t) -> Xb
    layer_norm_rows_bf<<<16384, 256, 0, stream>>>(tb, ln3_w, ln3_b, Xb);
    // ag = a * gelu(g) (bf16), aliases q/k/v/attn space
    geglu_mfma<<<dim3(32, 64), 512, 0, stream>>>(Xb, wgT, bg, ag);
    // t += ag @ wd + bd (bf16 in-place on tb)
    mfma_gemm<7><<<dim3(4, 64), 512, 0, stream>>>(ag, wdT, bd, nullptr, tb, 2048, 512);
    // tmp = t @ pout_w^T + pout_b -> tmp_f32
    mfma_gemm<1><<<dim3(4, 64), 512, 0, stream>>>(tb, poutB, pout_b, tmp_f32, nullptr, 512, 512);
    // out = tmp^T + x
    final_out<<<dim3(32, 16, 16), tb8, 0, stream>>>(tmp_f32, x, out);
}

// Round 25
// 438.850 us; speedup vs baseline: 1.2720x; 1.0048x over previous
//
#include <hip/hip_runtime.h>
#include <hip/hip_bf16.h>
#include <math.h>

typedef unsigned short u16;
typedef __attribute__((ext_vector_type(8))) short bf16x8;
typedef __attribute__((ext_vector_type(4))) float f32x4;

#define Bb 16
#define Cch 512
#define Ss 1024
#define NHh 8
#define DHh 64
#define CPG 64
#define EPSV 1e-5f
#define R_TOTAL (Bb*Ss)   // 16384
#define QSCL 0.18033688011112042f   // 0.125 * log2(e)

__device__ inline u16 f2bf(float f) {
    unsigned int u = __float_as_uint(f);
    unsigned int r = (u + 0x7fffu + ((u >> 16) & 1u)) >> 16;
    return (u16)r;
}
__device__ inline u16 f2bf_rz(float f) { return (u16)(__float_as_uint(f) >> 16); }
__device__ inline float bf2f(u16 v) { return __uint_as_float((unsigned)v << 16); }
__device__ inline float exp2_raw(float x) {
    float r; asm("v_exp_f32 %0, %1" : "=v"(r) : "v"(x)); return r;
}

// swizzles: 16B chunk XOR'd by row&7 within stride-64 rows (proven clean r14-r19).
__device__ inline int swz(int row, int chunk) {      // [R][64] tile
    return row * 64 + ((chunk ^ (row & 7)) * 8);
}
// 128-wide tiles split into two stride-64 halves (chunk bit 3 = half select, wave-uniform
// in every access) so all within-instruction patterns match the measured-clean config.
__device__ inline int psw(int row, int chunk) {      // Ps[128][128]: halves of [128][64]
    return ((chunk >> 3) << 13) + row * 64 + (((chunk & 7) ^ (row & 7)) * 8);
}
__device__ inline int vsw(int row, int chunk) {      // Vt[64][128]: halves of [64][64]
    return ((chunk >> 3) << 12) + row * 64 + (((chunk & 7) ^ (row & 7)) * 8);
}
__device__ inline int swzg(int r, int c) {           // GEMM [R][32] tile
    int span = r >> 1;
    int c8 = ((r & 1) << 2) | c;
    return span * 64 + ((c8 ^ (span & 7)) * 8);
}

// ---------------- GroupNorm stats (float4 loads) ----------------
__global__ __launch_bounds__(256) void gn_stats(const float* __restrict__ x,
                                                float* __restrict__ stats) {
    int bg = blockIdx.x;
    int b = bg >> 3, g = bg & 7;
    const float4* base = (const float4*)(x + ((size_t)b * Cch + (size_t)g * CPG) * Ss);
    float s = 0.f, ss = 0.f;
    for (int i = threadIdx.x; i < CPG * Ss / 4; i += 256) {
        float4 v = base[i];
        s  += v.x + v.y + v.z + v.w;
        ss += v.x * v.x + v.y * v.y + v.z * v.z + v.w * v.w;
    }
    for (int o = 32; o > 0; o >>= 1) { s += __shfl_down(s, o); ss += __shfl_down(ss, o); }
    __shared__ float red[2][4];
    int wid = threadIdx.x >> 6, lane = threadIdx.x & 63;
    if (lane == 0) { red[0][wid] = s; red[1][wid] = ss; }
    __syncthreads();
    if (threadIdx.x == 0) {
        float S1 = red[0][0] + red[0][1] + red[0][2] + red[0][3];
        float S2 = red[1][0] + red[1][1] + red[1][2] + red[1][3];
        const float inv_n = 1.0f / (CPG * Ss);
        float mu = S1 * inv_n;
        float var = S2 * inv_n - mu * mu;
        stats[bg * 2]     = mu;
        stats[bg * 2 + 1] = rsqrtf(var + EPSV);
    }
}

// ---------------- GroupNorm apply + transpose -> bf16 (B,S,C) ----------------
__global__ __launch_bounds__(256) void gn_apply_t_bf(const float* __restrict__ x,
                                                     const float* __restrict__ stats,
                                                     const float* __restrict__ gw,
                                                     const float* __restrict__ gb,
                                                     u16* __restrict__ ht) {
    __shared__ float tile[32][33];
    int b  = blockIdx.z;
    int c0 = blockIdx.y * 32;
    int s0 = blockIdx.x * 32;
    int tx = threadIdx.x, ty = threadIdx.y;
#pragma unroll
    for (int i = 0; i < 4; i++) {
        int c = c0 + ty + i * 8;
        int g = c >> 6;
        float mu = stats[(b * 8 + g) * 2];
        float rs = stats[(b * 8 + g) * 2 + 1];
        float v = x[((size_t)b * Cch + c) * Ss + s0 + tx];
        tile[ty + i * 8][tx] = (v - mu) * rs * gw[c] + gb[c];
    }
    __syncthreads();
#pragma unroll
    for (int i = 0; i < 4; i++) {
        int s = s0 + ty + i * 8;
        ht[((size_t)b * Ss + s) * Cch + c0 + tx] = f2bf(tile[tx][ty + i * 8]);
    }
}

// ---------------- fused weight prep: ALL conversions/transposes in 1 launch ----------
__global__ __launch_bounds__(256) void prep_all(const float* __restrict__ pin_w,
                                                const float* __restrict__ pout_w,
                                                u16* __restrict__ pinB,
                                                u16* __restrict__ poutB,
                                                const float* __restrict__ wq,
                                                const float* __restrict__ wk,
                                                const float* __restrict__ wv,
                                                const float* __restrict__ wo,
                                                u16* __restrict__ wqT,
                                                u16* __restrict__ wkT,
                                                u16* __restrict__ wvT,
                                                u16* __restrict__ woT,
                                                const float* __restrict__ wg,
                                                u16* __restrict__ wgT,
                                                const float* __restrict__ wd,
                                                u16* __restrict__ wdT) {
    __shared__ float tile[32][33];
    int bid = blockIdx.x;
    int tx = threadIdx.x, ty = threadIdx.y;
    int tid = ty * 32 + tx;
    if (bid < 512) {
        int base = bid * 1024 + tid * 4;
        const float* src; u16* dst; int off;
        if (base < 262144) { src = pin_w;  dst = pinB;  off = base; }
        else               { src = pout_w; dst = poutB; off = base - 262144; }
        float4 v = *(const float4*)&src[off];
        ushort4 o;
        o.x = f2bf(v.x); o.y = f2bf(v.y); o.z = f2bf(v.z); o.w = f2bf(v.w);
        *(ushort4*)&dst[off] = o;
        return;
    }
    const float* in; u16* outp; int c0, r0, C, R; float scl = 1.0f;
    if (bid < 1536) {
        int z = (bid - 512) >> 8, rem = (bid - 512) & 255;
        switch (z) {
            case 0: in = wq; outp = wqT; scl = QSCL; break;
            case 1: in = wk; outp = wkT; break;
            case 2: in = wv; outp = wvT; break;
            default: in = wo; outp = woT; break;
        }
        c0 = (rem & 15) * 32; r0 = (rem >> 4) * 32; C = 512; R = 512;
    } else if (bid < 3584) {
        int rem = bid - 1536;
        in = wg; outp = wgT; C = 4096; R = 512;
        c0 = (rem & 127) * 32; r0 = (rem >> 7) * 32;
    } else {
        int rem = bid - 3584;
        in = wd; outp = wdT; C = 512; R = 2048;
        c0 = (rem & 15) * 32; r0 = (rem >> 4) * 32;
    }
#pragma unroll
    for (int i = 0; i < 4; i++)
        tile[ty + i * 8][tx] = in[(size_t)(r0 + ty + i * 8) * C + c0 + tx] * scl;
    __syncthreads();
#pragma unroll
    for (int i = 0; i < 4; i++)
        outp[(size_t)(c0 + ty + i * 8) * R + r0 + tx] = f2bf(tile[tx][ty + i * 8]);
}

// ---------------- per-head V transpose: vb [b][s][512] -> vt [(b*8+h)][64][1024] ----------
__global__ __launch_bounds__(256) void vtrans(const u16* __restrict__ in,
                                              u16* __restrict__ outp) {
    __shared__ u16 tile[64][66];
    int s0 = blockIdx.x * 64, h = blockIdx.y, b = blockIdx.z;
    const u16* src = in + ((size_t)b * Ss + s0) * Cch + h * 64;
    int r = threadIdx.x >> 3, c8 = (threadIdx.x & 7) * 8;
#pragma unroll
    for (int p = 0; p < 2; p++) {
        int rr = r + p * 32;
        *(int4*)&tile[rr][c8] = *(const int4*)&src[(size_t)rr * Cch + c8];
    }
    __syncthreads();
    u16* dst = outp + ((size_t)(b * 8 + h) * 64) * Ss + s0;
#pragma unroll
    for (int p = 0; p < 2; p++) {
        int d = r + p * 32;
        u16 vals[8];
#pragma unroll
        for (int e = 0; e < 8; e++) vals[e] = tile[c8 + e][d];
        *(int4*)&dst[(size_t)d * Ss + c8] = *(int4*)vals;
    }
}

// ---------------- LayerNorm rows (bf16 in, bf16 out) ----------------
__global__ __launch_bounds__(256) void layer_norm_rows_bf(const u16* __restrict__ in,
                                                          const float* __restrict__ w,
                                                          const float* __restrict__ bb,
                                                          u16* __restrict__ outp) {
    int row = blockIdx.x;
    const u16* p = in + (size_t)row * Cch;
    int i0 = threadIdx.x * 2;
    ushort2 u = *(const ushort2*)&p[i0];
    float v0 = bf2f(u.x), v1 = bf2f(u.y);
    float s = v0 + v1, ss = v0 * v0 + v1 * v1;
    for (int o = 32; o > 0; o >>= 1) { s += __shfl_down(s, o); ss += __shfl_down(ss, o); }
    __shared__ float red[2][4];
    __shared__ float mu_s, rs_s;
    int wid = threadIdx.x >> 6, lane = threadIdx.x & 63;
    if (lane == 0) { red[0][wid] = s; red[1][wid] = ss; }
    __syncthreads();
    if (threadIdx.x == 0) {
        float S1 = red[0][0] + red[0][1] + red[0][2] + red[0][3];
        float S2 = red[1][0] + red[1][1] + red[1][2] + red[1][3];
        float mu = S1 * (1.0f / Cch);
        float var = S2 * (1.0f / Cch) - mu * mu;
        mu_s = mu; rs_s = rsqrtf(var + EPSV);
    }
    __syncthreads();
    float mu = mu_s, rs = rs_s;
    outp[(size_t)row * Cch + i0]     = f2bf((v0 - mu) * rs * w[i0] + bb[i0]);
    outp[(size_t)row * Cch + i0 + 1] = f2bf((v1 - mu) * rs * w[i0 + 1] + bb[i0 + 1]);
}

// ---------------- MFMA GEMM: out(MxN) = A(MxK bf16) @ Bt(NxK bf16)^T ----------------
// 256x128 tile, BK=32, 512 thr = 8 waves (4x2). Per-wave 64x64; swizzled LDS (swzg).
// EPI: 0 = bf16; 1 = fp32 +bias; 6 = bf16 +bias; 7 = bf16 +bias + bf16 residual in-place;
//      8 = bf16 routed qkv (outb base = qb; col>>9 selects q/k/v slot, 8388608 apart).
template<int EPI>
__global__ __launch_bounds__(512) void mfma_gemm(const u16* __restrict__ A,
                                                 const u16* __restrict__ Bt,
                                                 const float* __restrict__ bias,
                                                 float* __restrict__ fout,
                                                 u16* __restrict__ outb,
                                                 int K, int N) {
    __shared__ u16 As[256 * 32];
    __shared__ u16 Bs[128 * 32];
    int tid = threadIdx.x;
    int m0 = blockIdx.y * 256, n0 = blockIdx.x * 128;
    int wave = tid >> 6, lane = tid & 63;
    int wr = wave >> 1, wc = wave & 1;      // 4x2 wave grid
    int l15 = lane & 15, l4 = lane >> 4;

    f32x4 zero4 = {0.f, 0.f, 0.f, 0.f};
    f32x4 acc[4][4];
#pragma unroll
    for (int i = 0; i < 4; i++)
#pragma unroll
        for (int j = 0; j < 4; j++) acc[i][j] = zero4;

    int srow = tid >> 1;
    int sc0  = (tid & 1) * 2;
    int se   = sc0 * 8;
    int brow = tid >> 2;
    int bch  = tid & 3;
    int bqe  = bch * 8;

    int4 ra0, ra1, rb0;
    {
        const u16* pa = A  + (size_t)(m0 + srow) * K + se;
        ra0 = *(const int4*)pa; ra1 = *(const int4*)(pa + 8);
        rb0 = *(const int4*)(Bt + (size_t)(n0 + brow) * K + bqe);
    }
    for (int kt = 0; kt < K; kt += 32) {
        __syncthreads();
        *(int4*)&As[swzg(srow, sc0)]     = ra0;
        *(int4*)&As[swzg(srow, sc0 + 1)] = ra1;
        *(int4*)&Bs[swzg(brow, bch)]     = rb0;
        __syncthreads();
        int kn = kt + 32;
        if (kn < K) {
            const u16* pa = A  + (size_t)(m0 + srow) * K + kn + se;
            ra0 = *(const int4*)pa; ra1 = *(const int4*)(pa + 8);
            rb0 = *(const int4*)(Bt + (size_t)(n0 + brow) * K + kn + bqe);
        }
        bf16x8 af[4], bfr[4];
#pragma unroll
        for (int mi = 0; mi < 4; mi++)
            af[mi] = *(const bf16x8*)&As[swzg(wr * 64 + mi * 16 + l15, l4)];
#pragma unroll
        for (int nj = 0; nj < 4; nj++)
            bfr[nj] = *(const bf16x8*)&Bs[swzg(wc * 64 + nj * 16 + l15, l4)];
#pragma unroll
        for (int mi = 0; mi < 4; mi++)
#pragma unroll
            for (int nj = 0; nj < 4; nj++)
                acc[mi][nj] = __builtin_amdgcn_mfma_f32_16x16x32_bf16(af[mi], bfr[nj], acc[mi][nj], 0, 0, 0);
    }

#pragma unroll
    for (int mi = 0; mi < 4; mi++)
#pragma unroll
        for (int nj = 0; nj < 4; nj++)
#pragma unroll
            for (int r = 0; r < 4; r++) {
                int row = m0 + wr * 64 + mi * 16 + l4 * 4 + r;
                int col = n0 + wc * 64 + nj * 16 + l15;
                float v = acc[mi][nj][r];
                if constexpr (EPI == 0) {
                    outb[(size_t)row * N + col] = f2bf(v);
                } else if constexpr (EPI == 1) {
                    fout[(size_t)row * N + col] = v + bias[col];
                } else if constexpr (EPI == 6) {
                    outb[(size_t)row * N + col] = f2bf(v + bias[col]);
                } else if constexpr (EPI == 7) {
                    size_t idx = (size_t)row * N + col;
                    v += bias[col] + bf2f(outb[idx]);
                    outb[idx] = f2bf(v);
                } else if constexpr (EPI == 8) {
                    size_t idx = (size_t)(col >> 9) * 8388608 + (size_t)row * 512 + (col & 511);
                    outb[idx] = f2bf(v);
                }
            }
}

// ---------------- GEGLU MFMA: 256x64(x2 halves) tile, 8 waves, fused exact GELU --------
__global__ __launch_bounds__(512) void geglu_mfma(const u16* __restrict__ A,
                                                  const u16* __restrict__ WgT,  // [4096][512]
                                                  const float* __restrict__ bg,
                                                  u16* __restrict__ ag) {
    __shared__ u16 As[256 * 32];
    __shared__ u16 Bs1[64 * 32];
    __shared__ u16 Bs2[64 * 32];
    const int K = 512;
    int tid = threadIdx.x;
    int m0 = blockIdx.y * 256, n0 = blockIdx.x * 64;
    int wave = tid >> 6, lane = tid & 63;
    int wr = wave >> 1, wc = wave & 1;
    int l15 = lane & 15, l4 = lane >> 4;

    f32x4 zero4 = {0.f, 0.f, 0.f, 0.f};
    f32x4 accA[4][2], accG[4][2];
#pragma unroll
    for (int i = 0; i < 4; i++) { accA[i][0] = zero4; accA[i][1] = zero4; accG[i][0] = zero4; accG[i][1] = zero4; }

    int srow = tid >> 1;
    int sc0  = (tid & 1) * 2;
    int se   = sc0 * 8;
    int bsel = tid >> 8;
    int bt   = tid & 255;
    int brow = bt >> 2;
    int bch  = bt & 3;
    int bqe  = bch * 8;
    const u16* gbp = WgT + (size_t)(bsel * 2048 + n0 + brow) * K + bqe;

    int4 ra0, ra1, rb;
    {
        const u16* pa = A + (size_t)(m0 + srow) * K + se;
        ra0 = *(const int4*)pa; ra1 = *(const int4*)(pa + 8);
        rb = *(const int4*)gbp;
    }
    for (int kt = 0; kt < K; kt += 32) {
        __syncthreads();
        *(int4*)&As[swzg(srow, sc0)]     = ra0;
        *(int4*)&As[swzg(srow, sc0 + 1)] = ra1;
        if (bsel == 0) *(int4*)&Bs1[swzg(brow, bch)] = rb;
        else           *(int4*)&Bs2[swzg(brow, bch)] = rb;
        __syncthreads();
        int kn = kt + 32;
        if (kn < K) {
            const u16* pa = A + (size_t)(m0 + srow) * K + kn + se;
            ra0 = *(const int4*)pa; ra1 = *(const int4*)(pa + 8);
            rb = *(const int4*)(gbp + kn);
        }
        bf16x8 af[4], b1[2], b2[2];
#pragma unroll
        for (int mi = 0; mi < 4; mi++)
            af[mi] = *(const bf16x8*)&As[swzg(wr * 64 + mi * 16 + l15, l4)];
#pragma unroll
        for (int nj = 0; nj < 2; nj++) {
            b1[nj] = *(const bf16x8*)&Bs1[swzg(wc * 32 + nj * 16 + l15, l4)];
            b2[nj] = *(const bf16x8*)&Bs2[swzg(wc * 32 + nj * 16 + l15, l4)];
        }
#pragma unroll
        for (int mi = 0; mi < 4; mi++)
#pragma unroll
            for (int nj = 0; nj < 2; nj++) {
                accA[mi][nj] = __builtin_amdgcn_mfma_f32_16x16x32_bf16(af[mi], b1[nj], accA[mi][nj], 0, 0, 0);
                accG[mi][nj] = __builtin_amdgcn_mfma_f32_16x16x32_bf16(af[mi], b2[nj], accG[mi][nj], 0, 0, 0);
            }
    }

#pragma unroll
    for (int mi = 0; mi < 4; mi++)
#pragma unroll
        for (int nj = 0; nj < 2; nj++)
#pragma unroll
            for (int r = 0; r < 4; r++) {
                int row = m0 + wr * 64 + mi * 16 + l4 * 4 + r;
                int col = n0 + wc * 32 + nj * 16 + l15;
                float a = accA[mi][nj][r] + bg[col];
                float g = accG[mi][nj][r] + bg[2048 + col];
                float ge = 0.5f * g * (1.0f + erff(g * 0.70710678118654752f));
                ag[(size_t)row * 2048 + col] = f2bf(a * ge);
            }
}

// ---------------- MFMA flash attention: QBLK=128 (8 waves), KVBLK=128 ------------
// Ps/Vt split into stride-64 halves (psw/vsw) so every access matches the
// measured-conflict-free pattern; chunk bit 3 (half select) is wave-uniform.
__global__ __launch_bounds__(512) void flash_attn_mfma(const u16* __restrict__ q,
                                                       const u16* __restrict__ k,
                                                       const u16* __restrict__ vt,  // [b*8+h][64][1024]
                                                       u16* __restrict__ o) {
    __shared__ u16 Ps[2 * 128 * 64];
    __shared__ u16 Ks[128 * 64];
    __shared__ u16 Vt[2 * 64 * 64];
    const int tid = threadIdx.x;
    const int h = blockIdx.y, b = blockIdx.z;
    const int q0 = blockIdx.x * 128;
    const size_t hb  = (size_t)b * Ss * Cch + (size_t)h * DHh;
    const size_t vhb = ((size_t)(b * NHh + h) * DHh) * Ss;

    const int wq = tid >> 6;               // 0..7: wave owns q-rows wq*16..wq*16+15
    const int lane = tid & 63;
    const int l15 = lane & 15, l4 = lane >> 4;

    // stage Q (128x64) into Ps half 0 (chunks 0..7)
    {
        int r = tid >> 2, ch = (tid & 3) * 2;
        const u16* src = q + hb + (size_t)(q0 + r) * Cch;
        *(int4*)&Ps[psw(r, ch)]     = *(const int4*)(src + ch * 8);
        *(int4*)&Ps[psw(r, ch + 1)] = *(const int4*)(src + (ch + 1) * 8);
    }
    __syncthreads();
    bf16x8 aq[2];
    aq[0] = *(const bf16x8*)&Ps[psw(wq * 16 + l15, 0 * 4 + l4)];
    aq[1] = *(const bf16x8*)&Ps[psw(wq * 16 + l15, 1 * 4 + l4)];

    f32x4 zero4 = {0.f, 0.f, 0.f, 0.f};
    f32x4 oacc[4];
    float m_[4], l_[4];
#pragma unroll
    for (int j = 0; j < 4; j++) oacc[j] = zero4;
#pragma unroll
    for (int r = 0; r < 4; r++) { m_[r] = -1e30f; l_[r] = 0.f; }

    for (int t0 = 0; t0 < Ss; t0 += 128) {
        __syncthreads();
        {
            // K: 128 rows x 64 u16; thread -> row tid>>2, chunk pair {2c, 2c+1}
            int r = tid >> 2, ck = (tid & 3) * 2;
            const u16* ksrc = k + hb + (size_t)(t0 + r) * Cch;
            *(int4*)&Ks[swz(r, ck)]     = *(const int4*)(ksrc + ck * 8);
            *(int4*)&Ks[swz(r, ck + 1)] = *(const int4*)(ksrc + (ck + 1) * 8);
            // V: 64 rows x 128 u16 as two halves; half hf = tid>>8, within-half
            // thread t: row t>>2, chunk pair {2c, 2c+1} (proven-clean map)
            int hf = tid >> 8, t = tid & 255;
            int d = t >> 2, cv = (t & 3) * 2;
            const u16* vsrc = vt + vhb + (size_t)d * Ss + t0 + hf * 64;
            *(int4*)&Vt[vsw(d, hf * 8 + cv)]     = *(const int4*)(vsrc + cv * 8);
            *(int4*)&Vt[vsw(d, hf * 8 + cv + 1)] = *(const int4*)(vsrc + (cv + 1) * 8);
        }
        __syncthreads();

        // QK^T (log2-scaled): wave's 16 q-rows x 128 t-cols
        f32x4 sacc[8];
#pragma unroll
        for (int j = 0; j < 8; j++) sacc[j] = zero4;
#pragma unroll
        for (int ks = 0; ks < 2; ks++) {
#pragma unroll
            for (int j = 0; j < 8; j++) {
                bf16x8 bk = *(const bf16x8*)&Ks[swz(j * 16 + l15, ks * 4 + l4)];
                sacc[j] = __builtin_amdgcn_mfma_f32_16x16x32_bf16(aq[ks], bk, sacc[j], 0, 0, 0);
            }
        }

        float tmv[4];
        int grew = 0;
#pragma unroll
        for (int r = 0; r < 4; r++) {
            float tm = fmaxf(fmaxf(fmaxf(sacc[0][r], sacc[1][r]), fmaxf(sacc[2][r], sacc[3][r])),
                             fmaxf(fmaxf(sacc[4][r], sacc[5][r]), fmaxf(sacc[6][r], sacc[7][r])));
            tm = fmaxf(tm, __shfl_xor(tm, 1));
            tm = fmaxf(tm, __shfl_xor(tm, 2));
            tm = fmaxf(tm, __shfl_xor(tm, 4));
            tm = fmaxf(tm, __shfl_xor(tm, 8));
            tmv[r] = tm;
            grew |= (tm > m_[r]);
        }

        if (__any(grew)) {
#pragma unroll
            for (int r = 0; r < 4; r++) {
                float nm = fmaxf(m_[r], tmv[r]);
                float sc = exp2_raw(m_[r] - nm);
                m_[r] = nm;
                int row = wq * 16 + l4 * 4 + r;
                int rx = row & 7, b64 = row * 64, wi = l15 & 7, hi = l15 >> 3;
                float rs = 0.f;
#pragma unroll
                for (int j = 0; j < 8; j++) {
                    float p = exp2_raw(sacc[j][r] - nm);
                    int cnk = 2 * j + hi;
                    Ps[((cnk >> 3) << 13) + b64 + (((cnk & 7) ^ rx) * 8) + wi] = f2bf_rz(p);
                    rs += p;
                }
                l_[r] = l_[r] * sc + rs;
#pragma unroll
                for (int j = 0; j < 4; j++) oacc[j][r] *= sc;
            }
        } else {
#pragma unroll
            for (int r = 0; r < 4; r++) {
                float nm = m_[r];
                int row = wq * 16 + l4 * 4 + r;
                int rx = row & 7, b64 = row * 64, wi = l15 & 7, hi = l15 >> 3;
                float rs = 0.f;
#pragma unroll
                for (int j = 0; j < 8; j++) {
                    float p = exp2_raw(sacc[j][r] - nm);
                    int cnk = 2 * j + hi;
                    Ps[((cnk >> 3) << 13) + b64 + (((cnk & 7) ^ rx) * 8) + wi] = f2bf_rz(p);
                    rs += p;
                }
                l_[r] += rs;
            }
        }

        // PV: A=Ps (wave-private rows, k=128 -> 4 ks), Bt=Vt[d][t]
#pragma unroll
        for (int ks = 0; ks < 4; ks++) {
            bf16x8 pa = *(const bf16x8*)&Ps[psw(wq * 16 + l15, ks * 4 + l4)];
#pragma unroll
            for (int j = 0; j < 4; j++) {
                bf16x8 bv = *(const bf16x8*)&Vt[vsw(j * 16 + l15, ks * 4 + l4)];
                oacc[j] = __builtin_amdgcn_mfma_f32_16x16x32_bf16(pa, bv, oacc[j], 0, 0, 0);
            }
        }
    }

    // finalize: reduce per-lane l partials, O /= l, stage via Ps half 0, coalesced store
#pragma unroll
    for (int r = 0; r < 4; r++) {
        float lt = l_[r];
        lt += __shfl_xor(lt, 1);
        lt += __shfl_xor(lt, 2);
        lt += __shfl_xor(lt, 4);
        lt += __shfl_xor(lt, 8);
        float inv = 1.0f / lt;
        int row = wq * 16 + l4 * 4 + r;
        int rx = row & 7, b64 = row * 64, wi = l15 & 7, hi = l15 >> 3;
#pragma unroll
        for (int j = 0; j < 4; j++) {
            int cnk = 2 * j + hi;    // 0..7 (half 0)
            Ps[b64 + ((cnk ^ rx) * 8) + wi] = f2bf(oacc[j][r] * inv);
        }
    }
    __syncthreads();
    {
        int r = tid >> 2, ch = (tid & 3) * 2;
        u16* dst = o + hb + (size_t)(q0 + r) * Cch;
        *(int4*)(dst + ch * 8)       = *(const int4*)&Ps[psw(r, ch)];
        *(int4*)(dst + (ch + 1) * 8) = *(const int4*)&Ps[psw(r, ch + 1)];
    }
}

// ---------------- final: out(B,C,S) = tmp(B,S,C)^T + x ----------------
__global__ __launch_bounds__(256) void final_out(const float* __restrict__ tmp,
                                                 const float* __restrict__ x,
                                                 float* __restrict__ outp) {
    __shared__ float tile[32][33];
    int b = blockIdx.z, c0 = blockIdx.y * 32, s0 = blockIdx.x * 32;
    int tx = threadIdx.x, ty = threadIdx.y;
#pragma unroll
    for (int i = 0; i < 4; i++) {
        int s = s0 + ty + i * 8;
        tile[ty + i * 8][tx] = tmp[((size_t)b * Ss + s) * Cch + c0 + tx];
    }
    __syncthreads();
#pragma unroll
    for (int i = 0; i < 4; i++) {
        int c = c0 + ty + i * 8;
        size_t idx = ((size_t)b * Cch + c) * Ss + s0 + tx;
        outp[idx] = tile[tx][ty + i * 8] + x[idx];
    }
}

extern "C" void kernel_launch(void* const* d_in, const int* in_sizes, int n_in,
                              void* d_out, int out_size, void* d_ws, size_t ws_size,
                              hipStream_t stream) {
    (void)in_sizes; (void)n_in; (void)out_size; (void)ws_size;
    const float* x      = (const float*)d_in[0];
    const float* gn_w   = (const float*)d_in[1];
    const float* gn_b   = (const float*)d_in[2];
    const float* pin_w  = (const float*)d_in[3];
    const float* pin_b  = (const float*)d_in[4];
    const float* ln1_w  = (const float*)d_in[5];
    const float* ln1_b  = (const float*)d_in[6];
    const float* wq     = (const float*)d_in[7];
    const float* wk     = (const float*)d_in[8];
    const float* wv     = (const float*)d_in[9];
    const float* wo     = (const float*)d_in[10];
    const float* bo     = (const float*)d_in[11];
    const float* ln3_w  = (const float*)d_in[12];
    const float* ln3_b  = (const float*)d_in[13];
    const float* wg     = (const float*)d_in[14];
    const float* bg     = (const float*)d_in[15];
    const float* wd     = (const float*)d_in[16];
    const float* bd     = (const float*)d_in[17];
    const float* pout_w = (const float*)d_in[18];
    const float* pout_b = (const float*)d_in[19];
    float* out = (float*)d_out;

    // ---- workspace layout (bytes) ----
    char* W = (char*)d_ws;
    u16* tb        = (u16*)W;                                     // t residual, bf16, 16.78 MB
    float* tmp_f32 = (float*)(W + 33554432);                      // 33.55 MB
    u16* qb    = (u16*)(W + 67108864);                            // 16.78 MB (qb,kb,vb contiguous)
    u16* kb    = qb + 8388608;
    u16* vb    = kb + 8388608;
    u16* attnb = vb + 8388608;
    u16* Xb    = attnb + 8388608;                                 // 16.78 MB
    float* stats = (float*)(W + 67108864 + 5ull * 16777216);      // 1 KB
    u16* wbase = (u16*)(W + 67108864 + 5ull * 16777216 + 1024);
    u16* pinB  = wbase;                 // 512*512  (already [N][K])
    u16* poutB = pinB  + 262144;
    u16* wqT   = poutB + 262144;        // [512][512] transposed, scaled by QSCL
    u16* wkT   = wqT   + 262144;        // contiguous with wqT -> [1536][512] for fused qkv
    u16* wvT   = wkT   + 262144;
    u16* woT   = wvT   + 262144;
    u16* wgT   = woT   + 262144;        // [4096][512]
    u16* wdT   = wgT   + 2097152;       // [512][2048]
    u16* ag    = qb;                    // R x 2048 bf16, aliases qb..attnb (dead by then)
    u16* vtb   = (u16*)tmp_f32;         // V^T [b*8+h][64][1024], aliases tmp_f32 (dead until pout)

    dim3 tb8(32, 8);

    // stats + fused weight prep (2 launches)
    gn_stats<<<128, 256, 0, stream>>>(x, stats);
    prep_all<<<4608, tb8, 0, stream>>>(pin_w, pout_w, pinB, poutB,
                                       wq, wk, wv, wo, wqT, wkT, wvT, woT,
                                       wg, wgT, wd, wdT);

    // h = GN(x) transposed -> Xb (bf16)
    gn_apply_t_bf<<<dim3(32, 16, 16), tb8, 0, stream>>>(x, stats, gn_w, gn_b, Xb);

    // t = h @ pin_w^T + pin_b -> tb (bf16)
    mfma_gemm<6><<<dim3(4, 64), 512, 0, stream>>>(Xb, pinB, pin_b, nullptr, tb, 512, 512);
    // tn = ln1(t) -> Xb
    layer_norm_rows_bf<<<16384, 256, 0, stream>>>(tb, ln1_w, ln1_b, Xb);
    // fused q(scaled)/k/v: N=1536, routed to qb/kb/vb
    mfma_gemm<8><<<dim3(12, 64), 512, 0, stream>>>(Xb, wqT, nullptr, nullptr, qb, 512, 1536);
    // per-head V transpose -> vtb
    vtrans<<<dim3(16, 8, 16), 256, 0, stream>>>(vb, vtb);
    // attention (MFMA, QBLK=128, KVBLK=128) -> attnb (bf16)
    flash_attn_mfma<<<dim3(8, 8, 16), 512, 0, stream>>>(qb, kb, vtb, attnb);
    // t += attn @ wo + bo (bf16 in-place on tb)
    mfma_gemm<7><<<dim3(4, 64), 512, 0, stream>>>(attnb, woT, bo, nullptr, tb, 512, 512);
    // tn3 = ln3(t) -> Xb
    layer_norm_rows_bf<<<16384, 256, 0, stream>>>(tb, ln3_w, ln3_b, Xb);
    // ag = a * gelu(g) (bf16), aliases q/k/v/attn space
    geglu_mfma<<<dim3(32, 64), 512, 0, stream>>>(Xb, wgT, bg, ag);
    // t += ag @ wd + bd (bf16 in-place on tb)
    mfma_gemm<7><<<dim3(4, 64), 512, 0, stream>>>(ag, wdT, bd, nullptr, tb, 2048, 512);
    // tmp = t @ pout_w^T + pout_b -> tmp_f32
    mfma_gemm<1><<<dim3(4, 64), 512, 0, stream>>>(tb, poutB, pout_b, tmp_f32, nullptr, 512, 512);
    // out = tmp^T + x
    final_out<<<dim3(32, 16, 16), tb8, 0, stream>>>(tmp_f32, x, out);
}

// Round 26
// 425.178 us; speedup vs baseline: 1.3129x; 1.0322x over previous
//
#include <hip/hip_runtime.h>
#include <hip/hip_bf16.h>
#include <math.h>

typedef unsigned short u16;
typedef __attribute__((ext_vector_type(8))) short bf16x8;
typedef __attribute__((ext_vector_type(4))) float f32x4;

#define Bb 16
#define Cch 512
#define Ss 1024
#define NHh 8
#define DHh 64
#define CPG 64
#define EPSV 1e-5f
#define R_TOTAL (Bb*Ss)   // 16384
#define QSCL 0.18033688011112042f   // 0.125 * log2(e)

__device__ inline u16 f2bf(float f) {
    unsigned int u = __float_as_uint(f);
    unsigned int r = (u + 0x7fffu + ((u >> 16) & 1u)) >> 16;
    return (u16)r;
}
__device__ inline u16 f2bf_rz(float f) { return (u16)(__float_as_uint(f) >> 16); }
__device__ inline float bf2f(u16 v) { return __uint_as_float((unsigned)v << 16); }
__device__ inline float exp2_raw(float x) {
    float r; asm("v_exp_f32 %0, %1" : "=v"(r) : "v"(x)); return r;
}

// swizzles: 16B chunk XOR'd by row&7 within stride-64 rows (proven clean r14-r25).
__device__ inline int swz(int row, int chunk) {      // [R][64] tile
    return row * 64 + ((chunk ^ (row & 7)) * 8);
}
// 128-wide tiles split into two stride-64 halves (chunk bit 3 = half select, wave-uniform)
__device__ inline int psw(int row, int chunk) {      // Ps[128][128]: halves of [128][64]
    return ((chunk >> 3) << 13) + row * 64 + (((chunk & 7) ^ (row & 7)) * 8);
}
__device__ inline int vsw(int row, int chunk) {      // Vt[64][128]: halves of [64][64]
    return ((chunk >> 3) << 12) + row * 64 + (((chunk & 7) ^ (row & 7)) * 8);
}
__device__ inline int swzg(int r, int c) {           // GEMM [R][32] tile
    int span = r >> 1;
    int c8 = ((r & 1) << 2) | c;
    return span * 64 + ((c8 ^ (span & 7)) * 8);
}

// ---------------- GroupNorm stats (float4 loads) ----------------
__global__ __launch_bounds__(256) void gn_stats(const float* __restrict__ x,
                                                float* __restrict__ stats) {
    int bg = blockIdx.x;
    int b = bg >> 3, g = bg & 7;
    const float4* base = (const float4*)(x + ((size_t)b * Cch + (size_t)g * CPG) * Ss);
    float s = 0.f, ss = 0.f;
    for (int i = threadIdx.x; i < CPG * Ss / 4; i += 256) {
        float4 v = base[i];
        s  += v.x + v.y + v.z + v.w;
        ss += v.x * v.x + v.y * v.y + v.z * v.z + v.w * v.w;
    }
    for (int o = 32; o > 0; o >>= 1) { s += __shfl_down(s, o); ss += __shfl_down(ss, o); }
    __shared__ float red[2][4];
    int wid = threadIdx.x >> 6, lane = threadIdx.x & 63;
    if (lane == 0) { red[0][wid] = s; red[1][wid] = ss; }
    __syncthreads();
    if (threadIdx.x == 0) {
        float S1 = red[0][0] + red[0][1] + red[0][2] + red[0][3];
        float S2 = red[1][0] + red[1][1] + red[1][2] + red[1][3];
        const float inv_n = 1.0f / (CPG * Ss);
        float mu = S1 * inv_n;
        float var = S2 * inv_n - mu * mu;
        stats[bg * 2]     = mu;
        stats[bg * 2 + 1] = rsqrtf(var + EPSV);
    }
}

// ---------------- GroupNorm apply + transpose -> bf16 (B,S,C) ----------------
__global__ __launch_bounds__(256) void gn_apply_t_bf(const float* __restrict__ x,
                                                     const float* __restrict__ stats,
                                                     const float* __restrict__ gw,
                                                     const float* __restrict__ gb,
                                                     u16* __restrict__ ht) {
    __shared__ float tile[32][33];
    int b  = blockIdx.z;
    int c0 = blockIdx.y * 32;
    int s0 = blockIdx.x * 32;
    int tx = threadIdx.x, ty = threadIdx.y;
#pragma unroll
    for (int i = 0; i < 4; i++) {
        int c = c0 + ty + i * 8;
        int g = c >> 6;
        float mu = stats[(b * 8 + g) * 2];
        float rs = stats[(b * 8 + g) * 2 + 1];
        float v = x[((size_t)b * Cch + c) * Ss + s0 + tx];
        tile[ty + i * 8][tx] = (v - mu) * rs * gw[c] + gb[c];
    }
    __syncthreads();
#pragma unroll
    for (int i = 0; i < 4; i++) {
        int s = s0 + ty + i * 8;
        ht[((size_t)b * Ss + s) * Cch + c0 + tx] = f2bf(tile[tx][ty + i * 8]);
    }
}

// ---------------- fused weight prep: ALL conversions/transposes in 1 launch ----------
__global__ __launch_bounds__(256) void prep_all(const float* __restrict__ pin_w,
                                                const float* __restrict__ pout_w,
                                                u16* __restrict__ pinB,
                                                u16* __restrict__ poutB,
                                                const float* __restrict__ wq,
                                                const float* __restrict__ wk,
                                                const float* __restrict__ wv,
                                                const float* __restrict__ wo,
                                                u16* __restrict__ wqT,
                                                u16* __restrict__ wkT,
                                                u16* __restrict__ wvT,
                                                u16* __restrict__ woT,
                                                const float* __restrict__ wg,
                                                u16* __restrict__ wgT,
                                                const float* __restrict__ wd,
                                                u16* __restrict__ wdT) {
    __shared__ float tile[32][33];
    int bid = blockIdx.x;
    int tx = threadIdx.x, ty = threadIdx.y;
    int tid = ty * 32 + tx;
    if (bid < 512) {
        int base = bid * 1024 + tid * 4;
        const float* src; u16* dst; int off;
        if (base < 262144) { src = pin_w;  dst = pinB;  off = base; }
        else               { src = pout_w; dst = poutB; off = base - 262144; }
        float4 v = *(const float4*)&src[off];
        ushort4 o;
        o.x = f2bf(v.x); o.y = f2bf(v.y); o.z = f2bf(v.z); o.w = f2bf(v.w);
        *(ushort4*)&dst[off] = o;
        return;
    }
    const float* in; u16* outp; int c0, r0, C, R; float scl = 1.0f;
    if (bid < 1536) {
        int z = (bid - 512) >> 8, rem = (bid - 512) & 255;
        switch (z) {
            case 0: in = wq; outp = wqT; scl = QSCL; break;
            case 1: in = wk; outp = wkT; break;
            case 2: in = wv; outp = wvT; break;
            default: in = wo; outp = woT; break;
        }
        c0 = (rem & 15) * 32; r0 = (rem >> 4) * 32; C = 512; R = 512;
    } else if (bid < 3584) {
        int rem = bid - 1536;
        in = wg; outp = wgT; C = 4096; R = 512;
        c0 = (rem & 127) * 32; r0 = (rem >> 7) * 32;
    } else {
        int rem = bid - 3584;
        in = wd; outp = wdT; C = 512; R = 2048;
        c0 = (rem & 15) * 32; r0 = (rem >> 4) * 32;
    }
#pragma unroll
    for (int i = 0; i < 4; i++)
        tile[ty + i * 8][tx] = in[(size_t)(r0 + ty + i * 8) * C + c0 + tx] * scl;
    __syncthreads();
#pragma unroll
    for (int i = 0; i < 4; i++)
        outp[(size_t)(c0 + ty + i * 8) * R + r0 + tx] = f2bf(tile[tx][ty + i * 8]);
}

// ---------------- per-head V transpose: vb [b][s][512] -> vt [(b*8+h)][64][1024] ----------
__global__ __launch_bounds__(256) void vtrans(const u16* __restrict__ in,
                                              u16* __restrict__ outp) {
    __shared__ u16 tile[64][66];
    int s0 = blockIdx.x * 64, h = blockIdx.y, b = blockIdx.z;
    const u16* src = in + ((size_t)b * Ss + s0) * Cch + h * 64;
    int r = threadIdx.x >> 3, c8 = (threadIdx.x & 7) * 8;
#pragma unroll
    for (int p = 0; p < 2; p++) {
        int rr = r + p * 32;
        *(int4*)&tile[rr][c8] = *(const int4*)&src[(size_t)rr * Cch + c8];
    }
    __syncthreads();
    u16* dst = outp + ((size_t)(b * 8 + h) * 64) * Ss + s0;
#pragma unroll
    for (int p = 0; p < 2; p++) {
        int d = r + p * 32;
        u16 vals[8];
#pragma unroll
        for (int e = 0; e < 8; e++) vals[e] = tile[c8 + e][d];
        *(int4*)&dst[(size_t)d * Ss + c8] = *(int4*)vals;
    }
}

// ---------------- LayerNorm rows (bf16 in, bf16 out) ----------------
__global__ __launch_bounds__(256) void layer_norm_rows_bf(const u16* __restrict__ in,
                                                          const float* __restrict__ w,
                                                          const float* __restrict__ bb,
                                                          u16* __restrict__ outp) {
    int row = blockIdx.x;
    const u16* p = in + (size_t)row * Cch;
    int i0 = threadIdx.x * 2;
    ushort2 u = *(const ushort2*)&p[i0];
    float v0 = bf2f(u.x), v1 = bf2f(u.y);
    float s = v0 + v1, ss = v0 * v0 + v1 * v1;
    for (int o = 32; o > 0; o >>= 1) { s += __shfl_down(s, o); ss += __shfl_down(ss, o); }
    __shared__ float red[2][4];
    __shared__ float mu_s, rs_s;
    int wid = threadIdx.x >> 6, lane = threadIdx.x & 63;
    if (lane == 0) { red[0][wid] = s; red[1][wid] = ss; }
    __syncthreads();
    if (threadIdx.x == 0) {
        float S1 = red[0][0] + red[0][1] + red[0][2] + red[0][3];
        float S2 = red[1][0] + red[1][1] + red[1][2] + red[1][3];
        float mu = S1 * (1.0f / Cch);
        float var = S2 * (1.0f / Cch) - mu * mu;
        mu_s = mu; rs_s = rsqrtf(var + EPSV);
    }
    __syncthreads();
    float mu = mu_s, rs = rs_s;
    outp[(size_t)row * Cch + i0]     = f2bf((v0 - mu) * rs * w[i0] + bb[i0]);
    outp[(size_t)row * Cch + i0 + 1] = f2bf((v1 - mu) * rs * w[i0 + 1] + bb[i0 + 1]);
}

// ---------------- MFMA GEMM: out(MxN) = A(MxK bf16) @ Bt(NxK bf16)^T ----------------
// 256x128 tile, BK=32, 512 thr = 8 waves (4x2). Per-wave 64x64; swizzled LDS (swzg).
// EPI: 0 = bf16; 1 = fp32 +bias; 6 = bf16 +bias; 7 = bf16 +bias + bf16 residual in-place;
//      8 = bf16 routed qkv (outb base = qb; col>>9 selects q/k/v slot, 8388608 apart).
template<int EPI>
__global__ __launch_bounds__(512) void mfma_gemm(const u16* __restrict__ A,
                                                 const u16* __restrict__ Bt,
                                                 const float* __restrict__ bias,
                                                 float* __restrict__ fout,
                                                 u16* __restrict__ outb,
                                                 int K, int N) {
    __shared__ u16 As[256 * 32];
    __shared__ u16 Bs[128 * 32];
    int tid = threadIdx.x;
    int m0 = blockIdx.y * 256, n0 = blockIdx.x * 128;
    int wave = tid >> 6, lane = tid & 63;
    int wr = wave >> 1, wc = wave & 1;      // 4x2 wave grid
    int l15 = lane & 15, l4 = lane >> 4;

    f32x4 zero4 = {0.f, 0.f, 0.f, 0.f};
    f32x4 acc[4][4];
#pragma unroll
    for (int i = 0; i < 4; i++)
#pragma unroll
        for (int j = 0; j < 4; j++) acc[i][j] = zero4;

    int srow = tid >> 1;
    int sc0  = (tid & 1) * 2;
    int se   = sc0 * 8;
    int brow = tid >> 2;
    int bch  = tid & 3;
    int bqe  = bch * 8;

    int4 ra0, ra1, rb0;
    {
        const u16* pa = A  + (size_t)(m0 + srow) * K + se;
        ra0 = *(const int4*)pa; ra1 = *(const int4*)(pa + 8);
        rb0 = *(const int4*)(Bt + (size_t)(n0 + brow) * K + bqe);
    }
    for (int kt = 0; kt < K; kt += 32) {
        __syncthreads();
        *(int4*)&As[swzg(srow, sc0)]     = ra0;
        *(int4*)&As[swzg(srow, sc0 + 1)] = ra1;
        *(int4*)&Bs[swzg(brow, bch)]     = rb0;
        __syncthreads();
        int kn = kt + 32;
        if (kn < K) {
            const u16* pa = A  + (size_t)(m0 + srow) * K + kn + se;
            ra0 = *(const int4*)pa; ra1 = *(const int4*)(pa + 8);
            rb0 = *(const int4*)(Bt + (size_t)(n0 + brow) * K + kn + bqe);
        }
        bf16x8 af[4], bfr[4];
#pragma unroll
        for (int mi = 0; mi < 4; mi++)
            af[mi] = *(const bf16x8*)&As[swzg(wr * 64 + mi * 16 + l15, l4)];
#pragma unroll
        for (int nj = 0; nj < 4; nj++)
            bfr[nj] = *(const bf16x8*)&Bs[swzg(wc * 64 + nj * 16 + l15, l4)];
#pragma unroll
        for (int mi = 0; mi < 4; mi++)
#pragma unroll
            for (int nj = 0; nj < 4; nj++)
                acc[mi][nj] = __builtin_amdgcn_mfma_f32_16x16x32_bf16(af[mi], bfr[nj], acc[mi][nj], 0, 0, 0);
    }

#pragma unroll
    for (int mi = 0; mi < 4; mi++)
#pragma unroll
        for (int nj = 0; nj < 4; nj++)
#pragma unroll
            for (int r = 0; r < 4; r++) {
                int row = m0 + wr * 64 + mi * 16 + l4 * 4 + r;
                int col = n0 + wc * 64 + nj * 16 + l15;
                float v = acc[mi][nj][r];
                if constexpr (EPI == 0) {
                    outb[(size_t)row * N + col] = f2bf(v);
                } else if constexpr (EPI == 1) {
                    fout[(size_t)row * N + col] = v + bias[col];
                } else if constexpr (EPI == 6) {
                    outb[(size_t)row * N + col] = f2bf(v + bias[col]);
                } else if constexpr (EPI == 7) {
                    size_t idx = (size_t)row * N + col;
                    v += bias[col] + bf2f(outb[idx]);
                    outb[idx] = f2bf(v);
                } else if constexpr (EPI == 8) {
                    size_t idx = (size_t)(col >> 9) * 8388608 + (size_t)row * 512 + (col & 511);
                    outb[idx] = f2bf(v);
                }
            }
}

// ---------------- GEGLU MFMA: 256x64(x2 halves) tile, 8 waves, fused exact GELU --------
__global__ __launch_bounds__(512) void geglu_mfma(const u16* __restrict__ A,
                                                  const u16* __restrict__ WgT,  // [4096][512]
                                                  const float* __restrict__ bg,
                                                  u16* __restrict__ ag) {
    __shared__ u16 As[256 * 32];
    __shared__ u16 Bs1[64 * 32];
    __shared__ u16 Bs2[64 * 32];
    const int K = 512;
    int tid = threadIdx.x;
    int m0 = blockIdx.y * 256, n0 = blockIdx.x * 64;
    int wave = tid >> 6, lane = tid & 63;
    int wr = wave >> 1, wc = wave & 1;
    int l15 = lane & 15, l4 = lane >> 4;

    f32x4 zero4 = {0.f, 0.f, 0.f, 0.f};
    f32x4 accA[4][2], accG[4][2];
#pragma unroll
    for (int i = 0; i < 4; i++) { accA[i][0] = zero4; accA[i][1] = zero4; accG[i][0] = zero4; accG[i][1] = zero4; }

    int srow = tid >> 1;
    int sc0  = (tid & 1) * 2;
    int se   = sc0 * 8;
    int bsel = tid >> 8;
    int bt   = tid & 255;
    int brow = bt >> 2;
    int bch  = bt & 3;
    int bqe  = bch * 8;
    const u16* gbp = WgT + (size_t)(bsel * 2048 + n0 + brow) * K + bqe;

    int4 ra0, ra1, rb;
    {
        const u16* pa = A + (size_t)(m0 + srow) * K + se;
        ra0 = *(const int4*)pa; ra1 = *(const int4*)(pa + 8);
        rb = *(const int4*)gbp;
    }
    for (int kt = 0; kt < K; kt += 32) {
        __syncthreads();
        *(int4*)&As[swzg(srow, sc0)]     = ra0;
        *(int4*)&As[swzg(srow, sc0 + 1)] = ra1;
        if (bsel == 0) *(int4*)&Bs1[swzg(brow, bch)] = rb;
        else           *(int4*)&Bs2[swzg(brow, bch)] = rb;
        __syncthreads();
        int kn = kt + 32;
        if (kn < K) {
            const u16* pa = A + (size_t)(m0 + srow) * K + kn + se;
            ra0 = *(const int4*)pa; ra1 = *(const int4*)(pa + 8);
            rb = *(const int4*)(gbp + kn);
        }
        bf16x8 af[4], b1[2], b2[2];
#pragma unroll
        for (int mi = 0; mi < 4; mi++)
            af[mi] = *(const bf16x8*)&As[swzg(wr * 64 + mi * 16 + l15, l4)];
#pragma unroll
        for (int nj = 0; nj < 2; nj++) {
            b1[nj] = *(const bf16x8*)&Bs1[swzg(wc * 32 + nj * 16 + l15, l4)];
            b2[nj] = *(const bf16x8*)&Bs2[swzg(wc * 32 + nj * 16 + l15, l4)];
        }
#pragma unroll
        for (int mi = 0; mi < 4; mi++)
#pragma unroll
            for (int nj = 0; nj < 2; nj++) {
                accA[mi][nj] = __builtin_amdgcn_mfma_f32_16x16x32_bf16(af[mi], b1[nj], accA[mi][nj], 0, 0, 0);
                accG[mi][nj] = __builtin_amdgcn_mfma_f32_16x16x32_bf16(af[mi], b2[nj], accG[mi][nj], 0, 0, 0);
            }
    }

#pragma unroll
    for (int mi = 0; mi < 4; mi++)
#pragma unroll
        for (int nj = 0; nj < 2; nj++)
#pragma unroll
            for (int r = 0; r < 4; r++) {
                int row = m0 + wr * 64 + mi * 16 + l4 * 4 + r;
                int col = n0 + wc * 32 + nj * 16 + l15;
                float a = accA[mi][nj][r] + bg[col];
                float g = accG[mi][nj][r] + bg[2048 + col];
                float ge = 0.5f * g * (1.0f + erff(g * 0.70710678118654752f));
                ag[(size_t)row * 2048 + col] = f2bf(a * ge);
            }
}

// ---------------- MFMA flash attention: QBLK=128, KVBLK=128, reg-prefetched staging ----
// Ps/Vt split into stride-64 halves (psw/vsw); next tile's K/V loads issued BEFORE
// compute (T14: latency hides under QK/softmax/PV). Barrier count unchanged.
__global__ __launch_bounds__(512) void flash_attn_mfma(const u16* __restrict__ q,
                                                       const u16* __restrict__ k,
                                                       const u16* __restrict__ vt,  // [b*8+h][64][1024]
                                                       u16* __restrict__ o) {
    __shared__ u16 Ps[2 * 128 * 64];
    __shared__ u16 Ks[128 * 64];
    __shared__ u16 Vt[2 * 64 * 64];
    const int tid = threadIdx.x;
    const int h = blockIdx.y, b = blockIdx.z;
    const int q0 = blockIdx.x * 128;
    const size_t hb  = (size_t)b * Ss * Cch + (size_t)h * DHh;
    const size_t vhb = ((size_t)(b * NHh + h) * DHh) * Ss;

    const int wq = tid >> 6;               // 0..7: wave owns q-rows wq*16..wq*16+15
    const int lane = tid & 63;
    const int l15 = lane & 15, l4 = lane >> 4;

    // staging thread maps (fixed per thread)
    const int kr = tid >> 2, kc = (tid & 3) * 2;           // K: row, chunk pair
    const int vf = tid >> 8, vtn = tid & 255;              // V: half, thread-in-half
    const int vd = vtn >> 2, vc = (vtn & 3) * 2;           // V: row, chunk pair
    const u16* kbase = k + hb + (size_t)kr * Cch + (size_t)kc * 8;
    const u16* vbase = vt + vhb + (size_t)vd * Ss + vf * 64 + (size_t)vc * 8;

    // stage Q (128x64) into Ps half 0 (chunks 0..7)
    {
        int r = tid >> 2, ch = (tid & 3) * 2;
        const u16* src = q + hb + (size_t)(q0 + r) * Cch;
        *(int4*)&Ps[psw(r, ch)]     = *(const int4*)(src + ch * 8);
        *(int4*)&Ps[psw(r, ch + 1)] = *(const int4*)(src + (ch + 1) * 8);
    }
    __syncthreads();
    bf16x8 aq[2];
    aq[0] = *(const bf16x8*)&Ps[psw(wq * 16 + l15, 0 * 4 + l4)];
    aq[1] = *(const bf16x8*)&Ps[psw(wq * 16 + l15, 1 * 4 + l4)];

    f32x4 zero4 = {0.f, 0.f, 0.f, 0.f};
    f32x4 oacc[4];
    float m_[4], l_[4];
#pragma unroll
    for (int j = 0; j < 4; j++) oacc[j] = zero4;
#pragma unroll
    for (int r = 0; r < 4; r++) { m_[r] = -1e30f; l_[r] = 0.f; }

    // prologue: load tile 0's K/V into registers
    int4 rk0, rk1, rv0, rv1;
    rk0 = *(const int4*)(kbase);
    rk1 = *(const int4*)(kbase + 8);
    rv0 = *(const int4*)(vbase);
    rv1 = *(const int4*)(vbase + 8);

    for (int t0 = 0; t0 < Ss; t0 += 128) {
        __syncthreads();                           // prev tile's LDS reads done
        // write staged regs -> LDS
        *(int4*)&Ks[swz(kr, kc)]     = rk0;
        *(int4*)&Ks[swz(kr, kc + 1)] = rk1;
        *(int4*)&Vt[vsw(vd, vf * 8 + vc)]     = rv0;
        *(int4*)&Vt[vsw(vd, vf * 8 + vc + 1)] = rv1;
        __syncthreads();                           // tile ready
        // issue next tile's loads (fly during compute)
        if (t0 + 128 < Ss) {
            rk0 = *(const int4*)(kbase + (size_t)(t0 + 128) * Cch);
            rk1 = *(const int4*)(kbase + (size_t)(t0 + 128) * Cch + 8);
            rv0 = *(const int4*)(vbase + t0 + 128);
            rv1 = *(const int4*)(vbase + t0 + 128 + 8);
        }

        // QK^T (log2-scaled): wave's 16 q-rows x 128 t-cols
        f32x4 sacc[8];
#pragma unroll
        for (int j = 0; j < 8; j++) sacc[j] = zero4;
#pragma unroll
        for (int ks = 0; ks < 2; ks++) {
#pragma unroll
            for (int j = 0; j < 8; j++) {
                bf16x8 bk = *(const bf16x8*)&Ks[swz(j * 16 + l15, ks * 4 + l4)];
                sacc[j] = __builtin_amdgcn_mfma_f32_16x16x32_bf16(aq[ks], bk, sacc[j], 0, 0, 0);
            }
        }

        float tmv[4];
        int grew = 0;
#pragma unroll
        for (int r = 0; r < 4; r++) {
            float tm = fmaxf(fmaxf(fmaxf(sacc[0][r], sacc[1][r]), fmaxf(sacc[2][r], sacc[3][r])),
                             fmaxf(fmaxf(sacc[4][r], sacc[5][r]), fmaxf(sacc[6][r], sacc[7][r])));
            tm = fmaxf(tm, __shfl_xor(tm, 1));
            tm = fmaxf(tm, __shfl_xor(tm, 2));
            tm = fmaxf(tm, __shfl_xor(tm, 4));
            tm = fmaxf(tm, __shfl_xor(tm, 8));
            tmv[r] = tm;
            grew |= (tm > m_[r]);
        }

        if (__any(grew)) {
#pragma unroll
            for (int r = 0; r < 4; r++) {
                float nm = fmaxf(m_[r], tmv[r]);
                float sc = exp2_raw(m_[r] - nm);
                m_[r] = nm;
                int row = wq * 16 + l4 * 4 + r;
                int rx = row & 7, b64 = row * 64, wi = l15 & 7, hi = l15 >> 3;
                float rs = 0.f;
#pragma unroll
                for (int j = 0; j < 8; j++) {
                    float p = exp2_raw(sacc[j][r] - nm);
                    int cnk = 2 * j + hi;
                    Ps[((cnk >> 3) << 13) + b64 + (((cnk & 7) ^ rx) * 8) + wi] = f2bf_rz(p);
                    rs += p;
                }
                l_[r] = l_[r] * sc + rs;
#pragma unroll
                for (int j = 0; j < 4; j++) oacc[j][r] *= sc;
            }
        } else {
#pragma unroll
            for (int r = 0; r < 4; r++) {
                float nm = m_[r];
                int row = wq * 16 + l4 * 4 + r;
                int rx = row & 7, b64 = row * 64, wi = l15 & 7, hi = l15 >> 3;
                float rs = 0.f;
#pragma unroll
                for (int j = 0; j < 8; j++) {
                    float p = exp2_raw(sacc[j][r] - nm);
                    int cnk = 2 * j + hi;
                    Ps[((cnk >> 3) << 13) + b64 + (((cnk & 7) ^ rx) * 8) + wi] = f2bf_rz(p);
                    rs += p;
                }
                l_[r] += rs;
            }
        }

        // PV: A=Ps (wave-private rows, k=128 -> 4 ks), Bt=Vt[d][t]
#pragma unroll
        for (int ks = 0; ks < 4; ks++) {
            bf16x8 pa = *(const bf16x8*)&Ps[psw(wq * 16 + l15, ks * 4 + l4)];
#pragma unroll
            for (int j = 0; j < 4; j++) {
                bf16x8 bv = *(const bf16x8*)&Vt[vsw(j * 16 + l15, ks * 4 + l4)];
                oacc[j] = __builtin_amdgcn_mfma_f32_16x16x32_bf16(pa, bv, oacc[j], 0, 0, 0);
            }
        }
    }

    // finalize: reduce per-lane l partials, O /= l, stage via Ps half 0, coalesced store
#pragma unroll
    for (int r = 0; r < 4; r++) {
        float lt = l_[r];
        lt += __shfl_xor(lt, 1);
        lt += __shfl_xor(lt, 2);
        lt += __shfl_xor(lt, 4);
        lt += __shfl_xor(lt, 8);
        float inv = 1.0f / lt;
        int row = wq * 16 + l4 * 4 + r;
        int rx = row & 7, b64 = row * 64, wi = l15 & 7, hi = l15 >> 3;
#pragma unroll
        for (int j = 0; j < 4; j++) {
            int cnk = 2 * j + hi;    // 0..7 (half 0)
            Ps[b64 + ((cnk ^ rx) * 8) + wi] = f2bf(oacc[j][r] * inv);
        }
    }
    __syncthreads();
    {
        int r = tid >> 2, ch = (tid & 3) * 2;
        u16* dst = o + hb + (size_t)(q0 + r) * Cch;
        *(int4*)(dst + ch * 8)       = *(const int4*)&Ps[psw(r, ch)];
        *(int4*)(dst + (ch + 1) * 8) = *(const int4*)&Ps[psw(r, ch + 1)];
    }
}

// ---------------- final: out(B,C,S) = tmp(B,S,C)^T + x ----------------
__global__ __launch_bounds__(256) void final_out(const float* __restrict__ tmp,
                                                 const float* __restrict__ x,
                                                 float* __restrict__ outp) {
    __shared__ float tile[32][33];
    int b = blockIdx.z, c0 = blockIdx.y * 32, s0 = blockIdx.x * 32;
    int tx = threadIdx.x, ty = threadIdx.y;
#pragma unroll
    for (int i = 0; i < 4; i++) {
        int s = s0 + ty + i * 8;
        tile[ty + i * 8][tx] = tmp[((size_t)b * Ss + s) * Cch + c0 + tx];
    }
    __syncthreads();
#pragma unroll
    for (int i = 0; i < 4; i++) {
        int c = c0 + ty + i * 8;
        size_t idx = ((size_t)b * Cch + c) * Ss + s0 + tx;
        outp[idx] = tile[tx][ty + i * 8] + x[idx];
    }
}

extern "C" void kernel_launch(void* const* d_in, const int* in_sizes, int n_in,
                              void* d_out, int out_size, void* d_ws, size_t ws_size,
                              hipStream_t stream) {
    (void)in_sizes; (void)n_in; (void)out_size; (void)ws_size;
    const float* x      = (const float*)d_in[0];
    const float* gn_w   = (const float*)d_in[1];
    const float* gn_b   = (const float*)d_in[2];
    const float* pin_w  = (const float*)d_in[3];
    const float* pin_b  = (const float*)d_in[4];
    const float* ln1_w  = (const float*)d_in[5];
    const float* ln1_b  = (const float*)d_in[6];
    const float* wq     = (const float*)d_in[7];
    const float* wk     = (const float*)d_in[8];
    const float* wv     = (const float*)d_in[9];
    const float* wo     = (const float*)d_in[10];
    const float* bo     = (const float*)d_in[11];
    const float* ln3_w  = (const float*)d_in[12];
    const float* ln3_b  = (const float*)d_in[13];
    const float* wg     = (const float*)d_in[14];
    const float* bg     = (const float*)d_in[15];
    const float* wd     = (const float*)d_in[16];
    const float* bd     = (const float*)d_in[17];
    const float* pout_w = (const float*)d_in[18];
    const float* pout_b = (const float*)d_in[19];
    float* out = (float*)d_out;

    // ---- workspace layout (bytes) ----
    char* W = (char*)d_ws;
    u16* tb        = (u16*)W;                                     // t residual, bf16, 16.78 MB
    float* tmp_f32 = (float*)(W + 33554432);                      // 33.55 MB
    u16* qb    = (u16*)(W + 67108864);                            // 16.78 MB (qb,kb,vb contiguous)
    u16* kb    = qb + 8388608;
    u16* vb    = kb + 8388608;
    u16* attnb = vb + 8388608;
    u16* Xb    = attnb + 8388608;                                 // 16.78 MB
    float* stats = (float*)(W + 67108864 + 5ull * 16777216);      // 1 KB
    u16* wbase = (u16*)(W + 67108864 + 5ull * 16777216 + 1024);
    u16* pinB  = wbase;                 // 512*512  (already [N][K])
    u16* poutB = pinB  + 262144;
    u16* wqT   = poutB + 262144;        // [512][512] transposed, scaled by QSCL
    u16* wkT   = wqT   + 262144;        // contiguous with wqT -> [1536][512] for fused qkv
    u16* wvT   = wkT   + 262144;
    u16* woT   = wvT   + 262144;
    u16* wgT   = woT   + 262144;        // [4096][512]
    u16* wdT   = wgT   + 2097152;       // [512][2048]
    u16* ag    = qb;                    // R x 2048 bf16, aliases qb..attnb (dead by then)
    u16* vtb   = (u16*)tmp_f32;         // V^T [b*8+h][64][1024], aliases tmp_f32 (dead until pout)

    dim3 tb8(32, 8);

    // stats + fused weight prep (2 launches)
    gn_stats<<<128, 256, 0, stream>>>(x, stats);
    prep_all<<<4608, tb8, 0, stream>>>(pin_w, pout_w, pinB, poutB,
                                       wq, wk, wv, wo, wqT, wkT, wvT, woT,
                                       wg, wgT, wd, wdT);

    // h = GN(x) transposed -> Xb (bf16)
    gn_apply_t_bf<<<dim3(32, 16, 16), tb8, 0, stream>>>(x, stats, gn_w, gn_b, Xb);

    // t = h @ pin_w^T + pin_b -> tb (bf16)
    mfma_gemm<6><<<dim3(4, 64), 512, 0, stream>>>(Xb, pinB, pin_b, nullptr, tb, 512, 512);
    // tn = ln1(t) -> Xb
    layer_norm_rows_bf<<<16384, 256, 0, stream>>>(tb, ln1_w, ln1_b, Xb);
    // fused q(scaled)/k/v: N=1536, routed to qb/kb/vb
    mfma_gemm<8><<<dim3(12, 64), 512, 0, stream>>>(Xb, wqT, nullptr, nullptr, qb, 512, 1536);
    // per-head V transpose -> vtb
    vtrans<<<dim3(16, 8, 16), 256, 0, stream>>>(vb, vtb);
    // attention (MFMA, QBLK=128, KVBLK=128, prefetched) -> attnb (bf16)
    flash_attn_mfma<<<dim3(8, 8, 16), 512, 0, stream>>>(qb, kb, vtb, attnb);
    // t += attn @ wo + bo (bf16 in-place on tb)
    mfma_gemm<7><<<dim3(4, 64), 512, 0, stream>>>(attnb, woT, bo, nullptr, tb, 512, 512);
    // tn3 = ln3(t) -> Xb
    layer_norm_rows_bf<<<16384, 256, 0, stream>>>(tb, ln3_w, ln3_b, Xb);
    // ag = a * gelu(g) (bf16), aliases q/k/v/attn space
    geglu_mfma<<<dim3(32, 64), 512, 0, stream>>>(Xb, wgT, bg, ag);
    // t += ag @ wd + bd (bf16 in-place on tb)
    mfma_gemm<7><<<dim3(4, 64), 512, 0, stream>>>(ag, wdT, bd, nullptr, tb, 2048, 512);
    // tmp = t @ pout_w^T + pout_b -> tmp_f32
    mfma_gemm<1><<<dim3(4, 64), 512, 0, stream>>>(tb, poutB, pout_b, tmp_f32, nullptr, 512, 512);
    // out = tmp^T + x
    final_out<<<dim3(32, 16, 16), tb8, 0, stream>>>(tmp_f32, x, out);
}

// Round 27
// 421.983 us; speedup vs baseline: 1.3229x; 1.0076x over previous
//
#include <hip/hip_runtime.h>
#include <hip/hip_bf16.h>
#include <math.h>

typedef unsigned short u16;
typedef __attribute__((ext_vector_type(8))) short bf16x8;
typedef __attribute__((ext_vector_type(4))) float f32x4;

#define Bb 16
#define Cch 512
#define Ss 1024
#define NHh 8
#define DHh 64
#define CPG 64
#define EPSV 1e-5f
#define R_TOTAL (Bb*Ss)   // 16384
#define QSCL 0.18033688011112042f   // 0.125 * log2(e)

__device__ inline u16 f2bf(float f) {
    unsigned int u = __float_as_uint(f);
    unsigned int r = (u + 0x7fffu + ((u >> 16) & 1u)) >> 16;
    return (u16)r;
}
__device__ inline u16 f2bf_rz(float f) { return (u16)(__float_as_uint(f) >> 16); }
__device__ inline float bf2f(u16 v) { return __uint_as_float((unsigned)v << 16); }
__device__ inline float exp2_raw(float x) {
    float r; asm("v_exp_f32 %0, %1" : "=v"(r) : "v"(x)); return r;
}
__device__ inline float rcp_raw(float x) {
    float r; asm("v_rcp_f32 %0, %1" : "=v"(r) : "v"(x)); return r;
}
// branchless exact-GELU via Abramowitz-Stegun 7.1.26 erf (max err 1.5e-7)
__device__ inline float gelu_f(float g) {
    float z = fabsf(g) * 0.70710678118654752f;
    float t = rcp_raw(1.0f + 0.3275911f * z);
    float poly = t * (0.254829592f + t * (-0.284496736f + t * (1.421413741f +
                 t * (-1.453152027f + t * 1.061405429f))));
    float e = exp2_raw(-z * z * 1.44269504089f);
    float erfa = 1.0f - poly * e;
    float erfv = (g < 0.f) ? -erfa : erfa;
    return 0.5f * g * (1.0f + erfv);
}

// swizzles: 16B chunk XOR'd by row&7 within stride-64 rows (proven clean r14-r25).
__device__ inline int swz(int row, int chunk) {      // [R][64] tile
    return row * 64 + ((chunk ^ (row & 7)) * 8);
}
// 128-wide tiles split into two stride-64 halves (chunk bit 3 = half select, wave-uniform)
__device__ inline int psw(int row, int chunk) {      // Ps[128][128]: halves of [128][64]
    return ((chunk >> 3) << 13) + row * 64 + (((chunk & 7) ^ (row & 7)) * 8);
}
__device__ inline int vsw(int row, int chunk) {      // Vt[64][128]: halves of [64][64]
    return ((chunk >> 3) << 12) + row * 64 + (((chunk & 7) ^ (row & 7)) * 8);
}
__device__ inline int swzg(int r, int c) {           // GEMM [R][32] tile
    int span = r >> 1;
    int c8 = ((r & 1) << 2) | c;
    return span * 64 + ((c8 ^ (span & 7)) * 8);
}

// ---------------- GroupNorm stats (float4 loads) ----------------
__global__ __launch_bounds__(256) void gn_stats(const float* __restrict__ x,
                                                float* __restrict__ stats) {
    int bg = blockIdx.x;
    int b = bg >> 3, g = bg & 7;
    const float4* base = (const float4*)(x + ((size_t)b * Cch + (size_t)g * CPG) * Ss);
    float s = 0.f, ss = 0.f;
    for (int i = threadIdx.x; i < CPG * Ss / 4; i += 256) {
        float4 v = base[i];
        s  += v.x + v.y + v.z + v.w;
        ss += v.x * v.x + v.y * v.y + v.z * v.z + v.w * v.w;
    }
    for (int o = 32; o > 0; o >>= 1) { s += __shfl_down(s, o); ss += __shfl_down(ss, o); }
    __shared__ float red[2][4];
    int wid = threadIdx.x >> 6, lane = threadIdx.x & 63;
    if (lane == 0) { red[0][wid] = s; red[1][wid] = ss; }
    __syncthreads();
    if (threadIdx.x == 0) {
        float S1 = red[0][0] + red[0][1] + red[0][2] + red[0][3];
        float S2 = red[1][0] + red[1][1] + red[1][2] + red[1][3];
        const float inv_n = 1.0f / (CPG * Ss);
        float mu = S1 * inv_n;
        float var = S2 * inv_n - mu * mu;
        stats[bg * 2]     = mu;
        stats[bg * 2 + 1] = rsqrtf(var + EPSV);
    }
}

// ---------------- GroupNorm apply + transpose -> bf16 (B,S,C) ----------------
__global__ __launch_bounds__(256) void gn_apply_t_bf(const float* __restrict__ x,
                                                     const float* __restrict__ stats,
                                                     const float* __restrict__ gw,
                                                     const float* __restrict__ gb,
                                                     u16* __restrict__ ht) {
    __shared__ float tile[32][33];
    int b  = blockIdx.z;
    int c0 = blockIdx.y * 32;
    int s0 = blockIdx.x * 32;
    int tx = threadIdx.x, ty = threadIdx.y;
#pragma unroll
    for (int i = 0; i < 4; i++) {
        int c = c0 + ty + i * 8;
        int g = c >> 6;
        float mu = stats[(b * 8 + g) * 2];
        float rs = stats[(b * 8 + g) * 2 + 1];
        float v = x[((size_t)b * Cch + c) * Ss + s0 + tx];
        tile[ty + i * 8][tx] = (v - mu) * rs * gw[c] + gb[c];
    }
    __syncthreads();
#pragma unroll
    for (int i = 0; i < 4; i++) {
        int s = s0 + ty + i * 8;
        ht[((size_t)b * Ss + s) * Cch + c0 + tx] = f2bf(tile[tx][ty + i * 8]);
    }
}

// ---------------- fused weight prep: ALL conversions/transposes in 1 launch ----------
__global__ __launch_bounds__(256) void prep_all(const float* __restrict__ pin_w,
                                                const float* __restrict__ pout_w,
                                                u16* __restrict__ pinB,
                                                u16* __restrict__ poutB,
                                                const float* __restrict__ wq,
                                                const float* __restrict__ wk,
                                                const float* __restrict__ wv,
                                                const float* __restrict__ wo,
                                                u16* __restrict__ wqT,
                                                u16* __restrict__ wkT,
                                                u16* __restrict__ wvT,
                                                u16* __restrict__ woT,
                                                const float* __restrict__ wg,
                                                u16* __restrict__ wgT,
                                                const float* __restrict__ wd,
                                                u16* __restrict__ wdT) {
    __shared__ float tile[32][33];
    int bid = blockIdx.x;
    int tx = threadIdx.x, ty = threadIdx.y;
    int tid = ty * 32 + tx;
    if (bid < 512) {
        int base = bid * 1024 + tid * 4;
        const float* src; u16* dst; int off;
        if (base < 262144) { src = pin_w;  dst = pinB;  off = base; }
        else               { src = pout_w; dst = poutB; off = base - 262144; }
        float4 v = *(const float4*)&src[off];
        ushort4 o;
        o.x = f2bf(v.x); o.y = f2bf(v.y); o.z = f2bf(v.z); o.w = f2bf(v.w);
        *(ushort4*)&dst[off] = o;
        return;
    }
    const float* in; u16* outp; int c0, r0, C, R; float scl = 1.0f;
    if (bid < 1536) {
        int z = (bid - 512) >> 8, rem = (bid - 512) & 255;
        switch (z) {
            case 0: in = wq; outp = wqT; scl = QSCL; break;
            case 1: in = wk; outp = wkT; break;
            case 2: in = wv; outp = wvT; break;
            default: in = wo; outp = woT; break;
        }
        c0 = (rem & 15) * 32; r0 = (rem >> 4) * 32; C = 512; R = 512;
    } else if (bid < 3584) {
        int rem = bid - 1536;
        in = wg; outp = wgT; C = 4096; R = 512;
        c0 = (rem & 127) * 32; r0 = (rem >> 7) * 32;
    } else {
        int rem = bid - 3584;
        in = wd; outp = wdT; C = 512; R = 2048;
        c0 = (rem & 15) * 32; r0 = (rem >> 4) * 32;
    }
#pragma unroll
    for (int i = 0; i < 4; i++)
        tile[ty + i * 8][tx] = in[(size_t)(r0 + ty + i * 8) * C + c0 + tx] * scl;
    __syncthreads();
#pragma unroll
    for (int i = 0; i < 4; i++)
        outp[(size_t)(c0 + ty + i * 8) * R + r0 + tx] = f2bf(tile[tx][ty + i * 8]);
}

// ---------------- per-head V transpose: vb [b][s][512] -> vt [(b*8+h)][64][1024] ----------
__global__ __launch_bounds__(256) void vtrans(const u16* __restrict__ in,
                                              u16* __restrict__ outp) {
    __shared__ u16 tile[64][66];
    int s0 = blockIdx.x * 64, h = blockIdx.y, b = blockIdx.z;
    const u16* src = in + ((size_t)b * Ss + s0) * Cch + h * 64;
    int r = threadIdx.x >> 3, c8 = (threadIdx.x & 7) * 8;
#pragma unroll
    for (int p = 0; p < 2; p++) {
        int rr = r + p * 32;
        *(int4*)&tile[rr][c8] = *(const int4*)&src[(size_t)rr * Cch + c8];
    }
    __syncthreads();
    u16* dst = outp + ((size_t)(b * 8 + h) * 64) * Ss + s0;
#pragma unroll
    for (int p = 0; p < 2; p++) {
        int d = r + p * 32;
        u16 vals[8];
#pragma unroll
        for (int e = 0; e < 8; e++) vals[e] = tile[c8 + e][d];
        *(int4*)&dst[(size_t)d * Ss + c8] = *(int4*)vals;
    }
}

// ---------------- LayerNorm rows (bf16 in, bf16 out) ----------------
__global__ __launch_bounds__(256) void layer_norm_rows_bf(const u16* __restrict__ in,
                                                          const float* __restrict__ w,
                                                          const float* __restrict__ bb,
                                                          u16* __restrict__ outp) {
    int row = blockIdx.x;
    const u16* p = in + (size_t)row * Cch;
    int i0 = threadIdx.x * 2;
    ushort2 u = *(const ushort2*)&p[i0];
    float v0 = bf2f(u.x), v1 = bf2f(u.y);
    float s = v0 + v1, ss = v0 * v0 + v1 * v1;
    for (int o = 32; o > 0; o >>= 1) { s += __shfl_down(s, o); ss += __shfl_down(ss, o); }
    __shared__ float red[2][4];
    __shared__ float mu_s, rs_s;
    int wid = threadIdx.x >> 6, lane = threadIdx.x & 63;
    if (lane == 0) { red[0][wid] = s; red[1][wid] = ss; }
    __syncthreads();
    if (threadIdx.x == 0) {
        float S1 = red[0][0] + red[0][1] + red[0][2] + red[0][3];
        float S2 = red[1][0] + red[1][1] + red[1][2] + red[1][3];
        float mu = S1 * (1.0f / Cch);
        float var = S2 * (1.0f / Cch) - mu * mu;
        mu_s = mu; rs_s = rsqrtf(var + EPSV);
    }
    __syncthreads();
    float mu = mu_s, rs = rs_s;
    outp[(size_t)row * Cch + i0]     = f2bf((v0 - mu) * rs * w[i0] + bb[i0]);
    outp[(size_t)row * Cch + i0 + 1] = f2bf((v1 - mu) * rs * w[i0 + 1] + bb[i0 + 1]);
}

// ---------------- MFMA GEMM: out(MxN) = A(MxK bf16) @ Bt(NxK bf16)^T ----------------
// 256x128 tile, BK=32, 512 thr = 8 waves (4x2). Per-wave 64x64; swizzled LDS (swzg).
// EPI: 0 = bf16; 1 = fp32 +bias; 6 = bf16 +bias; 7 = bf16 +bias + bf16 residual in-place;
//      8 = bf16 routed qkv (outb base = qb; col>>9 selects q/k/v slot, 8388608 apart).
template<int EPI>
__global__ __launch_bounds__(512) void mfma_gemm(const u16* __restrict__ A,
                                                 const u16* __restrict__ Bt,
                                                 const float* __restrict__ bias,
                                                 float* __restrict__ fout,
                                                 u16* __restrict__ outb,
                                                 int K, int N) {
    __shared__ u16 As[256 * 32];
    __shared__ u16 Bs[128 * 32];
    int tid = threadIdx.x;
    int m0 = blockIdx.y * 256, n0 = blockIdx.x * 128;
    int wave = tid >> 6, lane = tid & 63;
    int wr = wave >> 1, wc = wave & 1;      // 4x2 wave grid
    int l15 = lane & 15, l4 = lane >> 4;

    f32x4 zero4 = {0.f, 0.f, 0.f, 0.f};
    f32x4 acc[4][4];
#pragma unroll
    for (int i = 0; i < 4; i++)
#pragma unroll
        for (int j = 0; j < 4; j++) acc[i][j] = zero4;

    int srow = tid >> 1;
    int sc0  = (tid & 1) * 2;
    int se   = sc0 * 8;
    int brow = tid >> 2;
    int bch  = tid & 3;
    int bqe  = bch * 8;

    int4 ra0, ra1, rb0;
    {
        const u16* pa = A  + (size_t)(m0 + srow) * K + se;
        ra0 = *(const int4*)pa; ra1 = *(const int4*)(pa + 8);
        rb0 = *(const int4*)(Bt + (size_t)(n0 + brow) * K + bqe);
    }
    for (int kt = 0; kt < K; kt += 32) {
        __syncthreads();
        *(int4*)&As[swzg(srow, sc0)]     = ra0;
        *(int4*)&As[swzg(srow, sc0 + 1)] = ra1;
        *(int4*)&Bs[swzg(brow, bch)]     = rb0;
        __syncthreads();
        int kn = kt + 32;
        if (kn < K) {
            const u16* pa = A  + (size_t)(m0 + srow) * K + kn + se;
            ra0 = *(const int4*)pa; ra1 = *(const int4*)(pa + 8);
            rb0 = *(const int4*)(Bt + (size_t)(n0 + brow) * K + kn + bqe);
        }
        bf16x8 af[4], bfr[4];
#pragma unroll
        for (int mi = 0; mi < 4; mi++)
            af[mi] = *(const bf16x8*)&As[swzg(wr * 64 + mi * 16 + l15, l4)];
#pragma unroll
        for (int nj = 0; nj < 4; nj++)
            bfr[nj] = *(const bf16x8*)&Bs[swzg(wc * 64 + nj * 16 + l15, l4)];
#pragma unroll
        for (int mi = 0; mi < 4; mi++)
#pragma unroll
            for (int nj = 0; nj < 4; nj++)
                acc[mi][nj] = __builtin_amdgcn_mfma_f32_16x16x32_bf16(af[mi], bfr[nj], acc[mi][nj], 0, 0, 0);
    }

#pragma unroll
    for (int mi = 0; mi < 4; mi++)
#pragma unroll
        for (int nj = 0; nj < 4; nj++)
#pragma unroll
            for (int r = 0; r < 4; r++) {
                int row = m0 + wr * 64 + mi * 16 + l4 * 4 + r;
                int col = n0 + wc * 64 + nj * 16 + l15;
                float v = acc[mi][nj][r];
                if constexpr (EPI == 0) {
                    outb[(size_t)row * N + col] = f2bf(v);
                } else if constexpr (EPI == 1) {
                    fout[(size_t)row * N + col] = v + bias[col];
                } else if constexpr (EPI == 6) {
                    outb[(size_t)row * N + col] = f2bf(v + bias[col]);
                } else if constexpr (EPI == 7) {
                    size_t idx = (size_t)row * N + col;
                    v += bias[col] + bf2f(outb[idx]);
                    outb[idx] = f2bf(v);
                } else if constexpr (EPI == 8) {
                    size_t idx = (size_t)(col >> 9) * 8388608 + (size_t)row * 512 + (col & 511);
                    outb[idx] = f2bf(v);
                }
            }
}

// ---------------- GEGLU MFMA: 256x64(x2 halves) tile, 8 waves, fused exact GELU --------
__global__ __launch_bounds__(512) void geglu_mfma(const u16* __restrict__ A,
                                                  const u16* __restrict__ WgT,  // [4096][512]
                                                  const float* __restrict__ bg,
                                                  u16* __restrict__ ag) {
    __shared__ u16 As[256 * 32];
    __shared__ u16 Bs1[64 * 32];
    __shared__ u16 Bs2[64 * 32];
    const int K = 512;
    int tid = threadIdx.x;
    int m0 = blockIdx.y * 256, n0 = blockIdx.x * 64;
    int wave = tid >> 6, lane = tid & 63;
    int wr = wave >> 1, wc = wave & 1;
    int l15 = lane & 15, l4 = lane >> 4;

    f32x4 zero4 = {0.f, 0.f, 0.f, 0.f};
    f32x4 accA[4][2], accG[4][2];
#pragma unroll
    for (int i = 0; i < 4; i++) { accA[i][0] = zero4; accA[i][1] = zero4; accG[i][0] = zero4; accG[i][1] = zero4; }

    int srow = tid >> 1;
    int sc0  = (tid & 1) * 2;
    int se   = sc0 * 8;
    int bsel = tid >> 8;
    int bt   = tid & 255;
    int brow = bt >> 2;
    int bch  = bt & 3;
    int bqe  = bch * 8;
    const u16* gbp = WgT + (size_t)(bsel * 2048 + n0 + brow) * K + bqe;

    int4 ra0, ra1, rb;
    {
        const u16* pa = A + (size_t)(m0 + srow) * K + se;
        ra0 = *(const int4*)pa; ra1 = *(const int4*)(pa + 8);
        rb = *(const int4*)gbp;
    }
    for (int kt = 0; kt < K; kt += 32) {
        __syncthreads();
        *(int4*)&As[swzg(srow, sc0)]     = ra0;
        *(int4*)&As[swzg(srow, sc0 + 1)] = ra1;
        if (bsel == 0) *(int4*)&Bs1[swzg(brow, bch)] = rb;
        else           *(int4*)&Bs2[swzg(brow, bch)] = rb;
        __syncthreads();
        int kn = kt + 32;
        if (kn < K) {
            const u16* pa = A + (size_t)(m0 + srow) * K + kn + se;
            ra0 = *(const int4*)pa; ra1 = *(const int4*)(pa + 8);
            rb = *(const int4*)(gbp + kn);
        }
        bf16x8 af[4], b1[2], b2[2];
#pragma unroll
        for (int mi = 0; mi < 4; mi++)
            af[mi] = *(const bf16x8*)&As[swzg(wr * 64 + mi * 16 + l15, l4)];
#pragma unroll
        for (int nj = 0; nj < 2; nj++) {
            b1[nj] = *(const bf16x8*)&Bs1[swzg(wc * 32 + nj * 16 + l15, l4)];
            b2[nj] = *(const bf16x8*)&Bs2[swzg(wc * 32 + nj * 16 + l15, l4)];
        }
#pragma unroll
        for (int mi = 0; mi < 4; mi++)
#pragma unroll
            for (int nj = 0; nj < 2; nj++) {
                accA[mi][nj] = __builtin_amdgcn_mfma_f32_16x16x32_bf16(af[mi], b1[nj], accA[mi][nj], 0, 0, 0);
                accG[mi][nj] = __builtin_amdgcn_mfma_f32_16x16x32_bf16(af[mi], b2[nj], accG[mi][nj], 0, 0, 0);
            }
    }

#pragma unroll
    for (int mi = 0; mi < 4; mi++)
#pragma unroll
        for (int nj = 0; nj < 2; nj++)
#pragma unroll
            for (int r = 0; r < 4; r++) {
                int row = m0 + wr * 64 + mi * 16 + l4 * 4 + r;
                int col = n0 + wc * 32 + nj * 16 + l15;
                float a = accA[mi][nj][r] + bg[col];
                float g = accG[mi][nj][r] + bg[2048 + col];
                ag[(size_t)row * 2048 + col] = f2bf(a * gelu_f(g));
            }
}

// ---------------- MFMA flash attention: QBLK=128, KVBLK=128, reg-prefetched staging ----
// Grid roles: x = h (fastest), y = q-block -> blocks sharing K/V land 8 apart in
// linear id = same XCD under round-robin (L2 reuse). Ps/Vt stride-64 halves.
__global__ __launch_bounds__(512) void flash_attn_mfma(const u16* __restrict__ q,
                                                       const u16* __restrict__ k,
                                                       const u16* __restrict__ vt,  // [b*8+h][64][1024]
                                                       u16* __restrict__ o) {
    __shared__ u16 Ps[2 * 128 * 64];
    __shared__ u16 Ks[128 * 64];
    __shared__ u16 Vt[2 * 64 * 64];
    const int tid = threadIdx.x;
    const int h = blockIdx.x, b = blockIdx.z;
    const int q0 = blockIdx.y * 128;
    const size_t hb  = (size_t)b * Ss * Cch + (size_t)h * DHh;
    const size_t vhb = ((size_t)(b * NHh + h) * DHh) * Ss;

    const int wq = tid >> 6;               // 0..7: wave owns q-rows wq*16..wq*16+15
    const int lane = tid & 63;
    const int l15 = lane & 15, l4 = lane >> 4;

    // staging thread maps (fixed per thread)
    const int kr = tid >> 2, kc = (tid & 3) * 2;           // K: row, chunk pair
    const int vf = tid >> 8, vtn = tid & 255;              // V: half, thread-in-half
    const int vd = vtn >> 2, vc = (vtn & 3) * 2;           // V: row, chunk pair
    const u16* kbase = k + hb + (size_t)kr * Cch + (size_t)kc * 8;
    const u16* vbase = vt + vhb + (size_t)vd * Ss + vf * 64 + (size_t)vc * 8;

    // stage Q (128x64) into Ps half 0 (chunks 0..7)
    {
        int r = tid >> 2, ch = (tid & 3) * 2;
        const u16* src = q + hb + (size_t)(q0 + r) * Cch;
        *(int4*)&Ps[psw(r, ch)]     = *(const int4*)(src + ch * 8);
        *(int4*)&Ps[psw(r, ch + 1)] = *(const int4*)(src + (ch + 1) * 8);
    }
    __syncthreads();
    bf16x8 aq[2];
    aq[0] = *(const bf16x8*)&Ps[psw(wq * 16 + l15, 0 * 4 + l4)];
    aq[1] = *(const bf16x8*)&Ps[psw(wq * 16 + l15, 1 * 4 + l4)];

    f32x4 zero4 = {0.f, 0.f, 0.f, 0.f};
    f32x4 oacc[4];
    float m_[4], l_[4];
#pragma unroll
    for (int j = 0; j < 4; j++) oacc[j] = zero4;
#pragma unroll
    for (int r = 0; r < 4; r++) { m_[r] = -1e30f; l_[r] = 0.f; }

    // prologue: load tile 0's K/V into registers
    int4 rk0, rk1, rv0, rv1;
    rk0 = *(const int4*)(kbase);
    rk1 = *(const int4*)(kbase + 8);
    rv0 = *(const int4*)(vbase);
    rv1 = *(const int4*)(vbase + 8);

    for (int t0 = 0; t0 < Ss; t0 += 128) {
        __syncthreads();                           // prev tile's LDS reads done
        *(int4*)&Ks[swz(kr, kc)]     = rk0;
        *(int4*)&Ks[swz(kr, kc + 1)] = rk1;
        *(int4*)&Vt[vsw(vd, vf * 8 + vc)]     = rv0;
        *(int4*)&Vt[vsw(vd, vf * 8 + vc + 1)] = rv1;
        __syncthreads();                           // tile ready
        if (t0 + 128 < Ss) {
            rk0 = *(const int4*)(kbase + (size_t)(t0 + 128) * Cch);
            rk1 = *(const int4*)(kbase + (size_t)(t0 + 128) * Cch + 8);
            rv0 = *(const int4*)(vbase + t0 + 128);
            rv1 = *(const int4*)(vbase + t0 + 128 + 8);
        }

        // QK^T (log2-scaled): wave's 16 q-rows x 128 t-cols
        f32x4 sacc[8];
#pragma unroll
        for (int j = 0; j < 8; j++) sacc[j] = zero4;
#pragma unroll
        for (int ks = 0; ks < 2; ks++) {
#pragma unroll
            for (int j = 0; j < 8; j++) {
                bf16x8 bk = *(const bf16x8*)&Ks[swz(j * 16 + l15, ks * 4 + l4)];
                sacc[j] = __builtin_amdgcn_mfma_f32_16x16x32_bf16(aq[ks], bk, sacc[j], 0, 0, 0);
            }
        }

        float tmv[4];
        int grew = 0;
#pragma unroll
        for (int r = 0; r < 4; r++) {
            float tm = fmaxf(fmaxf(fmaxf(sacc[0][r], sacc[1][r]), fmaxf(sacc[2][r], sacc[3][r])),
                             fmaxf(fmaxf(sacc[4][r], sacc[5][r]), fmaxf(sacc[6][r], sacc[7][r])));
            tm = fmaxf(tm, __shfl_xor(tm, 1));
            tm = fmaxf(tm, __shfl_xor(tm, 2));
            tm = fmaxf(tm, __shfl_xor(tm, 4));
            tm = fmaxf(tm, __shfl_xor(tm, 8));
            tmv[r] = tm;
            grew |= (tm > m_[r]);
        }

        if (__any(grew)) {
#pragma unroll
            for (int r = 0; r < 4; r++) {
                float nm = fmaxf(m_[r], tmv[r]);
                float sc = exp2_raw(m_[r] - nm);
                m_[r] = nm;
                int row = wq * 16 + l4 * 4 + r;
                int rx = row & 7, b64 = row * 64, wi = l15 & 7, hi = l15 >> 3;
                float rs = 0.f;
#pragma unroll
                for (int j = 0; j < 8; j++) {
                    float p = exp2_raw(sacc[j][r] - nm);
                    int cnk = 2 * j + hi;
                    Ps[((cnk >> 3) << 13) + b64 + (((cnk & 7) ^ rx) * 8) + wi] = f2bf_rz(p);
                    rs += p;
                }
                l_[r] = l_[r] * sc + rs;
#pragma unroll
                for (int j = 0; j < 4; j++) oacc[j][r] *= sc;
            }
        } else {
#pragma unroll
            for (int r = 0; r < 4; r++) {
                float nm = m_[r];
                int row = wq * 16 + l4 * 4 + r;
                int rx = row & 7, b64 = row * 64, wi = l15 & 7, hi = l15 >> 3;
                float rs = 0.f;
#pragma unroll
                for (int j = 0; j < 8; j++) {
                    float p = exp2_raw(sacc[j][r] - nm);
                    int cnk = 2 * j + hi;
                    Ps[((cnk >> 3) << 13) + b64 + (((cnk & 7) ^ rx) * 8) + wi] = f2bf_rz(p);
                    rs += p;
                }
                l_[r] += rs;
            }
        }

        // PV: A=Ps (wave-private rows, k=128 -> 4 ks), Bt=Vt[d][t]
#pragma unroll
        for (int ks = 0; ks < 4; ks++) {
            bf16x8 pa = *(const bf16x8*)&Ps[psw(wq * 16 + l15, ks * 4 + l4)];
#pragma unroll
            for (int j = 0; j < 4; j++) {
                bf16x8 bv = *(const bf16x8*)&Vt[vsw(j * 16 + l15, ks * 4 + l4)];
                oacc[j] = __builtin_amdgcn_mfma_f32_16x16x32_bf16(pa, bv, oacc[j], 0, 0, 0);
            }
        }
    }

    // finalize: reduce per-lane l partials, O /= l, stage via Ps half 0, coalesced store
#pragma unroll
    for (int r = 0; r < 4; r++) {
        float lt = l_[r];
        lt += __shfl_xor(lt, 1);
        lt += __shfl_xor(lt, 2);
        lt += __shfl_xor(lt, 4);
        lt += __shfl_xor(lt, 8);
        float inv = 1.0f / lt;
        int row = wq * 16 + l4 * 4 + r;
        int rx = row & 7, b64 = row * 64, wi = l15 & 7, hi = l15 >> 3;
#pragma unroll
        for (int j = 0; j < 4; j++) {
            int cnk = 2 * j + hi;    // 0..7 (half 0)
            Ps[b64 + ((cnk ^ rx) * 8) + wi] = f2bf(oacc[j][r] * inv);
        }
    }
    __syncthreads();
    {
        int r = tid >> 2, ch = (tid & 3) * 2;
        u16* dst = o + hb + (size_t)(q0 + r) * Cch;
        *(int4*)(dst + ch * 8)       = *(const int4*)&Ps[psw(r, ch)];
        *(int4*)(dst + (ch + 1) * 8) = *(const int4*)&Ps[psw(r, ch + 1)];
    }
}

// ---------------- final: out(B,C,S) = tmp(B,S,C bf16)^T + x ----------------
__global__ __launch_bounds__(256) void final_out_bf(const u16* __restrict__ tmp,
                                                    const float* __restrict__ x,
                                                    float* __restrict__ outp) {
    __shared__ float tile[32][33];
    int b = blockIdx.z, c0 = blockIdx.y * 32, s0 = blockIdx.x * 32;
    int tx = threadIdx.x, ty = threadIdx.y;
#pragma unroll
    for (int i = 0; i < 4; i++) {
        int s = s0 + ty + i * 8;
        tile[ty + i * 8][tx] = bf2f(tmp[((size_t)b * Ss + s) * Cch + c0 + tx]);
    }
    __syncthreads();
#pragma unroll
    for (int i = 0; i < 4; i++) {
        int c = c0 + ty + i * 8;
        size_t idx = ((size_t)b * Cch + c) * Ss + s0 + tx;
        outp[idx] = tile[tx][ty + i * 8] + x[idx];
    }
}

extern "C" void kernel_launch(void* const* d_in, const int* in_sizes, int n_in,
                              void* d_out, int out_size, void* d_ws, size_t ws_size,
                              hipStream_t stream) {
    (void)in_sizes; (void)n_in; (void)out_size; (void)ws_size;
    const float* x      = (const float*)d_in[0];
    const float* gn_w   = (const float*)d_in[1];
    const float* gn_b   = (const float*)d_in[2];
    const float* pin_w  = (const float*)d_in[3];
    const float* pin_b  = (const float*)d_in[4];
    const float* ln1_w  = (const float*)d_in[5];
    const float* ln1_b  = (const float*)d_in[6];
    const float* wq     = (const float*)d_in[7];
    const float* wk     = (const float*)d_in[8];
    const float* wv     = (const float*)d_in[9];
    const float* wo     = (const float*)d_in[10];
    const float* bo     = (const float*)d_in[11];
    const float* ln3_w  = (const float*)d_in[12];
    const float* ln3_b  = (const float*)d_in[13];
    const float* wg     = (const float*)d_in[14];
    const float* bg     = (const float*)d_in[15];
    const float* wd     = (const float*)d_in[16];
    const float* bd     = (const float*)d_in[17];
    const float* pout_w = (const float*)d_in[18];
    const float* pout_b = (const float*)d_in[19];
    float* out = (float*)d_out;

    // ---- workspace layout (bytes) ----
    char* W = (char*)d_ws;
    u16* tb        = (u16*)W;                                     // t residual, bf16, 16.78 MB
    float* tmp_f32 = (float*)(W + 33554432);                      // vtb region
    u16* qb    = (u16*)(W + 67108864);                            // 16.78 MB (qb,kb,vb contiguous)
    u16* kb    = qb + 8388608;
    u16* vb    = kb + 8388608;
    u16* attnb = vb + 8388608;
    u16* Xb    = attnb + 8388608;                                 // 16.78 MB
    float* stats = (float*)(W + 67108864 + 5ull * 16777216);      // 1 KB
    u16* wbase = (u16*)(W + 67108864 + 5ull * 16777216 + 1024);
    u16* pinB  = wbase;                 // 512*512  (already [N][K])
    u16* poutB = pinB  + 262144;
    u16* wqT   = poutB + 262144;        // [512][512] transposed, scaled by QSCL
    u16* wkT   = wqT   + 262144;        // contiguous with wqT -> [1536][512] for fused qkv
    u16* wvT   = wkT   + 262144;
    u16* woT   = wvT   + 262144;
    u16* wgT   = woT   + 262144;        // [4096][512]
    u16* wdT   = wgT   + 2097152;       // [512][2048]
    u16* ag    = qb;                    // R x 2048 bf16, aliases qb..attnb (dead by then)
    u16* vtb   = (u16*)tmp_f32;         // V^T [b*8+h][64][1024]

    dim3 tb8(32, 8);

    // stats + fused weight prep (2 launches)
    gn_stats<<<128, 256, 0, stream>>>(x, stats);
    prep_all<<<4608, tb8, 0, stream>>>(pin_w, pout_w, pinB, poutB,
                                       wq, wk, wv, wo, wqT, wkT, wvT, woT,
                                       wg, wgT, wd, wdT);

    // h = GN(x) transposed -> Xb (bf16)
    gn_apply_t_bf<<<dim3(32, 16, 16), tb8, 0, stream>>>(x, stats, gn_w, gn_b, Xb);

    // t = h @ pin_w^T + pin_b -> tb (bf16)
    mfma_gemm<6><<<dim3(4, 64), 512, 0, stream>>>(Xb, pinB, pin_b, nullptr, tb, 512, 512);
    // tn = ln1(t) -> Xb
    layer_norm_rows_bf<<<16384, 256, 0, stream>>>(tb, ln1_w, ln1_b, Xb);
    // fused q(scaled)/k/v: N=1536, routed to qb/kb/vb
    mfma_gemm<8><<<dim3(12, 64), 512, 0, stream>>>(Xb, wqT, nullptr, nullptr, qb, 512, 1536);
    // per-head V transpose -> vtb
    vtrans<<<dim3(16, 8, 16), 256, 0, stream>>>(vb, vtb);
    // attention (MFMA, QBLK=128, KVBLK=128, prefetched, XCD-friendly grid) -> attnb
    flash_attn_mfma<<<dim3(8, 8, 16), 512, 0, stream>>>(qb, kb, vtb, attnb);
    // t += attn @ wo + bo (bf16 in-place on tb)
    mfma_gemm<7><<<dim3(4, 64), 512, 0, stream>>>(attnb, woT, bo, nullptr, tb, 512, 512);
    // tn3 = ln3(t) -> Xb
    layer_norm_rows_bf<<<16384, 256, 0, stream>>>(tb, ln3_w, ln3_b, Xb);
    // ag = a * gelu(g) (bf16), aliases q/k/v/attn space
    geglu_mfma<<<dim3(32, 64), 512, 0, stream>>>(Xb, wgT, bg, ag);
    // t += ag @ wd + bd (bf16 in-place on tb)
    mfma_gemm<7><<<dim3(4, 64), 512, 0, stream>>>(ag, wdT, bd, nullptr, tb, 2048, 512);
    // tmp = t @ pout_w^T + pout_b -> Xb (bf16)
    mfma_gemm<6><<<dim3(4, 64), 512, 0, stream>>>(tb, poutB, pout_b, nullptr, Xb, 512, 512);
    // out = tmp^T + x
    final_out_bf<<<dim3(32, 16, 16), tb8, 0, stream>>>(Xb, x, out);
}